// Round 4
// baseline (492.094 us; speedup 1.0000x reference)
//
#include <hip/hip_runtime.h>
#include <cstddef>
#include <cstdint>

#define BB 4
#define HH 8
#define HEADD 64
#define DIMM 512
#define XLL 1024
#define KLL 256
#define BHH (BB*HH)
#define SCALEF 0.125f

typedef __attribute__((ext_vector_type(8))) short bf16x8;
typedef __attribute__((ext_vector_type(8))) unsigned short u16x8;
typedef __attribute__((ext_vector_type(4))) float f32x4;
typedef unsigned short u16;

__device__ __forceinline__ u16 f2b(float f) {
    unsigned int u = __builtin_bit_cast(unsigned int, f);
    u = u + 0x7fffu + ((u >> 16) & 1u);
    return (u16)(u >> 16);
}
__device__ __forceinline__ float b2f(u16 h) {
    unsigned int u = ((unsigned int)h) << 16;
    return __builtin_bit_cast(float, u);
}
__device__ __forceinline__ f32x4 mfma16(bf16x8 a, bf16x8 b, f32x4 c) {
    return __builtin_amdgcn_mfma_f32_16x16x32_bf16(a, b, c, 0, 0, 0);
}
__device__ __forceinline__ float wred_max(float v) {
    #pragma unroll
    for (int o = 1; o < 64; o <<= 1) v = fmaxf(v, __shfl_xor(v, o, 64));
    return v;
}
__device__ __forceinline__ float wred_sum(float v) {
    #pragma unroll
    for (int o = 1; o < 64; o <<= 1) v += __shfl_xor(v, o, 64);
    return v;
}

// ---------------------------------------------------------------------------
// f32 -> bf16 cast, 8 elems/thread
// ---------------------------------------------------------------------------
__global__ __launch_bounds__(256) void cast_bf16_k(
    const float* __restrict__ in, u16* __restrict__ out, int n8)
{
    int i = blockIdx.x * 256 + threadIdx.x;
    if (i >= n8) return;
    const float4* p = reinterpret_cast<const float4*>(in) + (size_t)i * 2;
    float4 a = p[0], b = p[1];
    u16x8 o;
    o[0] = f2b(a.x); o[1] = f2b(a.y); o[2] = f2b(a.z); o[3] = f2b(a.w);
    o[4] = f2b(b.x); o[5] = f2b(b.y); o[6] = f2b(b.z); o[7] = f2b(b.w);
    *reinterpret_cast<u16x8*>(out + (size_t)i * 8) = o;
}

// ---------------------------------------------------------------------------
// W [K][N] f32  ->  Wt [N][K] bf16
// ---------------------------------------------------------------------------
__global__ __launch_bounds__(256) void transpose_cast_k(
    const float* __restrict__ W, u16* __restrict__ Wt, int K, int N)
{
    __shared__ float t[32][33];
    int bx = blockIdx.x, by = blockIdx.y;
    int tx = threadIdx.x & 31, ty = threadIdx.x >> 5;
    #pragma unroll
    for (int r = ty; r < 32; r += 8)
        t[r][tx] = W[(size_t)(by * 32 + r) * N + bx * 32 + tx];
    __syncthreads();
    #pragma unroll
    for (int r = ty; r < 32; r += 8)
        Wt[(size_t)(bx * 32 + r) * K + by * 32 + tx] = f2b(t[tx][r]);
}

// ---------------------------------------------------------------------------
// mask int32 [bh, 1024(x), 256(k)] -> uint8 [bh, 256(k), 1024(x)]
// ---------------------------------------------------------------------------
__global__ __launch_bounds__(256) void mask_t8_k(
    const int* __restrict__ m, unsigned char* __restrict__ mt)
{
    __shared__ unsigned char t[32][33];
    const int bh = blockIdx.z, xt = blockIdx.x, kt = blockIdx.y;
    const int tx = threadIdx.x & 31, ty = threadIdx.x >> 5;
    #pragma unroll
    for (int r = ty; r < 32; r += 8)
        t[r][tx] = (unsigned char)(m[((size_t)bh * 1024 + xt * 32 + r) * 256 + kt * 32 + tx] != 0);
    __syncthreads();
    #pragma unroll
    for (int r = ty; r < 32; r += 8)
        mt[((size_t)bh * 256 + kt * 32 + r) * 1024 + xt * 32 + tx] = t[tx][r];
}

// ---------------------------------------------------------------------------
// mask int32 -> uint8 same layout, 4 elems/thread
// ---------------------------------------------------------------------------
__global__ __launch_bounds__(256) void mask_u8_k(
    const int* __restrict__ m, unsigned char* __restrict__ o, int n4)
{
    int i = blockIdx.x * 256 + threadIdx.x;
    if (i >= n4) return;
    int4 v = reinterpret_cast<const int4*>(m)[i];
    uchar4 u;
    u.x = (unsigned char)(v.x != 0); u.y = (unsigned char)(v.y != 0);
    u.z = (unsigned char)(v.z != 0); u.w = (unsigned char)(v.w != 0);
    reinterpret_cast<uchar4*>(o)[i] = u;
}

// ---------------------------------------------------------------------------
// Combined bias for branch-2 s0: biasT[bh, x, k] bf16 =
//   att[bh,x,k] ? -1e9 : dis[rd[b,k,x]*8+h] + pemb[(clamp(polar)-MO[bh,k])&7]
// Grid (x/32, k/32, b); one block computes all 8 h.
// ---------------------------------------------------------------------------
__global__ __launch_bounds__(256) void bias_build_k(
    const int* __restrict__ rd, const int* __restrict__ polar,
    const int* __restrict__ att, const float* __restrict__ dis,
    const float* __restrict__ pemb, const int* __restrict__ MO,
    u16* __restrict__ biasT)
{
    const int b = blockIdx.z;
    const int xt = blockIdx.x * 32, kt = blockIdx.y * 32;
    const int tid = threadIdx.x;
    __shared__ int rds[32][33];
    __shared__ int pls[32][33];
    const int tx = tid & 31, ty = tid >> 5;
    #pragma unroll
    for (int r = ty; r < 32; r += 8) {
        size_t src = ((size_t)b * 256 + kt + r) * 1024 + xt + tx;
        rds[tx][r] = rd[src];
        int p = polar[src]; pls[tx][r] = p < 0 ? 0 : (p > 7 ? 7 : p);
    }
    __syncthreads();
    float pe[8];
    #pragma unroll
    for (int o = 0; o < 8; ++o) pe[o] = pemb[o];
    const int x = tid >> 3, k4 = (tid & 7) * 4;
    int rv[4], pv[4];
    #pragma unroll
    for (int j = 0; j < 4; ++j) { rv[j] = rds[x][k4 + j]; pv[j] = pls[x][k4 + j]; }
    #pragma unroll
    for (int h = 0; h < 8; ++h) {
        const int bh = b * 8 + h;
        size_t oidx = ((size_t)bh * 1024 + xt + x) * 256 + kt + k4;
        int4 m4 = *reinterpret_cast<const int4*>(att + oidx);
        int mm[4] = { m4.x, m4.y, m4.z, m4.w };
        unsigned short ov[4];
        #pragma unroll
        for (int j = 0; j < 4; ++j) {
            float v;
            if (mm[j]) v = -1e9f;
            else v = dis[rv[j] * 8 + h] + pe[(pv[j] - MO[bh * 256 + kt + k4 + j] + 8) & 7];
            ov[j] = f2b(v);
        }
        ushort4 o4; o4.x = ov[0]; o4.y = ov[1]; o4.z = ov[2]; o4.w = ov[3];
        *reinterpret_cast<ushort4*>(biasT + oidx) = o4;
    }
}

// ---------------------------------------------------------------------------
// QKV GEMM: A bf16 [M,512] @ Wt bf16 [1536,512]^T, epilogue split per head.
// q,k -> [b,h,n,64] bf16; v -> [b,h,64,n] bf16 (transposed for PV B-operand)
// ---------------------------------------------------------------------------
__global__ __launch_bounds__(256) void gemm_qkv_mfma_k(
    const u16* __restrict__ A, const u16* __restrict__ Wt,
    u16* __restrict__ qb, u16* __restrict__ kb, u16* __restrict__ vt,
    int sl)
{
    __shared__ __align__(16) short As[128][72];
    __shared__ __align__(16) short Bs[128][72];
    const int tid = threadIdx.x;
    const int wave = tid >> 6, lane = tid & 63;
    const int lr = lane & 15, lk = (lane >> 4) * 8;
    const int rb = blockIdx.y * 128, cb = blockIdx.x * 128;
    const int wr = (wave >> 1) * 64, wc = (wave & 1) * 64;
    const int seq = 1 << sl, smask = seq - 1;
    f32x4 acc[4][4] = {};
    const int srow = tid >> 3, skc = (tid & 7) * 8;
    for (int k0 = 0; k0 < 512; k0 += 64) {
        #pragma unroll
        for (int it = 0; it < 4; ++it) {
            int row = it * 32 + srow;
            *reinterpret_cast<bf16x8*>(&As[row][skc]) =
                *reinterpret_cast<const bf16x8*>(A + (size_t)(rb + row) * 512 + k0 + skc);
            *reinterpret_cast<bf16x8*>(&Bs[row][skc]) =
                *reinterpret_cast<const bf16x8*>(Wt + (size_t)(cb + row) * 512 + k0 + skc);
        }
        __syncthreads();
        #pragma unroll
        for (int ks = 0; ks < 2; ++ks) {
            bf16x8 af[4], bf_[4];
            #pragma unroll
            for (int mi = 0; mi < 4; ++mi)
                af[mi] = *reinterpret_cast<const bf16x8*>(&As[wr + mi * 16 + lr][ks * 32 + lk]);
            #pragma unroll
            for (int ni = 0; ni < 4; ++ni)
                bf_[ni] = *reinterpret_cast<const bf16x8*>(&Bs[wc + ni * 16 + lr][ks * 32 + lk]);
            #pragma unroll
            for (int mi = 0; mi < 4; ++mi)
                #pragma unroll
                for (int ni = 0; ni < 4; ++ni)
                    acc[mi][ni] = mfma16(af[mi], bf_[ni], acc[mi][ni]);
        }
        __syncthreads();
    }
    #pragma unroll
    for (int mi = 0; mi < 4; ++mi) {
        int m0 = rb + wr + mi * 16 + (lane >> 4) * 4;
        #pragma unroll
        for (int ni = 0; ni < 4; ++ni) {
            int c = cb + wc + ni * 16 + lr;
            int which = c >> 9, h = (c >> 6) & 7, d = c & 63;
            f32x4 v = acc[mi][ni];
            #pragma unroll
            for (int j = 0; j < 4; ++j) {
                int mm = m0 + j;
                int b = mm >> sl, n = mm & smask;
                u16 val = f2b(v[j]);
                if (which == 0) { if (qb) qb[(((size_t)b * HH + h) * seq + n) * 64 + d] = val; }
                else if (which == 1) { if (kb) kb[(((size_t)b * HH + h) * seq + n) * 64 + d] = val; }
                else vt[(((size_t)b * HH + h) * 64 + d) * seq + n] = val;
            }
        }
    }
}

// ---------------------------------------------------------------------------
// Proj GEMM: A bf16 [M,512] @ Wt bf16 [512,512]^T + bscale*bias
// ---------------------------------------------------------------------------
template<bool OUTBF>
__global__ __launch_bounds__(256) void gemm_proj_mfma_k(
    const u16* __restrict__ A, const u16* __restrict__ Wt,
    const float* __restrict__ bias, float bscale, void* __restrict__ outp)
{
    __shared__ __align__(16) short As[128][72];
    __shared__ __align__(16) short Bs[128][72];
    const int tid = threadIdx.x;
    const int wave = tid >> 6, lane = tid & 63;
    const int lr = lane & 15, lk = (lane >> 4) * 8;
    const int rb = blockIdx.y * 128, cb = blockIdx.x * 128;
    const int wr = (wave >> 1) * 64, wc = (wave & 1) * 64;
    f32x4 acc[4][4] = {};
    const int srow = tid >> 3, skc = (tid & 7) * 8;
    for (int k0 = 0; k0 < 512; k0 += 64) {
        #pragma unroll
        for (int it = 0; it < 4; ++it) {
            int row = it * 32 + srow;
            *reinterpret_cast<bf16x8*>(&As[row][skc]) =
                *reinterpret_cast<const bf16x8*>(A + (size_t)(rb + row) * 512 + k0 + skc);
            *reinterpret_cast<bf16x8*>(&Bs[row][skc]) =
                *reinterpret_cast<const bf16x8*>(Wt + (size_t)(cb + row) * 512 + k0 + skc);
        }
        __syncthreads();
        #pragma unroll
        for (int ks = 0; ks < 2; ++ks) {
            bf16x8 af[4], bf_[4];
            #pragma unroll
            for (int mi = 0; mi < 4; ++mi)
                af[mi] = *reinterpret_cast<const bf16x8*>(&As[wr + mi * 16 + lr][ks * 32 + lk]);
            #pragma unroll
            for (int ni = 0; ni < 4; ++ni)
                bf_[ni] = *reinterpret_cast<const bf16x8*>(&Bs[wc + ni * 16 + lr][ks * 32 + lk]);
            #pragma unroll
            for (int mi = 0; mi < 4; ++mi)
                #pragma unroll
                for (int ni = 0; ni < 4; ++ni)
                    acc[mi][ni] = mfma16(af[mi], bf_[ni], acc[mi][ni]);
        }
        __syncthreads();
    }
    #pragma unroll
    for (int mi = 0; mi < 4; ++mi) {
        int m0 = rb + wr + mi * 16 + (lane >> 4) * 4;
        #pragma unroll
        for (int ni = 0; ni < 4; ++ni) {
            int c = cb + wc + ni * 16 + lr;
            float bv = bscale * bias[c];
            f32x4 v = acc[mi][ni];
            #pragma unroll
            for (int j = 0; j < 4; ++j) {
                size_t o = (size_t)(m0 + j) * 512 + c;
                if (OUTBF) reinterpret_cast<u16*>(outp)[o] = f2b(v[j] + bv);
                else       reinterpret_cast<float*>(outp)[o] = v[j] + bv;
            }
        }
    }
}

// ---------------------------------------------------------------------------
// Scores: S[bh,r,c] = SCALE * Aq[bh,r,:64] . Bk[bh,c,:64], bf16 out
// ---------------------------------------------------------------------------
__global__ __launch_bounds__(256) void scores_mfma_k(
    const u16* __restrict__ Aq, const u16* __restrict__ Bk,
    u16* __restrict__ S, int R, int C)
{
    __shared__ __align__(16) short As[128][72];
    __shared__ __align__(16) short Bs[128][72];
    const int tid = threadIdx.x;
    const int wave = tid >> 6, lane = tid & 63;
    const int lr = lane & 15, lk = (lane >> 4) * 8;
    const int bh = blockIdx.z;
    const int rb = blockIdx.y * 128, cb = blockIdx.x * 128;
    const int wr = (wave >> 1) * 64, wc = (wave & 1) * 64;
    const u16* Ap = Aq + (size_t)bh * R * 64;
    const u16* Bp = Bk + (size_t)bh * C * 64;
    const int srow = tid >> 3, skc = (tid & 7) * 8;
    #pragma unroll
    for (int it = 0; it < 4; ++it) {
        int row = it * 32 + srow;
        *reinterpret_cast<bf16x8*>(&As[row][skc]) =
            *reinterpret_cast<const bf16x8*>(Ap + (size_t)(rb + row) * 64 + skc);
        *reinterpret_cast<bf16x8*>(&Bs[row][skc]) =
            *reinterpret_cast<const bf16x8*>(Bp + (size_t)(cb + row) * 64 + skc);
    }
    __syncthreads();
    f32x4 acc[4][4] = {};
    #pragma unroll
    for (int ks = 0; ks < 2; ++ks) {
        bf16x8 af[4], bf_[4];
        #pragma unroll
        for (int mi = 0; mi < 4; ++mi)
            af[mi] = *reinterpret_cast<const bf16x8*>(&As[wr + mi * 16 + lr][ks * 32 + lk]);
        #pragma unroll
        for (int ni = 0; ni < 4; ++ni)
            bf_[ni] = *reinterpret_cast<const bf16x8*>(&Bs[wc + ni * 16 + lr][ks * 32 + lk]);
        #pragma unroll
        for (int mi = 0; mi < 4; ++mi)
            #pragma unroll
            for (int ni = 0; ni < 4; ++ni)
                acc[mi][ni] = mfma16(af[mi], bf_[ni], acc[mi][ni]);
    }
    #pragma unroll
    for (int mi = 0; mi < 4; ++mi) {
        int r0 = rb + wr + mi * 16 + (lane >> 4) * 4;
        #pragma unroll
        for (int ni = 0; ni < 4; ++ni) {
            int c = cb + wc + ni * 16 + lr;
            f32x4 v = acc[mi][ni];
            #pragma unroll
            for (int j = 0; j < 4; ++j)
                S[((size_t)bh * R + r0 + j) * C + c] = f2b(v[j] * SCALEF);
        }
    }
}

// ---------------------------------------------------------------------------
// PV (wide path): out[b,r,h*64+d] = P[bh,r,:C] @ V[bh,:C,d]; Vt [bh,64,C]
// 64-row tiles, 4 waves x 16 rows, grid (R/64, BHH)
// ---------------------------------------------------------------------------
__global__ __launch_bounds__(256) void pv_mfma_k(
    const u16* __restrict__ P1, const u16* __restrict__ V1t,
    u16* __restrict__ out, int R, int C)
{
    __shared__ __align__(16) short As[64][72];
    __shared__ __align__(16) short Bs[64][72];
    const int tid = threadIdx.x;
    const int wave = tid >> 6, lane = tid & 63;
    const int lr = lane & 15, lg = lane >> 4, lk = lg * 8;
    const int bh = blockIdx.y, b = bh >> 3, h = bh & 7;
    const int rb = blockIdx.x * 64;
    const int wr = wave * 16;
    f32x4 acc[4] = {};
    const u16* Pb = P1 + ((size_t)bh * R + rb) * C;
    const u16* Vb = V1t + (size_t)bh * 64 * C;
    for (int c0 = 0; c0 < C; c0 += 64) {
        #pragma unroll
        for (int it = 0; it < 2; ++it) {
            int chunk = tid + it * 256;
            int r_ = chunk >> 3, c8 = (chunk & 7) * 8;
            *reinterpret_cast<bf16x8*>(&As[r_][c8]) =
                *reinterpret_cast<const bf16x8*>(Pb + (size_t)r_ * C + c0 + c8);
            *reinterpret_cast<bf16x8*>(&Bs[r_][c8]) =
                *reinterpret_cast<const bf16x8*>(Vb + (size_t)r_ * C + c0 + c8);
        }
        __syncthreads();
        #pragma unroll
        for (int ks = 0; ks < 2; ++ks) {
            bf16x8 ap = *reinterpret_cast<const bf16x8*>(&As[wr + lr][ks * 32 + lk]);
            #pragma unroll
            for (int ni = 0; ni < 4; ++ni) {
                bf16x8 bv = *reinterpret_cast<const bf16x8*>(&Bs[ni * 16 + lr][ks * 32 + lk]);
                acc[ni] = mfma16(ap, bv, acc[ni]);
            }
        }
        __syncthreads();
    }
    #pragma unroll
    for (int ni = 0; ni < 4; ++ni) {
        int d = ni * 16 + lr;
        f32x4 v = acc[ni];
        #pragma unroll
        for (int j = 0; j < 4; ++j) {
            int r0 = rb + wr + lg * 4 + j;
            out[((size_t)(b * R + r0)) * 512 + h * 64 + d] = f2b(v[j]);
        }
    }
}

// ---------------------------------------------------------------------------
// Wide softmax (C=1024 rows of S), fused main_ori (BIAS=1). maskT uint8 [bh,k,x].
// ---------------------------------------------------------------------------
template<int BIAS>
__global__ __launch_bounds__(256) void softmax_wide_k(
    u16* __restrict__ S, const unsigned char* __restrict__ maskT, float maskval,
    const int* __restrict__ rd, const int* __restrict__ polar,
    const float* __restrict__ dis, const float* __restrict__ pemb,
    int* __restrict__ MO)
{
    const int row_g = blockIdx.x;                 // bh*256 + k
    const int bh = row_g >> 8, k = row_g & 255;
    const int b = bh >> 3, h = bh & 7;
    const int tid = threadIdx.x;
    const int wave = tid >> 6, lane = tid & 63;
    const int c = tid * 4;
    u16* rowp = S + (size_t)row_g * 1024;
    ushort4 sv = *reinterpret_cast<const ushort4*>(rowp + c);
    float s[4] = { b2f(sv.x), b2f(sv.y), b2f(sv.z), b2f(sv.w) };
    uchar4 mk = *reinterpret_cast<const uchar4*>(maskT + (size_t)row_g * 1024 + c);
    unsigned char mka[4] = { mk.x, mk.y, mk.z, mk.w };

    __shared__ float sred[4][8];
    __shared__ int smo;
    __shared__ float swv[4];

    int mo = 0;
    int rr[4] = {}, pp[4] = {};
    if (BIAS) {
        size_t pbase = ((size_t)b * 256 + k) * 1024 + c;
        int4 r4 = *reinterpret_cast<const int4*>(rd + pbase);
        int4 p4 = *reinterpret_cast<const int4*>(polar + pbase);
        rr[0] = r4.x; rr[1] = r4.y; rr[2] = r4.z; rr[3] = r4.w;
        int pt[4] = { p4.x, p4.y, p4.z, p4.w };
        #pragma unroll
        for (int j = 0; j < 4; ++j) { int p = pt[j]; pp[j] = p < 0 ? 0 : (p > 7 ? 7 : p); }
        float bins[8] = {};
        #pragma unroll
        for (int j = 0; j < 4; ++j) {
            float av = fabsf(s[j]);
            #pragma unroll
            for (int o = 0; o < 8; ++o) bins[o] += (pp[j] == o) ? av : 0.0f;
        }
        #pragma unroll
        for (int o = 0; o < 8; ++o) bins[o] = wred_sum(bins[o]);
        if (lane == 0) {
            #pragma unroll
            for (int o = 0; o < 8; ++o) sred[wave][o] = bins[o];
        }
        __syncthreads();
        if (tid == 0) {
            int best = 0; float bv = -1.0f;
            #pragma unroll
            for (int o = 0; o < 8; ++o) {
                float t = sred[0][o] + sred[1][o] + sred[2][o] + sred[3][o];
                if (t > bv) { bv = t; best = o; }
            }
            smo = best;
            MO[row_g] = best;
        }
        __syncthreads();
        mo = smo;
    }
    #pragma unroll
    for (int j = 0; j < 4; ++j) if (mka[j]) s[j] = maskval;
    if (BIAS) {
        #pragma unroll
        for (int j = 0; j < 4; ++j)
            s[j] += dis[rr[j] * HH + h] + pemb[(pp[j] - mo + 8) & 7];
    }
    float lm = fmaxf(fmaxf(s[0], s[1]), fmaxf(s[2], s[3]));
    lm = wred_max(lm);
    if (lane == 0) swv[wave] = lm;
    __syncthreads();
    float m = fmaxf(fmaxf(swv[0], swv[1]), fmaxf(swv[2], swv[3]));
    __syncthreads();
    float ls = 0.0f;
    #pragma unroll
    for (int j = 0; j < 4; ++j) { s[j] = __expf(s[j] - m); ls += s[j]; }
    ls = wred_sum(ls);
    if (lane == 0) swv[wave] = ls;
    __syncthreads();
    float inv = 1.0f / (swv[0] + swv[1] + swv[2] + swv[3]);
    ushort4 ov = { f2b(s[0] * inv), f2b(s[1] * inv), f2b(s[2] * inv), f2b(s[3] * inv) };
    *reinterpret_cast<ushort4*>(rowp + c) = ov;
}

// ---------------------------------------------------------------------------
// Fused attention for R=1024 (x rows), C=256 (k cols):
// scores -> (combined bf16 bias incl. mask | u8 mask) -> softmax -> PV.
// NSRC=2 accumulates two (K,V) sets. Grid: 256 blocks 1-D, XCD-swizzled.
// ---------------------------------------------------------------------------
template<int NSRC, bool BIAS0>
__global__ __launch_bounds__(512) void attn_xk_fused_k(
    const u16* __restrict__ Qp,
    const u16* __restrict__ K1, const u16* __restrict__ V1t,
    const u16* __restrict__ B1bias, const unsigned char* __restrict__ M1,
    const u16* __restrict__ K2, const u16* __restrict__ V2t,
    const unsigned char* __restrict__ M2,
    u16* __restrict__ outm)
{
    const int tid = threadIdx.x;
    const int w = tid >> 6, lane = tid & 63;
    const int lr = lane & 15, lg = lane >> 4;
    const int lk = lg * 8;
    // XCD-aware swizzle: all 8 x-blocks of a bh land on one XCD
    const int lin = blockIdx.x;
    const int xcd = lin & 7, idx = lin >> 3;
    const int bh = xcd * 4 + (idx & 3);
    const int rb = (idx >> 2) * 128;
    const int b = bh >> 3, h = bh & 7;
    const int wrow = (w >> 2) * 64, wcol = (w & 3) * 64;   // scores tiling
    const int wrow2 = w * 16;                               // pv tiling
    const int wcg = w & 3;

    __shared__ __align__(16) char lds[18432 + 67584 + 33792 + 2048];
    short* Qs = (short*)lds;                       // [128][72]
    short* KP = (short*)(lds + 18432);             // Ks [256][72] | Ps [128][264]
    short* Vsl = (short*)(lds + 18432 + 67584);    // [64][264]
    float* red = (float*)(lds + 18432 + 67584 + 33792); // [128][4]

    // stage Q tile [128][64]
    {
        const u16* Qb = Qp + ((size_t)bh * 1024 + rb) * 64;
        #pragma unroll
        for (int it = 0; it < 2; ++it) {
            int chunk = tid + it * 512;
            int r_ = chunk >> 3, c8 = (chunk & 7) * 8;
            *reinterpret_cast<bf16x8*>(&Qs[r_ * 72 + c8]) =
                *reinterpret_cast<const bf16x8*>(Qb + (size_t)r_ * 64 + c8);
        }
    }

    f32x4 acc2[4] = {};   // PV accumulator over d (4 ni fragments)

    #pragma unroll
    for (int s = 0; s < NSRC; ++s) {
        const u16* Kp = (s == 0) ? K1 : K2;
        const u16* Vp = (s == 0) ? V1t : V2t;
        __syncthreads();   // prior PV done (and Q staged on iter 0)
        // stage K [256][64] and V [64][256]
        #pragma unroll
        for (int it = 0; it < 4; ++it) {
            int chunk = tid + it * 512;
            int r_ = chunk >> 3, c8 = (chunk & 7) * 8;
            *reinterpret_cast<bf16x8*>(&KP[r_ * 72 + c8]) =
                *reinterpret_cast<const bf16x8*>(Kp + ((size_t)bh * 256 + r_) * 64 + c8);
            int vd = chunk >> 5, vc8 = (chunk & 31) * 8;
            *reinterpret_cast<bf16x8*>(&Vsl[vd * 264 + vc8]) =
                *reinterpret_cast<const bf16x8*>(Vp + ((size_t)bh * 64 + vd) * 256 + vc8);
        }
        __syncthreads();
        // scores: 64x64 per wave, K=64
        f32x4 acc[4][4] = {};
        #pragma unroll
        for (int ks = 0; ks < 2; ++ks) {
            bf16x8 af[4], bfv[4];
            #pragma unroll
            for (int mi = 0; mi < 4; ++mi)
                af[mi] = *reinterpret_cast<const bf16x8*>(&Qs[(wrow + mi * 16 + lr) * 72 + ks * 32 + lk]);
            #pragma unroll
            for (int ni = 0; ni < 4; ++ni)
                bfv[ni] = *reinterpret_cast<const bf16x8*>(&KP[(wcol + ni * 16 + lr) * 72 + ks * 32 + lk]);
            #pragma unroll
            for (int mi = 0; mi < 4; ++mi)
                #pragma unroll
                for (int ni = 0; ni < 4; ++ni)
                    acc[mi][ni] = mfma16(af[mi], bfv[ni], acc[mi][ni]);
        }
        // scale + combined bias (incl. mask) or u8 mask
        #pragma unroll
        for (int ni = 0; ni < 4; ++ni) {
            const int cK = wcol + ni * 16 + lr;
            #pragma unroll
            for (int mi = 0; mi < 4; ++mi) {
                #pragma unroll
                for (int j = 0; j < 4; ++j) {
                    const int rXj = rb + wrow + mi * 16 + lg * 4 + j;
                    size_t idx_ = ((size_t)bh * 1024 + rXj) * 256 + cK;
                    float sv_ = acc[mi][ni][j] * SCALEF;
                    if (BIAS0 && s == 0) {
                        sv_ += b2f(B1bias[idx_]);
                    } else {
                        const unsigned char* Mp = (s == 0) ? M1 : M2;
                        if (Mp[idx_]) sv_ = -1e9f;
                    }
                    acc[mi][ni][j] = sv_;
                }
            }
        }
        // row max (cross 16 lanes, then cross 4 col-waves via LDS)
        float rmax[4][4];
        #pragma unroll
        for (int mi = 0; mi < 4; ++mi)
            #pragma unroll
            for (int j = 0; j < 4; ++j) {
                float v = fmaxf(fmaxf(acc[mi][0][j], acc[mi][1][j]),
                                fmaxf(acc[mi][2][j], acc[mi][3][j]));
                #pragma unroll
                for (int o = 1; o < 16; o <<= 1) v = fmaxf(v, __shfl_xor(v, o, 64));
                rmax[mi][j] = v;
            }
        if (lr == 0) {
            #pragma unroll
            for (int mi = 0; mi < 4; ++mi)
                #pragma unroll
                for (int j = 0; j < 4; ++j)
                    red[(wrow + mi * 16 + lg * 4 + j) * 4 + wcg] = rmax[mi][j];
        }
        __syncthreads();
        float rowm[4][4];
        #pragma unroll
        for (int mi = 0; mi < 4; ++mi)
            #pragma unroll
            for (int j = 0; j < 4; ++j) {
                f32x4 r4 = *reinterpret_cast<f32x4*>(&red[(wrow + mi * 16 + lg * 4 + j) * 4]);
                rowm[mi][j] = fmaxf(fmaxf(r4[0], r4[1]), fmaxf(r4[2], r4[3]));
            }
        __syncthreads();   // all max reads done before sum writes
        // exp + row sum
        float rsum[4][4];
        #pragma unroll
        for (int mi = 0; mi < 4; ++mi)
            #pragma unroll
            for (int j = 0; j < 4; ++j) {
                float m_ = rowm[mi][j];
                float e0 = __expf(acc[mi][0][j] - m_);
                float e1 = __expf(acc[mi][1][j] - m_);
                float e2 = __expf(acc[mi][2][j] - m_);
                float e3 = __expf(acc[mi][3][j] - m_);
                acc[mi][0][j] = e0; acc[mi][1][j] = e1;
                acc[mi][2][j] = e2; acc[mi][3][j] = e3;
                float v = (e0 + e1) + (e2 + e3);
                #pragma unroll
                for (int o = 1; o < 16; o <<= 1) v += __shfl_xor(v, o, 64);
                rsum[mi][j] = v;
            }
        if (lr == 0) {
            #pragma unroll
            for (int mi = 0; mi < 4; ++mi)
                #pragma unroll
                for (int j = 0; j < 4; ++j)
                    red[(wrow + mi * 16 + lg * 4 + j) * 4 + wcg] = rsum[mi][j];
        }
        __syncthreads();
        // normalize + write P (aliases K region; all K reads finished above)
        #pragma unroll
        for (int mi = 0; mi < 4; ++mi)
            #pragma unroll
            for (int j = 0; j < 4; ++j) {
                f32x4 r4 = *reinterpret_cast<f32x4*>(&red[(wrow + mi * 16 + lg * 4 + j) * 4]);
                float inv = 1.0f / (((r4[0] + r4[1]) + (r4[2] + r4[3])));
                int rloc = wrow + mi * 16 + lg * 4 + j;
                #pragma unroll
                for (int ni = 0; ni < 4; ++ni)
                    KP[rloc * 264 + wcol + ni * 16 + lr] = (short)f2b(acc[mi][ni][j] * inv);
            }
        __syncthreads();
        // PV: 16 rows per wave, N=64, K=256
        #pragma unroll
        for (int kc = 0; kc < 8; ++kc) {
            bf16x8 ap = *reinterpret_cast<const bf16x8*>(&KP[(wrow2 + lr) * 264 + kc * 32 + lk]);
            #pragma unroll
            for (int ni = 0; ni < 4; ++ni) {
                bf16x8 vv = *reinterpret_cast<const bf16x8*>(&Vsl[(ni * 16 + lr) * 264 + kc * 32 + lk]);
                acc2[ni] = mfma16(ap, vv, acc2[ni]);
            }
        }
    }
    // epilogue: merged bf16 out [b, x, 512]
    #pragma unroll
    for (int ni = 0; ni < 4; ++ni) {
        int d = ni * 16 + lr;
        f32x4 v = acc2[ni];
        #pragma unroll
        for (int j = 0; j < 4; ++j) {
            int row = rb + wrow2 + lg * 4 + j;
            outm[((size_t)(b * 1024 + row)) * 512 + h * 64 + d] = f2b(v[j]);
        }
    }
}

// ---------------------------------------------------------------------------
extern "C" void kernel_launch(void* const* d_in, const int* in_sizes, int n_in,
                              void* d_out, int out_size, void* d_ws, size_t ws_size,
                              hipStream_t stream)
{
    const float* x        = (const float*)d_in[0];
    const float* kernal   = (const float*)d_in[1];
    const float* i_x      = (const float*)d_in[2];
    const float* i_kernal = (const float*)d_in[3];
    const int*   rd       = (const int*)d_in[4];
    const int*   polar    = (const int*)d_in[5];
    const int*   att      = (const int*)d_in[6];
    const int*   i_att    = (const int*)d_in[7];
    const int*   cross    = (const int*)d_in[8];
    const float* Wqkv     = (const float*)d_in[9];
    const float* Wqkv_i   = (const float*)d_in[10];
    const float* Wqkv_i2  = (const float*)d_in[11];
    const float* Wproj    = (const float*)d_in[12];
    const float* bproj    = (const float*)d_in[13];
    const float* Wproj_i  = (const float*)d_in[14];
    const float* bproj_i  = (const float*)d_in[15];
    const float* Wproj_i2 = (const float*)d_in[16];
    const float* bproj_i2 = (const float*)d_in[17];
    const float* dis      = (const float*)d_in[18];
    const float* pemb     = (const float*)d_in[19];

    float* out = (float*)d_out;
    float* x_out   = out;
    float* k_out   = out + (size_t)BB * XLL * DIMM;
    float* i_x_out = k_out + (size_t)BB * KLL * DIMM;

    char* ws = (char*)d_ws;
    size_t off = 0;
    auto alloc = [&](size_t bytes) { void* p = ws + off; off += (bytes + 255) & ~(size_t)255; return p; };

    const size_t NAX = (size_t)BB * XLL * DIMM;
    const size_t NAK = (size_t)BB * KLL * DIMM;
    const size_t NHX = (size_t)BHH * XLL * HEADD;
    const size_t NHK = (size_t)BHH * KLL * HEADD;
    const size_t NS  = (size_t)BHH * KLL * XLL;

    u16* WqkvT     = (u16*)alloc((size_t)1536 * 512 * 2);
    u16* WqkvIT    = (u16*)alloc((size_t)1536 * 512 * 2);
    u16* WqkvI2T   = (u16*)alloc((size_t)1536 * 512 * 2);
    u16* WprojT    = (u16*)alloc((size_t)512 * 512 * 2);
    u16* WprojIT   = (u16*)alloc((size_t)512 * 512 * 2);
    u16* WprojI2T  = (u16*)alloc((size_t)512 * 512 * 2);
    u16* Abf       = (u16*)alloc(NAX * 2);
    u16* Q    = (u16*)alloc(NHX * 2);
    u16* KX   = (u16*)alloc(NHX * 2);
    u16* VXt  = (u16*)alloc(NHX * 2);
    u16* KQ   = (u16*)alloc(NHK * 2);
    u16* KK   = (u16*)alloc(NHK * 2);
    u16* KVt  = (u16*)alloc(NHK * 2);
    u16* IQ   = (u16*)alloc(NHX * 2);
    u16* IK   = (u16*)alloc(NHX * 2);
    u16* IVt  = (u16*)alloc(NHX * 2);
    u16* IKQ  = (u16*)alloc(NHK * 2);
    u16* IKK  = (u16*)alloc(NHK * 2);
    u16* IKVt = (u16*)alloc(NHK * 2);
    u16* K2K  = (u16*)alloc(NHK * 2);
    u16* K2Vt = (u16*)alloc(NHK * 2);
    u16* SPa  = (u16*)alloc(NS * 2);
    u16* KMb  = (u16*)alloc(NAK * 2);
    u16* XMb  = (u16*)alloc(NAX * 2);
    u16* IKOUTb = (u16*)alloc(NAK * 2);
    u16* biasT = (u16*)alloc(NS * 2);
    unsigned char* attT8   = (unsigned char*)alloc(NS);
    unsigned char* iattT8  = (unsigned char*)alloc(NS);
    unsigned char* crossU8 = (unsigned char*)alloc(NS);
    unsigned char* iattU8  = (unsigned char*)alloc(NS);
    int* MO   = (int*)alloc((size_t)BHH * KLL * 4);

    dim3 blk(256);

    // weight transposes
    transpose_cast_k<<<dim3(48, 16), blk, 0, stream>>>(Wqkv,     WqkvT,   512, 1536);
    transpose_cast_k<<<dim3(48, 16), blk, 0, stream>>>(Wqkv_i,   WqkvIT,  512, 1536);
    transpose_cast_k<<<dim3(48, 16), blk, 0, stream>>>(Wqkv_i2,  WqkvI2T, 512, 1536);
    transpose_cast_k<<<dim3(16, 16), blk, 0, stream>>>(Wproj,    WprojT,  512, 512);
    transpose_cast_k<<<dim3(16, 16), blk, 0, stream>>>(Wproj_i,  WprojIT, 512, 512);
    transpose_cast_k<<<dim3(16, 16), blk, 0, stream>>>(Wproj_i2, WprojI2T,512, 512);

    // mask conversions
    mask_t8_k<<<dim3(32, 8, 32), blk, 0, stream>>>(att,   attT8);
    mask_t8_k<<<dim3(32, 8, 32), blk, 0, stream>>>(i_att, iattT8);
    mask_u8_k<<<dim3(8192), blk, 0, stream>>>(cross, crossU8, (int)(NS / 4));
    mask_u8_k<<<dim3(8192), blk, 0, stream>>>(i_att, iattU8, (int)(NS / 4));

    // QKV projections
    cast_bf16_k<<<dim3(1024), blk, 0, stream>>>(x, Abf, (int)(NAX / 8));
    gemm_qkv_mfma_k<<<dim3(12, 32), blk, 0, stream>>>(Abf, WqkvT, Q, KX, VXt, 10);
    cast_bf16_k<<<dim3(256), blk, 0, stream>>>(kernal, Abf, (int)(NAK / 8));
    gemm_qkv_mfma_k<<<dim3(12, 8), blk, 0, stream>>>(Abf, WqkvT, KQ, KK, KVt, 8);
    cast_bf16_k<<<dim3(1024), blk, 0, stream>>>(i_x, Abf, (int)(NAX / 8));
    gemm_qkv_mfma_k<<<dim3(12, 32), blk, 0, stream>>>(Abf, WqkvIT, IQ, IK, IVt, 10);
    cast_bf16_k<<<dim3(256), blk, 0, stream>>>(kernal ? i_kernal : i_kernal, Abf, (int)(NAK / 8));
    gemm_qkv_mfma_k<<<dim3(12, 8), blk, 0, stream>>>(Abf, WqkvIT, IKQ, IKK, IKVt, 8);

    // --- branch 1: k_out ---
    scores_mfma_k<<<dim3(8, 2, BHH), blk, 0, stream>>>(KQ, KX, SPa, KLL, XLL);
    softmax_wide_k<1><<<dim3(BHH * KLL), blk, 0, stream>>>(SPa, attT8, -1e6f, rd, polar, dis, pemb, MO);
    pv_mfma_k<<<dim3(4, BHH), blk, 0, stream>>>(SPa, VXt, KMb, KLL, XLL);
    gemm_proj_mfma_k<false><<<dim3(4, 8), blk, 0, stream>>>(KMb, WprojT, bproj, 1.0f, k_out);

    // combined bias for branch 2 (needs MO)
    bias_build_k<<<dim3(32, 8, 4), blk, 0, stream>>>(rd, polar, att, dis, pemb, MO, biasT);

    // --- branch 2: x_out (fused dual attention) ---
    attn_xk_fused_k<2, true><<<dim3(256), dim3(512), 0, stream>>>(
        Q, KK, KVt, biasT, nullptr, IKK, IKVt, crossU8, XMb);
    gemm_proj_mfma_k<false><<<dim3(4, 32), blk, 0, stream>>>(XMb, WprojT, bproj, 2.0f, x_out);

    // --- branch 3: i_x_out ---
    scores_mfma_k<<<dim3(8, 2, BHH), blk, 0, stream>>>(IKQ, IK, SPa, KLL, XLL);
    softmax_wide_k<0><<<dim3(BHH * KLL), blk, 0, stream>>>(SPa, iattT8, -1e9f, rd, polar, dis, pemb, MO);
    pv_mfma_k<<<dim3(4, BHH), blk, 0, stream>>>(SPa, IVt, KMb, KLL, XLL);
    gemm_proj_mfma_k<true><<<dim3(4, 8), blk, 0, stream>>>(KMb, WprojIT, bproj_i, 1.0f, IKOUTb);
    gemm_qkv_mfma_k<<<dim3(12, 8), blk, 0, stream>>>(IKOUTb, WqkvI2T, nullptr, K2K, K2Vt, 8);
    attn_xk_fused_k<1, false><<<dim3(256), dim3(512), 0, stream>>>(
        IQ, K2K, K2Vt, nullptr, iattU8, nullptr, nullptr, nullptr, XMb);
    gemm_proj_mfma_k<false><<<dim3(4, 32), blk, 0, stream>>>(XMb, WprojI2T, bproj_i2, 1.0f, i_x_out);

    (void)in_sizes; (void)n_in; (void)out_size; (void)ws_size;
}

// Round 5
// 475.114 us; speedup vs baseline: 1.0357x; 1.0357x over previous
//
#include <hip/hip_runtime.h>
#include <cstddef>
#include <cstdint>

#define BB 4
#define HH 8
#define HEADD 64
#define DIMM 512
#define XLL 1024
#define KLL 256
#define BHH (BB*HH)

typedef __attribute__((ext_vector_type(8))) short bf16x8;
typedef __attribute__((ext_vector_type(8))) unsigned short u16x8;
typedef __attribute__((ext_vector_type(4))) float f32x4;
typedef unsigned short u16;

__device__ __forceinline__ u16 f2b(float f) {
    unsigned int u = __builtin_bit_cast(unsigned int, f);
    u = u + 0x7fffu + ((u >> 16) & 1u);
    return (u16)(u >> 16);
}
__device__ __forceinline__ float b2f(u16 h) {
    unsigned int u = ((unsigned int)h) << 16;
    return __builtin_bit_cast(float, u);
}
__device__ __forceinline__ f32x4 mfma16(bf16x8 a, bf16x8 b, f32x4 c) {
    return __builtin_amdgcn_mfma_f32_16x16x32_bf16(a, b, c, 0, 0, 0);
}
__device__ __forceinline__ float wred_max(float v) {
    #pragma unroll
    for (int o = 1; o < 64; o <<= 1) v = fmaxf(v, __shfl_xor(v, o, 64));
    return v;
}
__device__ __forceinline__ float wred_sum(float v) {
    #pragma unroll
    for (int o = 1; o < 64; o <<= 1) v += __shfl_xor(v, o, 64);
    return v;
}

// ---------------------------------------------------------------------------
// f32 -> bf16 cast, 8 elems/thread
// ---------------------------------------------------------------------------
__global__ __launch_bounds__(256) void cast_bf16_k(
    const float* __restrict__ in, u16* __restrict__ out, int n8)
{
    int i = blockIdx.x * 256 + threadIdx.x;
    if (i >= n8) return;
    const float4* p = reinterpret_cast<const float4*>(in) + (size_t)i * 2;
    float4 a = p[0], b = p[1];
    u16x8 o;
    o[0] = f2b(a.x); o[1] = f2b(a.y); o[2] = f2b(a.z); o[3] = f2b(a.w);
    o[4] = f2b(b.x); o[5] = f2b(b.y); o[6] = f2b(b.z); o[7] = f2b(b.w);
    *reinterpret_cast<u16x8*>(out + (size_t)i * 8) = o;
}

// ---------------------------------------------------------------------------
// W [K][N] f32  ->  Wt [N][K] bf16
// ---------------------------------------------------------------------------
__global__ __launch_bounds__(256) void transpose_cast_k(
    const float* __restrict__ W, u16* __restrict__ Wt, int K, int N)
{
    __shared__ float t[32][33];
    int bx = blockIdx.x, by = blockIdx.y;
    int tx = threadIdx.x & 31, ty = threadIdx.x >> 5;
    #pragma unroll
    for (int r = ty; r < 32; r += 8)
        t[r][tx] = W[(size_t)(by * 32 + r) * N + bx * 32 + tx];
    __syncthreads();
    #pragma unroll
    for (int r = ty; r < 32; r += 8)
        Wt[(size_t)(bx * 32 + r) * K + by * 32 + tx] = f2b(t[tx][r]);
}

// ---------------------------------------------------------------------------
// i_att int32 [bh,x,k] -> iattT8 u8 [bh,k,x]  AND  iattBias bf16 [bh,x,k]
// ---------------------------------------------------------------------------
__global__ __launch_bounds__(256) void conv_iatt_k(
    const int* __restrict__ m, unsigned char* __restrict__ mt,
    u16* __restrict__ mb)
{
    __shared__ unsigned char t[32][33];
    const int bh = blockIdx.z, xt = blockIdx.x, kt = blockIdx.y;
    const int tx = threadIdx.x & 31, ty = threadIdx.x >> 5;
    const u16 NEG = f2b(-1e9f);
    #pragma unroll
    for (int r = ty; r < 32; r += 8) {
        size_t idx = ((size_t)bh * 1024 + xt * 32 + r) * 256 + kt * 32 + tx;
        unsigned char v = (unsigned char)(m[idx] != 0);
        t[r][tx] = v;
        mb[idx] = v ? NEG : (u16)0;
    }
    __syncthreads();
    #pragma unroll
    for (int r = ty; r < 32; r += 8)
        mt[((size_t)bh * 256 + kt * 32 + r) * 1024 + xt * 32 + tx] = t[tx][r];
}

// ---------------------------------------------------------------------------
// mask int32 -> bf16 bias (0 / -1e9), same layout, 4 elems/thread
// ---------------------------------------------------------------------------
__global__ __launch_bounds__(256) void mask_bias_k(
    const int* __restrict__ m, u16* __restrict__ o, int n4)
{
    int i = blockIdx.x * 256 + threadIdx.x;
    if (i >= n4) return;
    int4 v = reinterpret_cast<const int4*>(m)[i];
    const u16 NEG = f2b(-1e9f);
    ushort4 u;
    u.x = v.x ? NEG : (u16)0; u.y = v.y ? NEG : (u16)0;
    u.z = v.z ? NEG : (u16)0; u.w = v.w ? NEG : (u16)0;
    reinterpret_cast<ushort4*>(o)[i] = u;
}

// ---------------------------------------------------------------------------
// main orientation: block per (b,k); reads polar row once, loops 8 heads.
// ---------------------------------------------------------------------------
__global__ __launch_bounds__(256) void main_ori_k8(
    const u16* __restrict__ S, const int* __restrict__ polar,
    int* __restrict__ MO)
{
    const int blk = blockIdx.x;          // b*256 + k
    const int b = blk >> 8, k = blk & 255;
    const int tid = threadIdx.x;
    const int wave = tid >> 6, lane = tid & 63;
    const int c = tid * 4;
    int4 p4 = *reinterpret_cast<const int4*>(polar + ((size_t)b * 256 + k) * 1024 + c);
    int pp[4] = { p4.x, p4.y, p4.z, p4.w };
    #pragma unroll
    for (int j = 0; j < 4; ++j) { int p = pp[j]; pp[j] = p < 0 ? 0 : (p > 7 ? 7 : p); }
    __shared__ float sred[4][8];
    for (int h = 0; h < 8; ++h) {
        const int bh = b * 8 + h;
        ushort4 sv = *reinterpret_cast<const ushort4*>(S + ((size_t)bh * 256 + k) * 1024 + c);
        float av[4] = { fabsf(b2f(sv.x)), fabsf(b2f(sv.y)), fabsf(b2f(sv.z)), fabsf(b2f(sv.w)) };
        float bins[8] = {};
        #pragma unroll
        for (int j = 0; j < 4; ++j) {
            #pragma unroll
            for (int o = 0; o < 8; ++o) bins[o] += (pp[j] == o) ? av[j] : 0.0f;
        }
        #pragma unroll
        for (int o = 0; o < 8; ++o) bins[o] = wred_sum(bins[o]);
        if (lane == 0) {
            #pragma unroll
            for (int o = 0; o < 8; ++o) sred[wave][o] = bins[o];
        }
        __syncthreads();
        if (tid == 0) {
            int best = 0; float bv = -1.0f;
            #pragma unroll
            for (int o = 0; o < 8; ++o) {
                float s = sred[0][o] + sred[1][o] + sred[2][o] + sred[3][o];
                if (s > bv) { bv = s; best = o; }
            }
            MO[bh * 256 + k] = best;
        }
        __syncthreads();
    }
}

// ---------------------------------------------------------------------------
// Combined bias build (after MO): per (b, x-tile32, k-tile32), all 8 heads:
//   v = dis[rd]+pemb[(polar-MO)&7]
//   biasT[bh,x,k] = att ? -1e9 : v   (branch 2)
//   bias1[bh,k,x] = att ? -1e6 : v   (branch 1)
// ---------------------------------------------------------------------------
__global__ __launch_bounds__(256) void bias_build_k(
    const int* __restrict__ rd, const int* __restrict__ polar,
    const int* __restrict__ att, const float* __restrict__ dis,
    const float* __restrict__ pemb, const int* __restrict__ MO,
    u16* __restrict__ biasT, u16* __restrict__ bias1)
{
    const int b = blockIdx.z;
    const int xt = blockIdx.x * 32, kt = blockIdx.y * 32;
    const int tid = threadIdx.x;
    __shared__ float dsh[528];
    __shared__ int rds[32][33];   // [x][k]
    __shared__ int pls[32][33];
    __shared__ u16 bt[32][33];    // bias (−1e6 variant) tile [x][k]
    for (int i = tid; i < 528; i += 256) dsh[i] = dis[i];
    const int tx = tid & 31, ty = tid >> 5;
    #pragma unroll
    for (int r = ty; r < 32; r += 8) {
        size_t src = ((size_t)b * 256 + kt + r) * 1024 + xt + tx;  // rd[b,k,x]
        rds[tx][r] = rd[src];
        int p = polar[src]; pls[tx][r] = p < 0 ? 0 : (p > 7 ? 7 : p);
    }
    float pe[8];
    #pragma unroll
    for (int o = 0; o < 8; ++o) pe[o] = pemb[o];
    __syncthreads();
    const int x = tid >> 3, k4 = (tid & 7) * 4;
    const u16 NEG9 = f2b(-1e9f), NEG6 = f2b(-1e6f);
    for (int h = 0; h < 8; ++h) {
        const int bh = b * 8 + h;
        size_t oidx = ((size_t)bh * 1024 + xt + x) * 256 + kt + k4;
        int4 m4 = *reinterpret_cast<const int4*>(att + oidx);
        int4 mo4 = *reinterpret_cast<const int4*>(MO + bh * 256 + kt + k4);
        int mm[4] = { m4.x, m4.y, m4.z, m4.w };
        int mo[4] = { mo4.x, mo4.y, mo4.z, mo4.w };
        u16 o_[4];
        #pragma unroll
        for (int j = 0; j < 4; ++j) {
            float v = dsh[rds[x][k4 + j] * 8 + h] + pe[(pls[x][k4 + j] - mo[j] + 8) & 7];
            u16 vb = f2b(v);
            o_[j] = mm[j] ? NEG9 : vb;
            bt[x][k4 + j] = mm[j] ? NEG6 : vb;
        }
        ushort4 ov; ov.x = o_[0]; ov.y = o_[1]; ov.z = o_[2]; ov.w = o_[3];
        *reinterpret_cast<ushort4*>(biasT + oidx) = ov;
        __syncthreads();
        const int k_ = tid >> 3, x4 = (tid & 7) * 4;
        ushort4 o2;
        o2.x = bt[x4 + 0][k_]; o2.y = bt[x4 + 1][k_];
        o2.z = bt[x4 + 2][k_]; o2.w = bt[x4 + 3][k_];
        *reinterpret_cast<ushort4*>(bias1 + ((size_t)bh * 256 + kt + k_) * 1024 + xt + x4) = o2;
        __syncthreads();
    }
}

// ---------------------------------------------------------------------------
// QKV GEMM: A bf16 [M,512] @ Wt bf16 [1536,512]^T; q pre-scaled by 0.125.
// q,k -> [b,h,n,64] bf16; v -> [b,h,64,n] bf16 (transposed)
// ---------------------------------------------------------------------------
__global__ __launch_bounds__(256) void gemm_qkv_mfma_k(
    const u16* __restrict__ A, const u16* __restrict__ Wt,
    u16* __restrict__ qb, u16* __restrict__ kb, u16* __restrict__ vt,
    int sl)
{
    __shared__ __align__(16) short As[128][72];
    __shared__ __align__(16) short Bs[128][72];
    const int tid = threadIdx.x;
    const int wave = tid >> 6, lane = tid & 63;
    const int lr = lane & 15, lk = (lane >> 4) * 8;
    const int rb = blockIdx.y * 128, cb = blockIdx.x * 128;
    const int wr = (wave >> 1) * 64, wc = (wave & 1) * 64;
    const int seq = 1 << sl, smask = seq - 1;
    f32x4 acc[4][4] = {};
    const int srow = tid >> 3, skc = (tid & 7) * 8;
    for (int k0 = 0; k0 < 512; k0 += 64) {
        #pragma unroll
        for (int it = 0; it < 4; ++it) {
            int row = it * 32 + srow;
            *reinterpret_cast<bf16x8*>(&As[row][skc]) =
                *reinterpret_cast<const bf16x8*>(A + (size_t)(rb + row) * 512 + k0 + skc);
            *reinterpret_cast<bf16x8*>(&Bs[row][skc]) =
                *reinterpret_cast<const bf16x8*>(Wt + (size_t)(cb + row) * 512 + k0 + skc);
        }
        __syncthreads();
        #pragma unroll
        for (int ks = 0; ks < 2; ++ks) {
            bf16x8 af[4], bf_[4];
            #pragma unroll
            for (int mi = 0; mi < 4; ++mi)
                af[mi] = *reinterpret_cast<const bf16x8*>(&As[wr + mi * 16 + lr][ks * 32 + lk]);
            #pragma unroll
            for (int ni = 0; ni < 4; ++ni)
                bf_[ni] = *reinterpret_cast<const bf16x8*>(&Bs[wc + ni * 16 + lr][ks * 32 + lk]);
            #pragma unroll
            for (int mi = 0; mi < 4; ++mi)
                #pragma unroll
                for (int ni = 0; ni < 4; ++ni)
                    acc[mi][ni] = mfma16(af[mi], bf_[ni], acc[mi][ni]);
        }
        __syncthreads();
    }
    #pragma unroll
    for (int mi = 0; mi < 4; ++mi) {
        int m0 = rb + wr + mi * 16 + (lane >> 4) * 4;
        #pragma unroll
        for (int ni = 0; ni < 4; ++ni) {
            int c = cb + wc + ni * 16 + lr;
            int which = c >> 9, h = (c >> 6) & 7, d = c & 63;
            f32x4 v = acc[mi][ni];
            #pragma unroll
            for (int j = 0; j < 4; ++j) {
                int mm = m0 + j;
                int b = mm >> sl, n = mm & smask;
                if (which == 0) {
                    if (qb) qb[(((size_t)b * HH + h) * seq + n) * 64 + d] = f2b(v[j] * 0.125f);
                } else if (which == 1) {
                    if (kb) kb[(((size_t)b * HH + h) * seq + n) * 64 + d] = f2b(v[j]);
                } else {
                    vt[(((size_t)b * HH + h) * 64 + d) * seq + n] = f2b(v[j]);
                }
            }
        }
    }
}

// ---------------------------------------------------------------------------
// Proj GEMM: A bf16 [M,512] @ Wt bf16 [512,512]^T + bscale*bias
// ---------------------------------------------------------------------------
template<bool OUTBF>
__global__ __launch_bounds__(256) void gemm_proj_mfma_k(
    const u16* __restrict__ A, const u16* __restrict__ Wt,
    const float* __restrict__ bias, float bscale, void* __restrict__ outp)
{
    __shared__ __align__(16) short As[128][72];
    __shared__ __align__(16) short Bs[128][72];
    const int tid = threadIdx.x;
    const int wave = tid >> 6, lane = tid & 63;
    const int lr = lane & 15, lk = (lane >> 4) * 8;
    const int rb = blockIdx.y * 128, cb = blockIdx.x * 128;
    const int wr = (wave >> 1) * 64, wc = (wave & 1) * 64;
    f32x4 acc[4][4] = {};
    const int srow = tid >> 3, skc = (tid & 7) * 8;
    for (int k0 = 0; k0 < 512; k0 += 64) {
        #pragma unroll
        for (int it = 0; it < 4; ++it) {
            int row = it * 32 + srow;
            *reinterpret_cast<bf16x8*>(&As[row][skc]) =
                *reinterpret_cast<const bf16x8*>(A + (size_t)(rb + row) * 512 + k0 + skc);
            *reinterpret_cast<bf16x8*>(&Bs[row][skc]) =
                *reinterpret_cast<const bf16x8*>(Wt + (size_t)(cb + row) * 512 + k0 + skc);
        }
        __syncthreads();
        #pragma unroll
        for (int ks = 0; ks < 2; ++ks) {
            bf16x8 af[4], bf_[4];
            #pragma unroll
            for (int mi = 0; mi < 4; ++mi)
                af[mi] = *reinterpret_cast<const bf16x8*>(&As[wr + mi * 16 + lr][ks * 32 + lk]);
            #pragma unroll
            for (int ni = 0; ni < 4; ++ni)
                bf_[ni] = *reinterpret_cast<const bf16x8*>(&Bs[wc + ni * 16 + lr][ks * 32 + lk]);
            #pragma unroll
            for (int mi = 0; mi < 4; ++mi)
                #pragma unroll
                for (int ni = 0; ni < 4; ++ni)
                    acc[mi][ni] = mfma16(af[mi], bf_[ni], acc[mi][ni]);
        }
        __syncthreads();
    }
    #pragma unroll
    for (int mi = 0; mi < 4; ++mi) {
        int m0 = rb + wr + mi * 16 + (lane >> 4) * 4;
        #pragma unroll
        for (int ni = 0; ni < 4; ++ni) {
            int c = cb + wc + ni * 16 + lr;
            float bv = bscale * bias[c];
            f32x4 v = acc[mi][ni];
            #pragma unroll
            for (int j = 0; j < 4; ++j) {
                size_t o = (size_t)(m0 + j) * 512 + c;
                if (OUTBF) reinterpret_cast<u16*>(outp)[o] = f2b(v[j] + bv);
                else       reinterpret_cast<float*>(outp)[o] = v[j] + bv;
            }
        }
    }
}

// ---------------------------------------------------------------------------
// Scores: S[bh,r,c] = Aq[bh,r,:64] . Bk[bh,c,:64] (q pre-scaled), bf16 out
// ---------------------------------------------------------------------------
__global__ __launch_bounds__(256) void scores_mfma_k(
    const u16* __restrict__ Aq, const u16* __restrict__ Bk,
    u16* __restrict__ S, int R, int C)
{
    __shared__ __align__(16) short As[128][72];
    __shared__ __align__(16) short Bs[128][72];
    const int tid = threadIdx.x;
    const int wave = tid >> 6, lane = tid & 63;
    const int lr = lane & 15, lk = (lane >> 4) * 8;
    const int bh = blockIdx.z;
    const int rb = blockIdx.y * 128, cb = blockIdx.x * 128;
    const int wr = (wave >> 1) * 64, wc = (wave & 1) * 64;
    const u16* Ap = Aq + (size_t)bh * R * 64;
    const u16* Bp = Bk + (size_t)bh * C * 64;
    const int srow = tid >> 3, skc = (tid & 7) * 8;
    #pragma unroll
    for (int it = 0; it < 4; ++it) {
        int row = it * 32 + srow;
        *reinterpret_cast<bf16x8*>(&As[row][skc]) =
            *reinterpret_cast<const bf16x8*>(Ap + (size_t)(rb + row) * 64 + skc);
        *reinterpret_cast<bf16x8*>(&Bs[row][skc]) =
            *reinterpret_cast<const bf16x8*>(Bp + (size_t)(cb + row) * 64 + skc);
    }
    __syncthreads();
    f32x4 acc[4][4] = {};
    #pragma unroll
    for (int ks = 0; ks < 2; ++ks) {
        bf16x8 af[4], bf_[4];
        #pragma unroll
        for (int mi = 0; mi < 4; ++mi)
            af[mi] = *reinterpret_cast<const bf16x8*>(&As[wr + mi * 16 + lr][ks * 32 + lk]);
        #pragma unroll
        for (int ni = 0; ni < 4; ++ni)
            bf_[ni] = *reinterpret_cast<const bf16x8*>(&Bs[wc + ni * 16 + lr][ks * 32 + lk]);
        #pragma unroll
        for (int mi = 0; mi < 4; ++mi)
            #pragma unroll
            for (int ni = 0; ni < 4; ++ni)
                acc[mi][ni] = mfma16(af[mi], bf_[ni], acc[mi][ni]);
    }
    #pragma unroll
    for (int mi = 0; mi < 4; ++mi) {
        int r0 = rb + wr + mi * 16 + (lane >> 4) * 4;
        #pragma unroll
        for (int ni = 0; ni < 4; ++ni) {
            int c = cb + wc + ni * 16 + lr;
            f32x4 v = acc[mi][ni];
            #pragma unroll
            for (int j = 0; j < 4; ++j)
                S[((size_t)bh * R + r0 + j) * C + c] = f2b(v[j]);
        }
    }
}

// ---------------------------------------------------------------------------
// PV (wide path): out[b,r,h*64+d] = P[bh,r,:C] @ V[bh,:C,d]; Vt [bh,64,C]
// ---------------------------------------------------------------------------
__global__ __launch_bounds__(256) void pv_mfma_k(
    const u16* __restrict__ P1, const u16* __restrict__ V1t,
    u16* __restrict__ out, int R, int C)
{
    __shared__ __align__(16) short As[64][72];
    __shared__ __align__(16) short Bs[64][72];
    const int tid = threadIdx.x;
    const int wave = tid >> 6, lane = tid & 63;
    const int lr = lane & 15, lg = lane >> 4, lk = lg * 8;
    const int bh = blockIdx.y, b = bh >> 3, h = bh & 7;
    const int rb = blockIdx.x * 64;
    const int wr = wave * 16;
    f32x4 acc[4] = {};
    const u16* Pb = P1 + ((size_t)bh * R + rb) * C;
    const u16* Vb = V1t + (size_t)bh * 64 * C;
    for (int c0 = 0; c0 < C; c0 += 64) {
        #pragma unroll
        for (int it = 0; it < 2; ++it) {
            int chunk = tid + it * 256;
            int r_ = chunk >> 3, c8 = (chunk & 7) * 8;
            *reinterpret_cast<bf16x8*>(&As[r_][c8]) =
                *reinterpret_cast<const bf16x8*>(Pb + (size_t)r_ * C + c0 + c8);
            *reinterpret_cast<bf16x8*>(&Bs[r_][c8]) =
                *reinterpret_cast<const bf16x8*>(Vb + (size_t)r_ * C + c0 + c8);
        }
        __syncthreads();
        #pragma unroll
        for (int ks = 0; ks < 2; ++ks) {
            bf16x8 ap = *reinterpret_cast<const bf16x8*>(&As[wr + lr][ks * 32 + lk]);
            #pragma unroll
            for (int ni = 0; ni < 4; ++ni) {
                bf16x8 bv = *reinterpret_cast<const bf16x8*>(&Bs[ni * 16 + lr][ks * 32 + lk]);
                acc[ni] = mfma16(ap, bv, acc[ni]);
            }
        }
        __syncthreads();
    }
    #pragma unroll
    for (int ni = 0; ni < 4; ++ni) {
        int d = ni * 16 + lr;
        f32x4 v = acc[ni];
        #pragma unroll
        for (int j = 0; j < 4; ++j) {
            int r0 = rb + wr + lg * 4 + j;
            out[((size_t)(b * R + r0)) * 512 + h * 64 + d] = f2b(v[j]);
        }
    }
}

// ---------------------------------------------------------------------------
// Wide softmax over 1024-col rows of S. BIASMODE 1: add bf16 bias row
// (mask folded in). BIASMODE 0: u8 maskT row -> maskval.
// ---------------------------------------------------------------------------
template<int BIASMODE>
__global__ __launch_bounds__(256) void softmax_wide_k(
    u16* __restrict__ S, const u16* __restrict__ bias,
    const unsigned char* __restrict__ maskT, float maskval)
{
    const int row_g = blockIdx.x;
    const int tid = threadIdx.x;
    const int wave = tid >> 6, lane = tid & 63;
    const int c = tid * 4;
    u16* rowp = S + (size_t)row_g * 1024;
    ushort4 sv = *reinterpret_cast<const ushort4*>(rowp + c);
    float s[4] = { b2f(sv.x), b2f(sv.y), b2f(sv.z), b2f(sv.w) };
    if (BIASMODE) {
        ushort4 bv = *reinterpret_cast<const ushort4*>(bias + (size_t)row_g * 1024 + c);
        s[0] += b2f(bv.x); s[1] += b2f(bv.y); s[2] += b2f(bv.z); s[3] += b2f(bv.w);
    } else {
        uchar4 mk = *reinterpret_cast<const uchar4*>(maskT + (size_t)row_g * 1024 + c);
        if (mk.x) s[0] = maskval; if (mk.y) s[1] = maskval;
        if (mk.z) s[2] = maskval; if (mk.w) s[3] = maskval;
    }
    __shared__ float swv[4];
    float lm = fmaxf(fmaxf(s[0], s[1]), fmaxf(s[2], s[3]));
    lm = wred_max(lm);
    if (lane == 0) swv[wave] = lm;
    __syncthreads();
    float m = fmaxf(fmaxf(swv[0], swv[1]), fmaxf(swv[2], swv[3]));
    __syncthreads();
    float ls = 0.0f;
    #pragma unroll
    for (int j = 0; j < 4; ++j) { s[j] = __expf(s[j] - m); ls += s[j]; }
    ls = wred_sum(ls);
    if (lane == 0) swv[wave] = ls;
    __syncthreads();
    float inv = 1.0f / (swv[0] + swv[1] + swv[2] + swv[3]);
    ushort4 ov = { f2b(s[0] * inv), f2b(s[1] * inv), f2b(s[2] * inv), f2b(s[3] * inv) };
    *reinterpret_cast<ushort4*>(rowp + c) = ov;
}

// ---------------------------------------------------------------------------
// Fused attention, R=1024 x-rows, C=256 k-cols; bias bf16 [bh,x,k] per src
// (mask folded into bias). scores -> +bias -> softmax -> PV.
// Bias staged in LDS (overwrites K after scores; P overwrites bias).
// ---------------------------------------------------------------------------
template<int NSRC>
__global__ __launch_bounds__(512) void attn_xk_fused_k(
    const u16* __restrict__ Qp,
    const u16* __restrict__ K1, const u16* __restrict__ V1t, const u16* __restrict__ B1,
    const u16* __restrict__ K2, const u16* __restrict__ V2t, const u16* __restrict__ B2,
    u16* __restrict__ outm)
{
    const int tid = threadIdx.x;
    const int w = tid >> 6, lane = tid & 63;
    const int lr = lane & 15, lg = lane >> 4;
    const int lk = lg * 8;
    const int bh = blockIdx.y, b = bh >> 3, h = bh & 7;
    const int rb = blockIdx.x * 128;
    const int wrow = (w >> 2) * 64, wcol = (w & 3) * 64;   // scores tiling
    const int wrow2 = w * 16;                               // pv tiling
    const int wcg = w & 3;

    __shared__ __align__(16) char lds[18432 + 67584 + 33792 + 2048];
    short* Qs = (short*)lds;                       // [128][72]
    short* KP = (short*)(lds + 18432);             // K [256][72] | bias/P [128][264]
    short* Vsl = (short*)(lds + 18432 + 67584);    // [64][264]
    float* red = (float*)(lds + 18432 + 67584 + 33792); // [128][4]

    // stage Q tile [128][64]
    {
        const u16* Qb = Qp + ((size_t)bh * 1024 + rb) * 64;
        #pragma unroll
        for (int it = 0; it < 2; ++it) {
            int chunk = tid + it * 512;
            int r_ = chunk >> 3, c8 = (chunk & 7) * 8;
            *reinterpret_cast<bf16x8*>(&Qs[r_ * 72 + c8]) =
                *reinterpret_cast<const bf16x8*>(Qb + (size_t)r_ * 64 + c8);
        }
    }

    f32x4 acc2[4] = {};   // PV accumulator

    #pragma unroll
    for (int s = 0; s < NSRC; ++s) {
        const u16* Kp = (s == 0) ? K1 : K2;
        const u16* Vp = (s == 0) ? V1t : V2t;
        const u16* Bp = (s == 0) ? B1 : B2;
        __syncthreads();   // Q staged / prev PV done
        // stage K [256][64] and V [64][256]
        #pragma unroll
        for (int it = 0; it < 4; ++it) {
            int chunk = tid + it * 512;
            int r_ = chunk >> 3, c8 = (chunk & 7) * 8;
            *reinterpret_cast<bf16x8*>(&KP[r_ * 72 + c8]) =
                *reinterpret_cast<const bf16x8*>(Kp + ((size_t)bh * 256 + r_) * 64 + c8);
            int vd = chunk >> 5, vc8 = (chunk & 31) * 8;
            *reinterpret_cast<bf16x8*>(&Vsl[vd * 264 + vc8]) =
                *reinterpret_cast<const bf16x8*>(Vp + ((size_t)bh * 64 + vd) * 256 + vc8);
        }
        __syncthreads();
        // scores: 64x64 per wave, K=64 (q pre-scaled)
        f32x4 acc[4][4] = {};
        #pragma unroll
        for (int ks = 0; ks < 2; ++ks) {
            bf16x8 af[4], bfv[4];
            #pragma unroll
            for (int mi = 0; mi < 4; ++mi)
                af[mi] = *reinterpret_cast<const bf16x8*>(&Qs[(wrow + mi * 16 + lr) * 72 + ks * 32 + lk]);
            #pragma unroll
            for (int ni = 0; ni < 4; ++ni)
                bfv[ni] = *reinterpret_cast<const bf16x8*>(&KP[(wcol + ni * 16 + lr) * 72 + ks * 32 + lk]);
            #pragma unroll
            for (int mi = 0; mi < 4; ++mi)
                #pragma unroll
                for (int ni = 0; ni < 4; ++ni)
                    acc[mi][ni] = mfma16(af[mi], bfv[ni], acc[mi][ni]);
        }
        __syncthreads();   // K fully consumed -> overwrite with bias
        // stage bias tile [128][256] into BP (stride 264), coalesced
        #pragma unroll
        for (int it = 0; it < 8; ++it) {
            int chunk = tid + it * 512;
            int row = chunk >> 5, c8 = (chunk & 31) * 8;
            *reinterpret_cast<bf16x8*>(&KP[row * 264 + c8]) =
                *reinterpret_cast<const bf16x8*>(Bp + ((size_t)bh * 1024 + rb + row) * 256 + c8);
        }
        __syncthreads();
        // apply bias from LDS
        #pragma unroll
        for (int ni = 0; ni < 4; ++ni) {
            const int cK = wcol + ni * 16 + lr;
            #pragma unroll
            for (int mi = 0; mi < 4; ++mi) {
                #pragma unroll
                for (int j = 0; j < 4; ++j) {
                    const int rloc = wrow + mi * 16 + lg * 4 + j;
                    acc[mi][ni][j] += b2f((u16)KP[rloc * 264 + cK]);
                }
            }
        }
        // row max (cross 16 lanes, then cross 4 col-waves via LDS)
        float rmax[4][4];
        #pragma unroll
        for (int mi = 0; mi < 4; ++mi)
            #pragma unroll
            for (int j = 0; j < 4; ++j) {
                float v = fmaxf(fmaxf(acc[mi][0][j], acc[mi][1][j]),
                                fmaxf(acc[mi][2][j], acc[mi][3][j]));
                #pragma unroll
                for (int o = 1; o < 16; o <<= 1) v = fmaxf(v, __shfl_xor(v, o, 64));
                rmax[mi][j] = v;
            }
        if (lr == 0) {
            #pragma unroll
            for (int mi = 0; mi < 4; ++mi)
                #pragma unroll
                for (int j = 0; j < 4; ++j)
                    red[(wrow + mi * 16 + lg * 4 + j) * 4 + wcg] = rmax[mi][j];
        }
        __syncthreads();
        float rowm[4][4];
        #pragma unroll
        for (int mi = 0; mi < 4; ++mi)
            #pragma unroll
            for (int j = 0; j < 4; ++j) {
                f32x4 r4 = *reinterpret_cast<f32x4*>(&red[(wrow + mi * 16 + lg * 4 + j) * 4]);
                rowm[mi][j] = fmaxf(fmaxf(r4[0], r4[1]), fmaxf(r4[2], r4[3]));
            }
        __syncthreads();   // max reads done before sum writes
        // exp + row sum
        float rsum[4][4];
        #pragma unroll
        for (int mi = 0; mi < 4; ++mi)
            #pragma unroll
            for (int j = 0; j < 4; ++j) {
                float m_ = rowm[mi][j];
                float e0 = __expf(acc[mi][0][j] - m_);
                float e1 = __expf(acc[mi][1][j] - m_);
                float e2 = __expf(acc[mi][2][j] - m_);
                float e3 = __expf(acc[mi][3][j] - m_);
                acc[mi][0][j] = e0; acc[mi][1][j] = e1;
                acc[mi][2][j] = e2; acc[mi][3][j] = e3;
                float v = (e0 + e1) + (e2 + e3);
                #pragma unroll
                for (int o = 1; o < 16; o <<= 1) v += __shfl_xor(v, o, 64);
                rsum[mi][j] = v;
            }
        if (lr == 0) {
            #pragma unroll
            for (int mi = 0; mi < 4; ++mi)
                #pragma unroll
                for (int j = 0; j < 4; ++j)
                    red[(wrow + mi * 16 + lg * 4 + j) * 4 + wcg] = rsum[mi][j];
        }
        __syncthreads();
        // normalize + write P over bias region (thread-local positions)
        #pragma unroll
        for (int mi = 0; mi < 4; ++mi)
            #pragma unroll
            for (int j = 0; j < 4; ++j) {
                f32x4 r4 = *reinterpret_cast<f32x4*>(&red[(wrow + mi * 16 + lg * 4 + j) * 4]);
                float inv = 1.0f / (((r4[0] + r4[1]) + (r4[2] + r4[3])));
                int rloc = wrow + mi * 16 + lg * 4 + j;
                #pragma unroll
                for (int ni = 0; ni < 4; ++ni)
                    KP[rloc * 264 + wcol + ni * 16 + lr] = (short)f2b(acc[mi][ni][j] * inv);
            }
        __syncthreads();
        // PV: 16 rows per wave, N=64, K=256
        #pragma unroll
        for (int kc = 0; kc < 8; ++kc) {
            bf16x8 ap = *reinterpret_cast<const bf16x8*>(&KP[(wrow2 + lr) * 264 + kc * 32 + lk]);
            #pragma unroll
            for (int ni = 0; ni < 4; ++ni) {
                bf16x8 vv = *reinterpret_cast<const bf16x8*>(&Vsl[(ni * 16 + lr) * 264 + kc * 32 + lk]);
                acc2[ni] = mfma16(ap, vv, acc2[ni]);
            }
        }
    }
    // epilogue: merged bf16 out [b, x, 512]
    #pragma unroll
    for (int ni = 0; ni < 4; ++ni) {
        int d = ni * 16 + lr;
        f32x4 v = acc2[ni];
        #pragma unroll
        for (int j = 0; j < 4; ++j) {
            int row = rb + wrow2 + lg * 4 + j;
            outm[((size_t)(b * 1024 + row)) * 512 + h * 64 + d] = f2b(v[j]);
        }
    }
}

// ---------------------------------------------------------------------------
extern "C" void kernel_launch(void* const* d_in, const int* in_sizes, int n_in,
                              void* d_out, int out_size, void* d_ws, size_t ws_size,
                              hipStream_t stream)
{
    const float* x        = (const float*)d_in[0];
    const float* kernal   = (const float*)d_in[1];
    const float* i_x      = (const float*)d_in[2];
    const float* i_kernal = (const float*)d_in[3];
    const int*   rd       = (const int*)d_in[4];
    const int*   polar    = (const int*)d_in[5];
    const int*   att      = (const int*)d_in[6];
    const int*   i_att    = (const int*)d_in[7];
    const int*   cross    = (const int*)d_in[8];
    const float* Wqkv     = (const float*)d_in[9];
    const float* Wqkv_i   = (const float*)d_in[10];
    const float* Wqkv_i2  = (const float*)d_in[11];
    const float* Wproj    = (const float*)d_in[12];
    const float* bproj    = (const float*)d_in[13];
    const float* Wproj_i  = (const float*)d_in[14];
    const float* bproj_i  = (const float*)d_in[15];
    const float* Wproj_i2 = (const float*)d_in[16];
    const float* bproj_i2 = (const float*)d_in[17];
    const float* dis      = (const float*)d_in[18];
    const float* pemb     = (const float*)d_in[19];

    float* out = (float*)d_out;
    float* x_out   = out;
    float* k_out   = out + (size_t)BB * XLL * DIMM;
    float* i_x_out = k_out + (size_t)BB * KLL * DIMM;

    char* ws = (char*)d_ws;
    size_t off = 0;
    auto alloc = [&](size_t bytes) { void* p = ws + off; off += (bytes + 255) & ~(size_t)255; return p; };

    const size_t NAX = (size_t)BB * XLL * DIMM;
    const size_t NAK = (size_t)BB * KLL * DIMM;
    const size_t NHX = (size_t)BHH * XLL * HEADD;
    const size_t NHK = (size_t)BHH * KLL * HEADD;
    const size_t NS  = (size_t)BHH * KLL * XLL;

    u16* WqkvT     = (u16*)alloc((size_t)1536 * 512 * 2);
    u16* WqkvIT    = (u16*)alloc((size_t)1536 * 512 * 2);
    u16* WqkvI2T   = (u16*)alloc((size_t)1536 * 512 * 2);
    u16* WprojT    = (u16*)alloc((size_t)512 * 512 * 2);
    u16* WprojIT   = (u16*)alloc((size_t)512 * 512 * 2);
    u16* WprojI2T  = (u16*)alloc((size_t)512 * 512 * 2);
    u16* Abf  = (u16*)alloc(NAX * 2);
    u16* Q    = (u16*)alloc(NHX * 2);
    u16* KX   = (u16*)alloc(NHX * 2);
    u16* VXt  = (u16*)alloc(NHX * 2);
    u16* KQ   = (u16*)alloc(NHK * 2);
    u16* KK   = (u16*)alloc(NHK * 2);
    u16* KVt  = (u16*)alloc(NHK * 2);
    u16* IQ   = (u16*)alloc(NHX * 2);
    u16* IK   = (u16*)alloc(NHX * 2);
    u16* IVt  = (u16*)alloc(NHX * 2);
    u16* IKQ  = (u16*)alloc(NHK * 2);
    u16* IKK  = (u16*)alloc(NHK * 2);
    u16* IKVt = (u16*)alloc(NHK * 2);
    u16* K2K  = (u16*)alloc(NHK * 2);
    u16* K2Vt = (u16*)alloc(NHK * 2);
    u16* SPa  = (u16*)alloc(NS * 2);      // S (branches 1,3) / crossBias (branch 2 src1)
    u16* KMb  = (u16*)alloc(NAK * 2);
    u16* XMb  = (u16*)alloc(NAX * 2);
    u16* IKOUTb = (u16*)alloc(NAK * 2);
    u16* biasT = (u16*)alloc(NS * 2);     // branch2 bias / later iattBias
    u16* bias1 = (u16*)alloc(NS * 2);     // branch1 bias [bh,k,x]
    unsigned char* iattT8 = (unsigned char*)alloc(NS);
    int* MO   = (int*)alloc((size_t)BHH * KLL * 4);

    u16* crossB = SPa;     // alias: crossBias lives in SPa between pv1 and fused2
    u16* iattB  = biasT;   // alias: iattBias lives in biasT after fused2

    dim3 blk(256);

    // weight transposes
    transpose_cast_k<<<dim3(48, 16), blk, 0, stream>>>(Wqkv,     WqkvT,   512, 1536);
    transpose_cast_k<<<dim3(48, 16), blk, 0, stream>>>(Wqkv_i,   WqkvIT,  512, 1536);
    transpose_cast_k<<<dim3(48, 16), blk, 0, stream>>>(Wqkv_i2,  WqkvI2T, 512, 1536);
    transpose_cast_k<<<dim3(16, 16), blk, 0, stream>>>(Wproj,    WprojT,  512, 512);
    transpose_cast_k<<<dim3(16, 16), blk, 0, stream>>>(Wproj_i,  WprojIT, 512, 512);
    transpose_cast_k<<<dim3(16, 16), blk, 0, stream>>>(Wproj_i2, WprojI2T,512, 512);

    // QKV projections (q pre-scaled by 0.125)
    cast_bf16_k<<<dim3(1024), blk, 0, stream>>>(x, Abf, (int)(NAX / 8));
    gemm_qkv_mfma_k<<<dim3(12, 32), blk, 0, stream>>>(Abf, WqkvT, Q, KX, VXt, 10);
    cast_bf16_k<<<dim3(256), blk, 0, stream>>>(kernal, Abf, (int)(NAK / 8));
    gemm_qkv_mfma_k<<<dim3(12, 8), blk, 0, stream>>>(Abf, WqkvT, KQ, KK, KVt, 8);
    cast_bf16_k<<<dim3(1024), blk, 0, stream>>>(i_x, Abf, (int)(NAX / 8));
    gemm_qkv_mfma_k<<<dim3(12, 32), blk, 0, stream>>>(Abf, WqkvIT, IQ, IK, IVt, 10);
    cast_bf16_k<<<dim3(256), blk, 0, stream>>>(i_kernal, Abf, (int)(NAK / 8));
    gemm_qkv_mfma_k<<<dim3(12, 8), blk, 0, stream>>>(Abf, WqkvIT, IKQ, IKK, IKVt, 8);

    // --- branch 1: k_out ---
    scores_mfma_k<<<dim3(8, 2, BHH), blk, 0, stream>>>(KQ, KX, SPa, KLL, XLL);
    main_ori_k8<<<dim3(BB * KLL), blk, 0, stream>>>(SPa, polar, MO);
    bias_build_k<<<dim3(32, 8, BB), blk, 0, stream>>>(rd, polar, att, dis, pemb, MO, biasT, bias1);
    softmax_wide_k<1><<<dim3(BHH * KLL), blk, 0, stream>>>(SPa, bias1, nullptr, 0.0f);
    pv_mfma_k<<<dim3(4, BHH), blk, 0, stream>>>(SPa, VXt, KMb, KLL, XLL);
    gemm_proj_mfma_k<false><<<dim3(4, 8), blk, 0, stream>>>(KMb, WprojT, bproj, 1.0f, k_out);

    // --- branch 2: x_out (fused dual attention; crossBias into SPa alias) ---
    mask_bias_k<<<dim3(8192), blk, 0, stream>>>(cross, crossB, (int)(NS / 4));
    attn_xk_fused_k<2><<<dim3(8, BHH), dim3(512), 0, stream>>>(
        Q, KK, KVt, biasT, IKK, IKVt, crossB, XMb);
    gemm_proj_mfma_k<false><<<dim3(4, 32), blk, 0, stream>>>(XMb, WprojT, bproj, 2.0f, x_out);

    // --- branch 3: i_x_out (iatt conversions into biasT alias after fused2) ---
    conv_iatt_k<<<dim3(32, 8, BHH), blk, 0, stream>>>(i_att, iattT8, iattB);
    scores_mfma_k<<<dim3(8, 2, BHH), blk, 0, stream>>>(IKQ, IK, SPa, KLL, XLL);
    softmax_wide_k<0><<<dim3(BHH * KLL), blk, 0, stream>>>(SPa, nullptr, iattT8, -1e9f);
    pv_mfma_k<<<dim3(4, BHH), blk, 0, stream>>>(SPa, IVt, KMb, KLL, XLL);
    gemm_proj_mfma_k<true><<<dim3(4, 8), blk, 0, stream>>>(KMb, WprojIT, bproj_i, 1.0f, IKOUTb);
    gemm_qkv_mfma_k<<<dim3(12, 8), blk, 0, stream>>>(IKOUTb, WqkvI2T, nullptr, K2K, K2Vt, 8);
    attn_xk_fused_k<1><<<dim3(8, BHH), dim3(512), 0, stream>>>(
        IQ, K2K, K2Vt, iattB, nullptr, nullptr, nullptr, XMb);
    gemm_proj_mfma_k<false><<<dim3(4, 32), blk, 0, stream>>>(XMb, WprojI2T, bproj_i2, 1.0f, i_x_out);

    (void)in_sizes; (void)n_in; (void)out_size; (void)ws_size;
}

// Round 6
// 467.384 us; speedup vs baseline: 1.0529x; 1.0165x over previous
//
#include <hip/hip_runtime.h>
#include <cstddef>
#include <cstdint>

#define BB 4
#define HH 8
#define HEADD 64
#define DIMM 512
#define XLL 1024
#define KLL 256
#define BHH (BB*HH)

typedef __attribute__((ext_vector_type(8))) short bf16x8;
typedef __attribute__((ext_vector_type(8))) unsigned short u16x8;
typedef __attribute__((ext_vector_type(4))) float f32x4;
typedef unsigned short u16;

__device__ __forceinline__ u16 f2b(float f) {
    unsigned int u = __builtin_bit_cast(unsigned int, f);
    u = u + 0x7fffu + ((u >> 16) & 1u);
    return (u16)(u >> 16);
}
__device__ __forceinline__ float b2f(u16 h) {
    unsigned int u = ((unsigned int)h) << 16;
    return __builtin_bit_cast(float, u);
}
__device__ __forceinline__ f32x4 mfma16(bf16x8 a, bf16x8 b, f32x4 c) {
    return __builtin_amdgcn_mfma_f32_16x16x32_bf16(a, b, c, 0, 0, 0);
}
__device__ __forceinline__ float wred_max(float v) {
    #pragma unroll
    for (int o = 1; o < 64; o <<= 1) v = fmaxf(v, __shfl_xor(v, o, 64));
    return v;
}
__device__ __forceinline__ float wred_sum(float v) {
    #pragma unroll
    for (int o = 1; o < 64; o <<= 1) v += __shfl_xor(v, o, 64);
    return v;
}

// ---------------------------------------------------------------------------
// f32 -> bf16 cast, 8 elems/thread
// ---------------------------------------------------------------------------
__global__ __launch_bounds__(256) void cast_bf16_k(
    const float* __restrict__ in, u16* __restrict__ out, int n8)
{
    int i = blockIdx.x * 256 + threadIdx.x;
    if (i >= n8) return;
    const float4* p = reinterpret_cast<const float4*>(in) + (size_t)i * 2;
    float4 a = p[0], b = p[1];
    u16x8 o;
    o[0] = f2b(a.x); o[1] = f2b(a.y); o[2] = f2b(a.z); o[3] = f2b(a.w);
    o[4] = f2b(b.x); o[5] = f2b(b.y); o[6] = f2b(b.z); o[7] = f2b(b.w);
    *reinterpret_cast<u16x8*>(out + (size_t)i * 8) = o;
}

// ---------------------------------------------------------------------------
// W [K][N] f32  ->  Wt [N][K] bf16
// ---------------------------------------------------------------------------
__global__ __launch_bounds__(256) void transpose_cast_k(
    const float* __restrict__ W, u16* __restrict__ Wt, int K, int N)
{
    __shared__ float t[32][33];
    int bx = blockIdx.x, by = blockIdx.y;
    int tx = threadIdx.x & 31, ty = threadIdx.x >> 5;
    #pragma unroll
    for (int r = ty; r < 32; r += 8)
        t[r][tx] = W[(size_t)(by * 32 + r) * N + bx * 32 + tx];
    __syncthreads();
    #pragma unroll
    for (int r = ty; r < 32; r += 8)
        Wt[(size_t)(bx * 32 + r) * K + by * 32 + tx] = f2b(t[tx][r]);
}

// ---------------------------------------------------------------------------
// i_att int32 [bh,x,k] -> iattT8 u8 [bh,k,x]  AND  iattBias bf16 [bh,x,k]
// ---------------------------------------------------------------------------
__global__ __launch_bounds__(256) void conv_iatt_k(
    const int* __restrict__ m, unsigned char* __restrict__ mt,
    u16* __restrict__ mb)
{
    __shared__ unsigned char t[32][33];
    const int bh = blockIdx.z, xt = blockIdx.x, kt = blockIdx.y;
    const int tx = threadIdx.x & 31, ty = threadIdx.x >> 5;
    const u16 NEG = f2b(-1e9f);
    #pragma unroll
    for (int r = ty; r < 32; r += 8) {
        size_t idx = ((size_t)bh * 1024 + xt * 32 + r) * 256 + kt * 32 + tx;
        unsigned char v = (unsigned char)(m[idx] != 0);
        t[r][tx] = v;
        mb[idx] = v ? NEG : (u16)0;
    }
    __syncthreads();
    #pragma unroll
    for (int r = ty; r < 32; r += 8)
        mt[((size_t)bh * 256 + kt * 32 + r) * 1024 + xt * 32 + tx] = t[tx][r];
}

// ---------------------------------------------------------------------------
// mask int32 -> bf16 bias (0 / -1e9), same layout, 4 elems/thread
// ---------------------------------------------------------------------------
__global__ __launch_bounds__(256) void mask_bias_k(
    const int* __restrict__ m, u16* __restrict__ o, int n4)
{
    int i = blockIdx.x * 256 + threadIdx.x;
    if (i >= n4) return;
    int4 v = reinterpret_cast<const int4*>(m)[i];
    const u16 NEG = f2b(-1e9f);
    ushort4 u;
    u.x = v.x ? NEG : (u16)0; u.y = v.y ? NEG : (u16)0;
    u.z = v.z ? NEG : (u16)0; u.w = v.w ? NEG : (u16)0;
    reinterpret_cast<ushort4*>(o)[i] = u;
}

// ---------------------------------------------------------------------------
// main orientation: block per (b,k); reads polar row once, loops 8 heads.
// ---------------------------------------------------------------------------
__global__ __launch_bounds__(256) void main_ori_k8(
    const u16* __restrict__ S, const int* __restrict__ polar,
    int* __restrict__ MO)
{
    const int blk = blockIdx.x;          // b*256 + k
    const int b = blk >> 8, k = blk & 255;
    const int tid = threadIdx.x;
    const int wave = tid >> 6, lane = tid & 63;
    const int c = tid * 4;
    int4 p4 = *reinterpret_cast<const int4*>(polar + ((size_t)b * 256 + k) * 1024 + c);
    int pp[4] = { p4.x, p4.y, p4.z, p4.w };
    #pragma unroll
    for (int j = 0; j < 4; ++j) { int p = pp[j]; pp[j] = p < 0 ? 0 : (p > 7 ? 7 : p); }
    __shared__ float sred[4][8];
    for (int h = 0; h < 8; ++h) {
        const int bh = b * 8 + h;
        ushort4 sv = *reinterpret_cast<const ushort4*>(S + ((size_t)bh * 256 + k) * 1024 + c);
        float av[4] = { fabsf(b2f(sv.x)), fabsf(b2f(sv.y)), fabsf(b2f(sv.z)), fabsf(b2f(sv.w)) };
        float bins[8] = {};
        #pragma unroll
        for (int j = 0; j < 4; ++j) {
            #pragma unroll
            for (int o = 0; o < 8; ++o) bins[o] += (pp[j] == o) ? av[j] : 0.0f;
        }
        #pragma unroll
        for (int o = 0; o < 8; ++o) bins[o] = wred_sum(bins[o]);
        if (lane == 0) {
            #pragma unroll
            for (int o = 0; o < 8; ++o) sred[wave][o] = bins[o];
        }
        __syncthreads();
        if (tid == 0) {
            int best = 0; float bv = -1.0f;
            #pragma unroll
            for (int o = 0; o < 8; ++o) {
                float s = sred[0][o] + sred[1][o] + sred[2][o] + sred[3][o];
                if (s > bv) { bv = s; best = o; }
            }
            MO[bh * 256 + k] = best;
        }
        __syncthreads();
    }
}

// ---------------------------------------------------------------------------
// Combined bias build (after MO): per (b, x-tile32, k-tile32), all 8 heads:
//   v = dis[rd]+pemb[(polar-MO)&7]
//   biasT[bh,x,k] = att ? -1e9 : v   (branch 2)
//   bias1[bh,k,x] = att ? -1e6 : v   (branch 1)
// ---------------------------------------------------------------------------
__global__ __launch_bounds__(256) void bias_build_k(
    const int* __restrict__ rd, const int* __restrict__ polar,
    const int* __restrict__ att, const float* __restrict__ dis,
    const float* __restrict__ pemb, const int* __restrict__ MO,
    u16* __restrict__ biasT, u16* __restrict__ bias1)
{
    const int b = blockIdx.z;
    const int xt = blockIdx.x * 32, kt = blockIdx.y * 32;
    const int tid = threadIdx.x;
    __shared__ float dsh[528];
    __shared__ int rds[32][33];   // [x][k]
    __shared__ int pls[32][33];
    __shared__ u16 bt[32][33];    // bias (−1e6 variant) tile [x][k]
    for (int i = tid; i < 528; i += 256) dsh[i] = dis[i];
    const int tx = tid & 31, ty = tid >> 5;
    #pragma unroll
    for (int r = ty; r < 32; r += 8) {
        size_t src = ((size_t)b * 256 + kt + r) * 1024 + xt + tx;  // rd[b,k,x]
        rds[tx][r] = rd[src];
        int p = polar[src]; pls[tx][r] = p < 0 ? 0 : (p > 7 ? 7 : p);
    }
    float pe[8];
    #pragma unroll
    for (int o = 0; o < 8; ++o) pe[o] = pemb[o];
    __syncthreads();
    const int x = tid >> 3, k4 = (tid & 7) * 4;
    const u16 NEG9 = f2b(-1e9f), NEG6 = f2b(-1e6f);
    for (int h = 0; h < 8; ++h) {
        const int bh = b * 8 + h;
        size_t oidx = ((size_t)bh * 1024 + xt + x) * 256 + kt + k4;
        int4 m4 = *reinterpret_cast<const int4*>(att + oidx);
        int4 mo4 = *reinterpret_cast<const int4*>(MO + bh * 256 + kt + k4);
        int mm[4] = { m4.x, m4.y, m4.z, m4.w };
        int mo[4] = { mo4.x, mo4.y, mo4.z, mo4.w };
        u16 o_[4];
        #pragma unroll
        for (int j = 0; j < 4; ++j) {
            float v = dsh[rds[x][k4 + j] * 8 + h] + pe[(pls[x][k4 + j] - mo[j] + 8) & 7];
            u16 vb = f2b(v);
            o_[j] = mm[j] ? NEG9 : vb;
            bt[x][k4 + j] = mm[j] ? NEG6 : vb;
        }
        ushort4 ov; ov.x = o_[0]; ov.y = o_[1]; ov.z = o_[2]; ov.w = o_[3];
        *reinterpret_cast<ushort4*>(biasT + oidx) = ov;
        __syncthreads();
        const int k_ = tid >> 3, x4 = (tid & 7) * 4;
        ushort4 o2;
        o2.x = bt[x4 + 0][k_]; o2.y = bt[x4 + 1][k_];
        o2.z = bt[x4 + 2][k_]; o2.w = bt[x4 + 3][k_];
        *reinterpret_cast<ushort4*>(bias1 + ((size_t)bh * 256 + kt + k_) * 1024 + xt + x4) = o2;
        __syncthreads();
    }
}

// ---------------------------------------------------------------------------
// QKV GEMM: A bf16 [M,512] @ Wt bf16 [1536,512]^T; q pre-scaled by 0.125.
// q,k -> [b,h,n,64] bf16; v -> [b,h,64,n] bf16 (transposed)
// ---------------------------------------------------------------------------
__global__ __launch_bounds__(256) void gemm_qkv_mfma_k(
    const u16* __restrict__ A, const u16* __restrict__ Wt,
    u16* __restrict__ qb, u16* __restrict__ kb, u16* __restrict__ vt,
    int sl)
{
    __shared__ __align__(16) short As[128][72];
    __shared__ __align__(16) short Bs[128][72];
    const int tid = threadIdx.x;
    const int wave = tid >> 6, lane = tid & 63;
    const int lr = lane & 15, lk = (lane >> 4) * 8;
    const int rb = blockIdx.y * 128, cb = blockIdx.x * 128;
    const int wr = (wave >> 1) * 64, wc = (wave & 1) * 64;
    const int seq = 1 << sl, smask = seq - 1;
    f32x4 acc[4][4] = {};
    const int srow = tid >> 3, skc = (tid & 7) * 8;
    for (int k0 = 0; k0 < 512; k0 += 64) {
        #pragma unroll
        for (int it = 0; it < 4; ++it) {
            int row = it * 32 + srow;
            *reinterpret_cast<bf16x8*>(&As[row][skc]) =
                *reinterpret_cast<const bf16x8*>(A + (size_t)(rb + row) * 512 + k0 + skc);
            *reinterpret_cast<bf16x8*>(&Bs[row][skc]) =
                *reinterpret_cast<const bf16x8*>(Wt + (size_t)(cb + row) * 512 + k0 + skc);
        }
        __syncthreads();
        #pragma unroll
        for (int ks = 0; ks < 2; ++ks) {
            bf16x8 af[4], bf_[4];
            #pragma unroll
            for (int mi = 0; mi < 4; ++mi)
                af[mi] = *reinterpret_cast<const bf16x8*>(&As[wr + mi * 16 + lr][ks * 32 + lk]);
            #pragma unroll
            for (int ni = 0; ni < 4; ++ni)
                bf_[ni] = *reinterpret_cast<const bf16x8*>(&Bs[wc + ni * 16 + lr][ks * 32 + lk]);
            #pragma unroll
            for (int mi = 0; mi < 4; ++mi)
                #pragma unroll
                for (int ni = 0; ni < 4; ++ni)
                    acc[mi][ni] = mfma16(af[mi], bf_[ni], acc[mi][ni]);
        }
        __syncthreads();
    }
    #pragma unroll
    for (int mi = 0; mi < 4; ++mi) {
        int m0 = rb + wr + mi * 16 + (lane >> 4) * 4;
        #pragma unroll
        for (int ni = 0; ni < 4; ++ni) {
            int c = cb + wc + ni * 16 + lr;
            int which = c >> 9, h = (c >> 6) & 7, d = c & 63;
            f32x4 v = acc[mi][ni];
            #pragma unroll
            for (int j = 0; j < 4; ++j) {
                int mm = m0 + j;
                int b = mm >> sl, n = mm & smask;
                if (which == 0) {
                    if (qb) qb[(((size_t)b * HH + h) * seq + n) * 64 + d] = f2b(v[j] * 0.125f);
                } else if (which == 1) {
                    if (kb) kb[(((size_t)b * HH + h) * seq + n) * 64 + d] = f2b(v[j]);
                } else {
                    vt[(((size_t)b * HH + h) * 64 + d) * seq + n] = f2b(v[j]);
                }
            }
        }
    }
}

// ---------------------------------------------------------------------------
// Proj GEMM: A bf16 [M,512] @ Wt bf16 [512,512]^T + bscale*bias
// ---------------------------------------------------------------------------
template<bool OUTBF>
__global__ __launch_bounds__(256) void gemm_proj_mfma_k(
    const u16* __restrict__ A, const u16* __restrict__ Wt,
    const float* __restrict__ bias, float bscale, void* __restrict__ outp)
{
    __shared__ __align__(16) short As[128][72];
    __shared__ __align__(16) short Bs[128][72];
    const int tid = threadIdx.x;
    const int wave = tid >> 6, lane = tid & 63;
    const int lr = lane & 15, lk = (lane >> 4) * 8;
    const int rb = blockIdx.y * 128, cb = blockIdx.x * 128;
    const int wr = (wave >> 1) * 64, wc = (wave & 1) * 64;
    f32x4 acc[4][4] = {};
    const int srow = tid >> 3, skc = (tid & 7) * 8;
    for (int k0 = 0; k0 < 512; k0 += 64) {
        #pragma unroll
        for (int it = 0; it < 4; ++it) {
            int row = it * 32 + srow;
            *reinterpret_cast<bf16x8*>(&As[row][skc]) =
                *reinterpret_cast<const bf16x8*>(A + (size_t)(rb + row) * 512 + k0 + skc);
            *reinterpret_cast<bf16x8*>(&Bs[row][skc]) =
                *reinterpret_cast<const bf16x8*>(Wt + (size_t)(cb + row) * 512 + k0 + skc);
        }
        __syncthreads();
        #pragma unroll
        for (int ks = 0; ks < 2; ++ks) {
            bf16x8 af[4], bf_[4];
            #pragma unroll
            for (int mi = 0; mi < 4; ++mi)
                af[mi] = *reinterpret_cast<const bf16x8*>(&As[wr + mi * 16 + lr][ks * 32 + lk]);
            #pragma unroll
            for (int ni = 0; ni < 4; ++ni)
                bf_[ni] = *reinterpret_cast<const bf16x8*>(&Bs[wc + ni * 16 + lr][ks * 32 + lk]);
            #pragma unroll
            for (int mi = 0; mi < 4; ++mi)
                #pragma unroll
                for (int ni = 0; ni < 4; ++ni)
                    acc[mi][ni] = mfma16(af[mi], bf_[ni], acc[mi][ni]);
        }
        __syncthreads();
    }
    #pragma unroll
    for (int mi = 0; mi < 4; ++mi) {
        int m0 = rb + wr + mi * 16 + (lane >> 4) * 4;
        #pragma unroll
        for (int ni = 0; ni < 4; ++ni) {
            int c = cb + wc + ni * 16 + lr;
            float bv = bscale * bias[c];
            f32x4 v = acc[mi][ni];
            #pragma unroll
            for (int j = 0; j < 4; ++j) {
                size_t o = (size_t)(m0 + j) * 512 + c;
                if (OUTBF) reinterpret_cast<u16*>(outp)[o] = f2b(v[j] + bv);
                else       reinterpret_cast<float*>(outp)[o] = v[j] + bv;
            }
        }
    }
}

// ---------------------------------------------------------------------------
// Scores: S[bh,r,c] = Aq[bh,r,:64] . Bk[bh,c,:64] (q pre-scaled), bf16 out
// ---------------------------------------------------------------------------
__global__ __launch_bounds__(256) void scores_mfma_k(
    const u16* __restrict__ Aq, const u16* __restrict__ Bk,
    u16* __restrict__ S, int R, int C)
{
    __shared__ __align__(16) short As[128][72];
    __shared__ __align__(16) short Bs[128][72];
    const int tid = threadIdx.x;
    const int wave = tid >> 6, lane = tid & 63;
    const int lr = lane & 15, lk = (lane >> 4) * 8;
    const int bh = blockIdx.z;
    const int rb = blockIdx.y * 128, cb = blockIdx.x * 128;
    const int wr = (wave >> 1) * 64, wc = (wave & 1) * 64;
    const u16* Ap = Aq + (size_t)bh * R * 64;
    const u16* Bp = Bk + (size_t)bh * C * 64;
    const int srow = tid >> 3, skc = (tid & 7) * 8;
    #pragma unroll
    for (int it = 0; it < 4; ++it) {
        int row = it * 32 + srow;
        *reinterpret_cast<bf16x8*>(&As[row][skc]) =
            *reinterpret_cast<const bf16x8*>(Ap + (size_t)(rb + row) * 64 + skc);
        *reinterpret_cast<bf16x8*>(&Bs[row][skc]) =
            *reinterpret_cast<const bf16x8*>(Bp + (size_t)(cb + row) * 64 + skc);
    }
    __syncthreads();
    f32x4 acc[4][4] = {};
    #pragma unroll
    for (int ks = 0; ks < 2; ++ks) {
        bf16x8 af[4], bf_[4];
        #pragma unroll
        for (int mi = 0; mi < 4; ++mi)
            af[mi] = *reinterpret_cast<const bf16x8*>(&As[wr + mi * 16 + lr][ks * 32 + lk]);
        #pragma unroll
        for (int ni = 0; ni < 4; ++ni)
            bf_[ni] = *reinterpret_cast<const bf16x8*>(&Bs[wc + ni * 16 + lr][ks * 32 + lk]);
        #pragma unroll
        for (int mi = 0; mi < 4; ++mi)
            #pragma unroll
            for (int ni = 0; ni < 4; ++ni)
                acc[mi][ni] = mfma16(af[mi], bf_[ni], acc[mi][ni]);
    }
    #pragma unroll
    for (int mi = 0; mi < 4; ++mi) {
        int r0 = rb + wr + mi * 16 + (lane >> 4) * 4;
        #pragma unroll
        for (int ni = 0; ni < 4; ++ni) {
            int c = cb + wc + ni * 16 + lr;
            f32x4 v = acc[mi][ni];
            #pragma unroll
            for (int j = 0; j < 4; ++j)
                S[((size_t)bh * R + r0 + j) * C + c] = f2b(v[j]);
        }
    }
}

// ---------------------------------------------------------------------------
// PV (wide path): out[b,r,h*64+d] = P[bh,r,:C] @ V[bh,:C,d]; Vt [bh,64,C]
// ---------------------------------------------------------------------------
__global__ __launch_bounds__(256) void pv_mfma_k(
    const u16* __restrict__ P1, const u16* __restrict__ V1t,
    u16* __restrict__ out, int R, int C)
{
    __shared__ __align__(16) short As[64][72];
    __shared__ __align__(16) short Bs[64][72];
    const int tid = threadIdx.x;
    const int wave = tid >> 6, lane = tid & 63;
    const int lr = lane & 15, lg = lane >> 4, lk = lg * 8;
    const int bh = blockIdx.y, b = bh >> 3, h = bh & 7;
    const int rb = blockIdx.x * 64;
    const int wr = wave * 16;
    f32x4 acc[4] = {};
    const u16* Pb = P1 + ((size_t)bh * R + rb) * C;
    const u16* Vb = V1t + (size_t)bh * 64 * C;
    for (int c0 = 0; c0 < C; c0 += 64) {
        #pragma unroll
        for (int it = 0; it < 2; ++it) {
            int chunk = tid + it * 256;
            int r_ = chunk >> 3, c8 = (chunk & 7) * 8;
            *reinterpret_cast<bf16x8*>(&As[r_][c8]) =
                *reinterpret_cast<const bf16x8*>(Pb + (size_t)r_ * C + c0 + c8);
            *reinterpret_cast<bf16x8*>(&Bs[r_][c8]) =
                *reinterpret_cast<const bf16x8*>(Vb + (size_t)r_ * C + c0 + c8);
        }
        __syncthreads();
        #pragma unroll
        for (int ks = 0; ks < 2; ++ks) {
            bf16x8 ap = *reinterpret_cast<const bf16x8*>(&As[wr + lr][ks * 32 + lk]);
            #pragma unroll
            for (int ni = 0; ni < 4; ++ni) {
                bf16x8 bv = *reinterpret_cast<const bf16x8*>(&Bs[ni * 16 + lr][ks * 32 + lk]);
                acc[ni] = mfma16(ap, bv, acc[ni]);
            }
        }
        __syncthreads();
    }
    #pragma unroll
    for (int ni = 0; ni < 4; ++ni) {
        int d = ni * 16 + lr;
        f32x4 v = acc[ni];
        #pragma unroll
        for (int j = 0; j < 4; ++j) {
            int r0 = rb + wr + lg * 4 + j;
            out[((size_t)(b * R + r0)) * 512 + h * 64 + d] = f2b(v[j]);
        }
    }
}

// ---------------------------------------------------------------------------
// Wide softmax over 1024-col rows of S. BIASMODE 1: add bf16 bias row
// (mask folded in). BIASMODE 0: u8 maskT row -> maskval.
// ---------------------------------------------------------------------------
template<int BIASMODE>
__global__ __launch_bounds__(256) void softmax_wide_k(
    u16* __restrict__ S, const u16* __restrict__ bias,
    const unsigned char* __restrict__ maskT, float maskval)
{
    const int row_g = blockIdx.x;
    const int tid = threadIdx.x;
    const int wave = tid >> 6, lane = tid & 63;
    const int c = tid * 4;
    u16* rowp = S + (size_t)row_g * 1024;
    ushort4 sv = *reinterpret_cast<const ushort4*>(rowp + c);
    float s[4] = { b2f(sv.x), b2f(sv.y), b2f(sv.z), b2f(sv.w) };
    if (BIASMODE) {
        ushort4 bv = *reinterpret_cast<const ushort4*>(bias + (size_t)row_g * 1024 + c);
        s[0] += b2f(bv.x); s[1] += b2f(bv.y); s[2] += b2f(bv.z); s[3] += b2f(bv.w);
    } else {
        uchar4 mk = *reinterpret_cast<const uchar4*>(maskT + (size_t)row_g * 1024 + c);
        if (mk.x) s[0] = maskval; if (mk.y) s[1] = maskval;
        if (mk.z) s[2] = maskval; if (mk.w) s[3] = maskval;
    }
    __shared__ float swv[4];
    float lm = fmaxf(fmaxf(s[0], s[1]), fmaxf(s[2], s[3]));
    lm = wred_max(lm);
    if (lane == 0) swv[wave] = lm;
    __syncthreads();
    float m = fmaxf(fmaxf(swv[0], swv[1]), fmaxf(swv[2], swv[3]));
    __syncthreads();
    float ls = 0.0f;
    #pragma unroll
    for (int j = 0; j < 4; ++j) { s[j] = __expf(s[j] - m); ls += s[j]; }
    ls = wred_sum(ls);
    if (lane == 0) swv[wave] = ls;
    __syncthreads();
    float inv = 1.0f / (swv[0] + swv[1] + swv[2] + swv[3]);
    ushort4 ov = { f2b(s[0] * inv), f2b(s[1] * inv), f2b(s[2] * inv), f2b(s[3] * inv) };
    *reinterpret_cast<ushort4*>(rowp + c) = ov;
}

// ---------------------------------------------------------------------------
// Fused attention v3: 64 x-rows per block, 256 threads (4 waves), each wave
// owns 16 full rows -> softmax fully in-wave (16-lane shfl). Bias bf16
// [bh,x,k] prefetched to regs, written to LDS after K consumed.
// Grid 512 blocks (2/CU), XCD-swizzled. NSRC=2 accumulates two (K,V,bias).
// LDS: Qs 9216 | union{K 36864, bias/P 33792} | Vt 33792 = 79872 B.
// ---------------------------------------------------------------------------
template<int NSRC>
__global__ __launch_bounds__(256) void attn_xk_fused_k(
    const u16* __restrict__ Qp,
    const u16* __restrict__ K1, const u16* __restrict__ V1t, const u16* __restrict__ B1,
    const u16* __restrict__ K2, const u16* __restrict__ V2t, const u16* __restrict__ B2,
    u16* __restrict__ outm)
{
    const int tid = threadIdx.x;
    const int w = tid >> 6, lane = tid & 63;
    const int lr = lane & 15, lg = lane >> 4, lk = lg * 8;
    // XCD swizzle: 64 consecutive-scheduled blocks per XCD share 4 bh
    const int lin = blockIdx.x;
    const int xcd = lin & 7, idx = lin >> 3;
    const int bh = xcd * 4 + (idx & 3);
    const int rb = (idx >> 2) * 64;
    const int b = bh >> 3, h = bh & 7;
    const int wr = w * 16;                 // wave's row strip

    __shared__ __align__(16) short Qs[64][72];
    __shared__ __align__(16) short KP[18432];   // K [256][72] | bias/P [64][264]
    __shared__ __align__(16) short Vs[64][264];

    // stage Q [64][64]
    {
        const u16* Qb = Qp + ((size_t)bh * 1024 + rb) * 64;
        #pragma unroll
        for (int it = 0; it < 2; ++it) {
            int chunk = tid + it * 256;
            int r_ = chunk >> 3, c8 = (chunk & 7) * 8;
            *reinterpret_cast<bf16x8*>(&Qs[r_][c8]) =
                *reinterpret_cast<const bf16x8*>(Qb + (size_t)r_ * 64 + c8);
        }
    }

    f32x4 acc2[4] = {};

    #pragma unroll
    for (int s = 0; s < NSRC; ++s) {
        const u16* Kp = s ? K2 : K1;
        const u16* Vp = s ? V2t : V1t;
        const u16* Bp = s ? B2 : B1;
        // bias prefetch into regs (coalesced); consumed after scores
        bf16x8 breg[8];
        #pragma unroll
        for (int it = 0; it < 8; ++it) {
            int chunk = tid + it * 256;
            int row = chunk >> 5, c8 = (chunk & 31) * 8;
            breg[it] = *reinterpret_cast<const bf16x8*>(
                Bp + ((size_t)bh * 1024 + rb + row) * 256 + c8);
        }
        __syncthreads();   // (A) Q staged / prev PV done
        // stage K [256][64] and Vt [64][256]
        #pragma unroll
        for (int it = 0; it < 8; ++it) {
            int chunk = tid + it * 256;
            int r_ = chunk >> 3, c8 = (chunk & 7) * 8;
            *reinterpret_cast<bf16x8*>(&KP[r_ * 72 + c8]) =
                *reinterpret_cast<const bf16x8*>(Kp + ((size_t)bh * 256 + r_) * 64 + c8);
            int vd = chunk >> 5, vc8 = (chunk & 31) * 8;
            *reinterpret_cast<bf16x8*>(&Vs[vd][vc8]) =
                *reinterpret_cast<const bf16x8*>(Vp + ((size_t)bh * 64 + vd) * 256 + vc8);
        }
        __syncthreads();   // (B)
        // scores: 16 rows x 256 cols per wave (q pre-scaled)
        f32x4 acc[16];
        #pragma unroll
        for (int ni = 0; ni < 16; ++ni) acc[ni] = (f32x4){0.f, 0.f, 0.f, 0.f};
        #pragma unroll
        for (int ks = 0; ks < 2; ++ks) {
            bf16x8 af = *reinterpret_cast<const bf16x8*>(&Qs[wr + lr][ks * 32 + lk]);
            #pragma unroll
            for (int ni = 0; ni < 16; ++ni) {
                bf16x8 bfv = *reinterpret_cast<const bf16x8*>(&KP[(ni * 16 + lr) * 72 + ks * 32 + lk]);
                acc[ni] = mfma16(af, bfv, acc[ni]);
            }
        }
        __syncthreads();   // (C) K consumed -> bias may overwrite
        // bias regs -> LDS [64][264]
        #pragma unroll
        for (int it = 0; it < 8; ++it) {
            int chunk = tid + it * 256;
            int row = chunk >> 5, c8 = (chunk & 31) * 8;
            *reinterpret_cast<bf16x8*>(&KP[row * 264 + c8]) = breg[it];
        }
        __syncthreads();   // (D)
        // apply bias + in-wave softmax (rows wr+lg*4+j, cols ni*16+lr)
        float mx[4] = { -3.4e38f, -3.4e38f, -3.4e38f, -3.4e38f };
        #pragma unroll
        for (int ni = 0; ni < 16; ++ni) {
            #pragma unroll
            for (int j = 0; j < 4; ++j) {
                float v = acc[ni][j] + b2f((u16)KP[(wr + lg * 4 + j) * 264 + ni * 16 + lr]);
                acc[ni][j] = v;
                mx[j] = fmaxf(mx[j], v);
            }
        }
        #pragma unroll
        for (int j = 0; j < 4; ++j) {
            #pragma unroll
            for (int o = 1; o < 16; o <<= 1) mx[j] = fmaxf(mx[j], __shfl_xor(mx[j], o, 64));
        }
        float sm[4] = {};
        #pragma unroll
        for (int ni = 0; ni < 16; ++ni) {
            #pragma unroll
            for (int j = 0; j < 4; ++j) {
                float e = __expf(acc[ni][j] - mx[j]);
                acc[ni][j] = e;
                sm[j] += e;
            }
        }
        #pragma unroll
        for (int j = 0; j < 4; ++j) {
            #pragma unroll
            for (int o = 1; o < 16; o <<= 1) sm[j] += __shfl_xor(sm[j], o, 64);
            sm[j] = 1.0f / sm[j];
        }
        // write P (lane-local overwrite of the bias slots just read)
        #pragma unroll
        for (int ni = 0; ni < 16; ++ni)
            #pragma unroll
            for (int j = 0; j < 4; ++j)
                KP[(wr + lg * 4 + j) * 264 + ni * 16 + lr] = (short)f2b(acc[ni][j] * sm[j]);
        __syncthreads();   // (E)
        // PV: 16 rows x 64 d per wave, K=256
        #pragma unroll
        for (int kc = 0; kc < 8; ++kc) {
            bf16x8 ap = *reinterpret_cast<const bf16x8*>(&KP[(wr + lr) * 264 + kc * 32 + lk]);
            #pragma unroll
            for (int ni = 0; ni < 4; ++ni) {
                bf16x8 vv = *reinterpret_cast<const bf16x8*>(&Vs[ni * 16 + lr][kc * 32 + lk]);
                acc2[ni] = mfma16(ap, vv, acc2[ni]);
            }
        }
    }
    // epilogue: merged bf16 out [b, x, 512]
    #pragma unroll
    for (int ni = 0; ni < 4; ++ni) {
        int d = ni * 16 + lr;
        f32x4 v = acc2[ni];
        #pragma unroll
        for (int j = 0; j < 4; ++j) {
            int row = rb + wr + lg * 4 + j;
            outm[((size_t)(b * 1024 + row)) * 512 + h * 64 + d] = f2b(v[j]);
        }
    }
}

// ---------------------------------------------------------------------------
extern "C" void kernel_launch(void* const* d_in, const int* in_sizes, int n_in,
                              void* d_out, int out_size, void* d_ws, size_t ws_size,
                              hipStream_t stream)
{
    const float* x        = (const float*)d_in[0];
    const float* kernal   = (const float*)d_in[1];
    const float* i_x      = (const float*)d_in[2];
    const float* i_kernal = (const float*)d_in[3];
    const int*   rd       = (const int*)d_in[4];
    const int*   polar    = (const int*)d_in[5];
    const int*   att      = (const int*)d_in[6];
    const int*   i_att    = (const int*)d_in[7];
    const int*   cross    = (const int*)d_in[8];
    const float* Wqkv     = (const float*)d_in[9];
    const float* Wqkv_i   = (const float*)d_in[10];
    const float* Wqkv_i2  = (const float*)d_in[11];
    const float* Wproj    = (const float*)d_in[12];
    const float* bproj    = (const float*)d_in[13];
    const float* Wproj_i  = (const float*)d_in[14];
    const float* bproj_i  = (const float*)d_in[15];
    const float* Wproj_i2 = (const float*)d_in[16];
    const float* bproj_i2 = (const float*)d_in[17];
    const float* dis      = (const float*)d_in[18];
    const float* pemb     = (const float*)d_in[19];

    float* out = (float*)d_out;
    float* x_out   = out;
    float* k_out   = out + (size_t)BB * XLL * DIMM;
    float* i_x_out = k_out + (size_t)BB * KLL * DIMM;

    char* ws = (char*)d_ws;
    size_t off = 0;
    auto alloc = [&](size_t bytes) { void* p = ws + off; off += (bytes + 255) & ~(size_t)255; return p; };

    const size_t NAX = (size_t)BB * XLL * DIMM;
    const size_t NAK = (size_t)BB * KLL * DIMM;
    const size_t NHX = (size_t)BHH * XLL * HEADD;
    const size_t NHK = (size_t)BHH * KLL * HEADD;
    const size_t NS  = (size_t)BHH * KLL * XLL;

    u16* WqkvT     = (u16*)alloc((size_t)1536 * 512 * 2);
    u16* WqkvIT    = (u16*)alloc((size_t)1536 * 512 * 2);
    u16* WqkvI2T   = (u16*)alloc((size_t)1536 * 512 * 2);
    u16* WprojT    = (u16*)alloc((size_t)512 * 512 * 2);
    u16* WprojIT   = (u16*)alloc((size_t)512 * 512 * 2);
    u16* WprojI2T  = (u16*)alloc((size_t)512 * 512 * 2);
    u16* Abf  = (u16*)alloc(NAX * 2);
    u16* Q    = (u16*)alloc(NHX * 2);
    u16* KX   = (u16*)alloc(NHX * 2);
    u16* VXt  = (u16*)alloc(NHX * 2);
    u16* KQ   = (u16*)alloc(NHK * 2);
    u16* KK   = (u16*)alloc(NHK * 2);
    u16* KVt  = (u16*)alloc(NHK * 2);
    u16* IQ   = (u16*)alloc(NHX * 2);
    u16* IK   = (u16*)alloc(NHX * 2);
    u16* IVt  = (u16*)alloc(NHX * 2);
    u16* IKQ  = (u16*)alloc(NHK * 2);
    u16* IKK  = (u16*)alloc(NHK * 2);
    u16* IKVt = (u16*)alloc(NHK * 2);
    u16* K2K  = (u16*)alloc(NHK * 2);
    u16* K2Vt = (u16*)alloc(NHK * 2);
    u16* SPa  = (u16*)alloc(NS * 2);      // S (branches 1,3) / crossBias (branch 2 src1)
    u16* KMb  = (u16*)alloc(NAK * 2);
    u16* XMb  = (u16*)alloc(NAX * 2);
    u16* IKOUTb = (u16*)alloc(NAK * 2);
    u16* biasT = (u16*)alloc(NS * 2);     // branch2 bias / later iattBias
    u16* bias1 = (u16*)alloc(NS * 2);     // branch1 bias [bh,k,x]
    unsigned char* iattT8 = (unsigned char*)alloc(NS);
    int* MO   = (int*)alloc((size_t)BHH * KLL * 4);

    u16* crossB = SPa;     // alias: crossBias lives in SPa between pv1 and fused2
    u16* iattB  = biasT;   // alias: iattBias lives in biasT after fused2

    dim3 blk(256);

    // weight transposes
    transpose_cast_k<<<dim3(48, 16), blk, 0, stream>>>(Wqkv,     WqkvT,   512, 1536);
    transpose_cast_k<<<dim3(48, 16), blk, 0, stream>>>(Wqkv_i,   WqkvIT,  512, 1536);
    transpose_cast_k<<<dim3(48, 16), blk, 0, stream>>>(Wqkv_i2,  WqkvI2T, 512, 1536);
    transpose_cast_k<<<dim3(16, 16), blk, 0, stream>>>(Wproj,    WprojT,  512, 512);
    transpose_cast_k<<<dim3(16, 16), blk, 0, stream>>>(Wproj_i,  WprojIT, 512, 512);
    transpose_cast_k<<<dim3(16, 16), blk, 0, stream>>>(Wproj_i2, WprojI2T,512, 512);

    // QKV projections (q pre-scaled by 0.125)
    cast_bf16_k<<<dim3(1024), blk, 0, stream>>>(x, Abf, (int)(NAX / 8));
    gemm_qkv_mfma_k<<<dim3(12, 32), blk, 0, stream>>>(Abf, WqkvT, Q, KX, VXt, 10);
    cast_bf16_k<<<dim3(256), blk, 0, stream>>>(kernal, Abf, (int)(NAK / 8));
    gemm_qkv_mfma_k<<<dim3(12, 8), blk, 0, stream>>>(Abf, WqkvT, KQ, KK, KVt, 8);
    cast_bf16_k<<<dim3(1024), blk, 0, stream>>>(i_x, Abf, (int)(NAX / 8));
    gemm_qkv_mfma_k<<<dim3(12, 32), blk, 0, stream>>>(Abf, WqkvIT, IQ, IK, IVt, 10);
    cast_bf16_k<<<dim3(256), blk, 0, stream>>>(i_kernal, Abf, (int)(NAK / 8));
    gemm_qkv_mfma_k<<<dim3(12, 8), blk, 0, stream>>>(Abf, WqkvIT, IKQ, IKK, IKVt, 8);

    // --- branch 1: k_out ---
    scores_mfma_k<<<dim3(8, 2, BHH), blk, 0, stream>>>(KQ, KX, SPa, KLL, XLL);
    main_ori_k8<<<dim3(BB * KLL), blk, 0, stream>>>(SPa, polar, MO);
    bias_build_k<<<dim3(32, 8, BB), blk, 0, stream>>>(rd, polar, att, dis, pemb, MO, biasT, bias1);
    softmax_wide_k<1><<<dim3(BHH * KLL), blk, 0, stream>>>(SPa, bias1, nullptr, 0.0f);
    pv_mfma_k<<<dim3(4, BHH), blk, 0, stream>>>(SPa, VXt, KMb, KLL, XLL);
    gemm_proj_mfma_k<false><<<dim3(4, 8), blk, 0, stream>>>(KMb, WprojT, bproj, 1.0f, k_out);

    // --- branch 2: x_out (fused dual attention; crossBias into SPa alias) ---
    mask_bias_k<<<dim3(8192), blk, 0, stream>>>(cross, crossB, (int)(NS / 4));
    attn_xk_fused_k<2><<<dim3(512), blk, 0, stream>>>(
        Q, KK, KVt, biasT, IKK, IKVt, crossB, XMb);
    gemm_proj_mfma_k<false><<<dim3(4, 32), blk, 0, stream>>>(XMb, WprojT, bproj, 2.0f, x_out);

    // --- branch 3: i_x_out (iatt conversions into biasT alias after fused2) ---
    conv_iatt_k<<<dim3(32, 8, BHH), blk, 0, stream>>>(i_att, iattT8, iattB);
    scores_mfma_k<<<dim3(8, 2, BHH), blk, 0, stream>>>(IKQ, IK, SPa, KLL, XLL);
    softmax_wide_k<0><<<dim3(BHH * KLL), blk, 0, stream>>>(SPa, nullptr, iattT8, -1e9f);
    pv_mfma_k<<<dim3(4, BHH), blk, 0, stream>>>(SPa, IVt, KMb, KLL, XLL);
    gemm_proj_mfma_k<true><<<dim3(4, 8), blk, 0, stream>>>(KMb, WprojIT, bproj_i, 1.0f, IKOUTb);
    gemm_qkv_mfma_k<<<dim3(12, 8), blk, 0, stream>>>(IKOUTb, WqkvI2T, nullptr, K2K, K2Vt, 8);
    attn_xk_fused_k<1><<<dim3(512), blk, 0, stream>>>(
        IQ, K2K, K2Vt, iattB, nullptr, nullptr, nullptr, XMb);
    gemm_proj_mfma_k<false><<<dim3(4, 32), blk, 0, stream>>>(XMb, WprojI2T, bproj_i2, 1.0f, i_x_out);

    (void)in_sizes; (void)n_in; (void)out_size; (void)ws_size;
}

// Round 7
// 464.100 us; speedup vs baseline: 1.0603x; 1.0071x over previous
//
#include <hip/hip_runtime.h>
#include <cstddef>
#include <cstdint>

#define BB 4
#define HH 8
#define HEADD 64
#define DIMM 512
#define XLL 1024
#define KLL 256
#define BHH (BB*HH)

typedef __attribute__((ext_vector_type(8))) short bf16x8;
typedef __attribute__((ext_vector_type(8))) unsigned short u16x8;
typedef __attribute__((ext_vector_type(4))) float f32x4;
typedef unsigned short u16;

__device__ __forceinline__ u16 f2b(float f) {
    unsigned int u = __builtin_bit_cast(unsigned int, f);
    u = u + 0x7fffu + ((u >> 16) & 1u);
    return (u16)(u >> 16);
}
__device__ __forceinline__ float b2f(u16 h) {
    unsigned int u = ((unsigned int)h) << 16;
    return __builtin_bit_cast(float, u);
}
__device__ __forceinline__ f32x4 mfma16(bf16x8 a, bf16x8 b, f32x4 c) {
    return __builtin_amdgcn_mfma_f32_16x16x32_bf16(a, b, c, 0, 0, 0);
}
__device__ __forceinline__ float wred_max(float v) {
    #pragma unroll
    for (int o = 1; o < 64; o <<= 1) v = fmaxf(v, __shfl_xor(v, o, 64));
    return v;
}
__device__ __forceinline__ float wred_sum(float v) {
    #pragma unroll
    for (int o = 1; o < 64; o <<= 1) v += __shfl_xor(v, o, 64);
    return v;
}

// ---------------------------------------------------------------------------
// f32 -> bf16 cast, 8 elems/thread
// ---------------------------------------------------------------------------
__global__ __launch_bounds__(256) void cast_bf16_k(
    const float* __restrict__ in, u16* __restrict__ out, int n8)
{
    int i = blockIdx.x * 256 + threadIdx.x;
    if (i >= n8) return;
    const float4* p = reinterpret_cast<const float4*>(in) + (size_t)i * 2;
    float4 a = p[0], b = p[1];
    u16x8 o;
    o[0] = f2b(a.x); o[1] = f2b(a.y); o[2] = f2b(a.z); o[3] = f2b(a.w);
    o[4] = f2b(b.x); o[5] = f2b(b.y); o[6] = f2b(b.z); o[7] = f2b(b.w);
    *reinterpret_cast<u16x8*>(out + (size_t)i * 8) = o;
}

// ---------------------------------------------------------------------------
// W [K][N] f32  ->  Wt [N][K] bf16
// ---------------------------------------------------------------------------
__global__ __launch_bounds__(256) void transpose_cast_k(
    const float* __restrict__ W, u16* __restrict__ Wt, int K, int N)
{
    __shared__ float t[32][33];
    int bx = blockIdx.x, by = blockIdx.y;
    int tx = threadIdx.x & 31, ty = threadIdx.x >> 5;
    #pragma unroll
    for (int r = ty; r < 32; r += 8)
        t[r][tx] = W[(size_t)(by * 32 + r) * N + bx * 32 + tx];
    __syncthreads();
    #pragma unroll
    for (int r = ty; r < 32; r += 8)
        Wt[(size_t)(bx * 32 + r) * K + by * 32 + tx] = f2b(t[tx][r]);
}

// ---------------------------------------------------------------------------
// i_att int32 [bh,x,k] -> iattT8 u8 [bh,k,x]  AND  iattBias bf16 [bh,x,k]
// ---------------------------------------------------------------------------
__global__ __launch_bounds__(256) void conv_iatt_k(
    const int* __restrict__ m, unsigned char* __restrict__ mt,
    u16* __restrict__ mb)
{
    __shared__ unsigned char t[32][33];
    const int bh = blockIdx.z, xt = blockIdx.x, kt = blockIdx.y;
    const int tx = threadIdx.x & 31, ty = threadIdx.x >> 5;
    const u16 NEG = f2b(-1e9f);
    #pragma unroll
    for (int r = ty; r < 32; r += 8) {
        size_t idx = ((size_t)bh * 1024 + xt * 32 + r) * 256 + kt * 32 + tx;
        unsigned char v = (unsigned char)(m[idx] != 0);
        t[r][tx] = v;
        mb[idx] = v ? NEG : (u16)0;
    }
    __syncthreads();
    #pragma unroll
    for (int r = ty; r < 32; r += 8)
        mt[((size_t)bh * 256 + kt * 32 + r) * 1024 + xt * 32 + tx] = t[tx][r];
}

// ---------------------------------------------------------------------------
// mask int32 -> bf16 bias (0 / -1e9), same layout, 4 elems/thread
// ---------------------------------------------------------------------------
__global__ __launch_bounds__(256) void mask_bias_k(
    const int* __restrict__ m, u16* __restrict__ o, int n4)
{
    int i = blockIdx.x * 256 + threadIdx.x;
    if (i >= n4) return;
    int4 v = reinterpret_cast<const int4*>(m)[i];
    const u16 NEG = f2b(-1e9f);
    ushort4 u;
    u.x = v.x ? NEG : (u16)0; u.y = v.y ? NEG : (u16)0;
    u.z = v.z ? NEG : (u16)0; u.w = v.w ? NEG : (u16)0;
    reinterpret_cast<ushort4*>(o)[i] = u;
}

// ---------------------------------------------------------------------------
// main orientation: block per (b,k); reads polar row once, loops 8 heads.
// ---------------------------------------------------------------------------
__global__ __launch_bounds__(256) void main_ori_k8(
    const u16* __restrict__ S, const int* __restrict__ polar,
    int* __restrict__ MO)
{
    const int blk = blockIdx.x;          // b*256 + k
    const int b = blk >> 8, k = blk & 255;
    const int tid = threadIdx.x;
    const int wave = tid >> 6, lane = tid & 63;
    const int c = tid * 4;
    int4 p4 = *reinterpret_cast<const int4*>(polar + ((size_t)b * 256 + k) * 1024 + c);
    int pp[4] = { p4.x, p4.y, p4.z, p4.w };
    #pragma unroll
    for (int j = 0; j < 4; ++j) { int p = pp[j]; pp[j] = p < 0 ? 0 : (p > 7 ? 7 : p); }
    __shared__ float sred[4][8];
    for (int h = 0; h < 8; ++h) {
        const int bh = b * 8 + h;
        ushort4 sv = *reinterpret_cast<const ushort4*>(S + ((size_t)bh * 256 + k) * 1024 + c);
        float av[4] = { fabsf(b2f(sv.x)), fabsf(b2f(sv.y)), fabsf(b2f(sv.z)), fabsf(b2f(sv.w)) };
        float bins[8] = {};
        #pragma unroll
        for (int j = 0; j < 4; ++j) {
            #pragma unroll
            for (int o = 0; o < 8; ++o) bins[o] += (pp[j] == o) ? av[j] : 0.0f;
        }
        #pragma unroll
        for (int o = 0; o < 8; ++o) bins[o] = wred_sum(bins[o]);
        if (lane == 0) {
            #pragma unroll
            for (int o = 0; o < 8; ++o) sred[wave][o] = bins[o];
        }
        __syncthreads();
        if (tid == 0) {
            int best = 0; float bv = -1.0f;
            #pragma unroll
            for (int o = 0; o < 8; ++o) {
                float s = sred[0][o] + sred[1][o] + sred[2][o] + sred[3][o];
                if (s > bv) { bv = s; best = o; }
            }
            MO[bh * 256 + k] = best;
        }
        __syncthreads();
    }
}

// ---------------------------------------------------------------------------
// Combined bias build (after MO): per (b, x-tile32, k-tile32), all 8 heads:
//   v = dis[rd]+pemb[(polar-MO)&7]
//   biasT[bh,x,k] = att ? -1e9 : v   (branch 2)
//   bias1[bh,k,x] = att ? -1e6 : v   (branch 1)
// ---------------------------------------------------------------------------
__global__ __launch_bounds__(256) void bias_build_k(
    const int* __restrict__ rd, const int* __restrict__ polar,
    const int* __restrict__ att, const float* __restrict__ dis,
    const float* __restrict__ pemb, const int* __restrict__ MO,
    u16* __restrict__ biasT, u16* __restrict__ bias1)
{
    const int b = blockIdx.z;
    const int xt = blockIdx.x * 32, kt = blockIdx.y * 32;
    const int tid = threadIdx.x;
    __shared__ float dsh[528];
    __shared__ int rds[32][33];   // [x][k]
    __shared__ int pls[32][33];
    __shared__ u16 bt[32][33];    // bias (−1e6 variant) tile [x][k]
    for (int i = tid; i < 528; i += 256) dsh[i] = dis[i];
    const int tx = tid & 31, ty = tid >> 5;
    #pragma unroll
    for (int r = ty; r < 32; r += 8) {
        size_t src = ((size_t)b * 256 + kt + r) * 1024 + xt + tx;  // rd[b,k,x]
        rds[tx][r] = rd[src];
        int p = polar[src]; pls[tx][r] = p < 0 ? 0 : (p > 7 ? 7 : p);
    }
    float pe[8];
    #pragma unroll
    for (int o = 0; o < 8; ++o) pe[o] = pemb[o];
    __syncthreads();
    const int x = tid >> 3, k4 = (tid & 7) * 4;
    const u16 NEG9 = f2b(-1e9f), NEG6 = f2b(-1e6f);
    for (int h = 0; h < 8; ++h) {
        const int bh = b * 8 + h;
        size_t oidx = ((size_t)bh * 1024 + xt + x) * 256 + kt + k4;
        int4 m4 = *reinterpret_cast<const int4*>(att + oidx);
        int4 mo4 = *reinterpret_cast<const int4*>(MO + bh * 256 + kt + k4);
        int mm[4] = { m4.x, m4.y, m4.z, m4.w };
        int mo[4] = { mo4.x, mo4.y, mo4.z, mo4.w };
        u16 o_[4];
        #pragma unroll
        for (int j = 0; j < 4; ++j) {
            float v = dsh[rds[x][k4 + j] * 8 + h] + pe[(pls[x][k4 + j] - mo[j] + 8) & 7];
            u16 vb = f2b(v);
            o_[j] = mm[j] ? NEG9 : vb;
            bt[x][k4 + j] = mm[j] ? NEG6 : vb;
        }
        ushort4 ov; ov.x = o_[0]; ov.y = o_[1]; ov.z = o_[2]; ov.w = o_[3];
        *reinterpret_cast<ushort4*>(biasT + oidx) = ov;
        __syncthreads();
        const int k_ = tid >> 3, x4 = (tid & 7) * 4;
        ushort4 o2;
        o2.x = bt[x4 + 0][k_]; o2.y = bt[x4 + 1][k_];
        o2.z = bt[x4 + 2][k_]; o2.w = bt[x4 + 3][k_];
        *reinterpret_cast<ushort4*>(bias1 + ((size_t)bh * 256 + kt + k_) * 1024 + xt + x4) = o2;
        __syncthreads();
    }
}

// ---------------------------------------------------------------------------
// QKV GEMM: A bf16 [M,512] @ Wt bf16 [1536,512]^T; q pre-scaled by 0.125.
// q,k -> [b,h,n,64] bf16; v -> [b,h,64,n] bf16 (transposed)
// ---------------------------------------------------------------------------
__global__ __launch_bounds__(256) void gemm_qkv_mfma_k(
    const u16* __restrict__ A, const u16* __restrict__ Wt,
    u16* __restrict__ qb, u16* __restrict__ kb, u16* __restrict__ vt,
    int sl)
{
    __shared__ __align__(16) short As[128][72];
    __shared__ __align__(16) short Bs[128][72];
    const int tid = threadIdx.x;
    const int wave = tid >> 6, lane = tid & 63;
    const int lr = lane & 15, lk = (lane >> 4) * 8;
    const int rb = blockIdx.y * 128, cb = blockIdx.x * 128;
    const int wr = (wave >> 1) * 64, wc = (wave & 1) * 64;
    const int seq = 1 << sl, smask = seq - 1;
    f32x4 acc[4][4] = {};
    const int srow = tid >> 3, skc = (tid & 7) * 8;
    for (int k0 = 0; k0 < 512; k0 += 64) {
        #pragma unroll
        for (int it = 0; it < 4; ++it) {
            int row = it * 32 + srow;
            *reinterpret_cast<bf16x8*>(&As[row][skc]) =
                *reinterpret_cast<const bf16x8*>(A + (size_t)(rb + row) * 512 + k0 + skc);
            *reinterpret_cast<bf16x8*>(&Bs[row][skc]) =
                *reinterpret_cast<const bf16x8*>(Wt + (size_t)(cb + row) * 512 + k0 + skc);
        }
        __syncthreads();
        #pragma unroll
        for (int ks = 0; ks < 2; ++ks) {
            bf16x8 af[4], bf_[4];
            #pragma unroll
            for (int mi = 0; mi < 4; ++mi)
                af[mi] = *reinterpret_cast<const bf16x8*>(&As[wr + mi * 16 + lr][ks * 32 + lk]);
            #pragma unroll
            for (int ni = 0; ni < 4; ++ni)
                bf_[ni] = *reinterpret_cast<const bf16x8*>(&Bs[wc + ni * 16 + lr][ks * 32 + lk]);
            #pragma unroll
            for (int mi = 0; mi < 4; ++mi)
                #pragma unroll
                for (int ni = 0; ni < 4; ++ni)
                    acc[mi][ni] = mfma16(af[mi], bf_[ni], acc[mi][ni]);
        }
        __syncthreads();
    }
    #pragma unroll
    for (int mi = 0; mi < 4; ++mi) {
        int m0 = rb + wr + mi * 16 + (lane >> 4) * 4;
        #pragma unroll
        for (int ni = 0; ni < 4; ++ni) {
            int c = cb + wc + ni * 16 + lr;
            int which = c >> 9, h = (c >> 6) & 7, d = c & 63;
            f32x4 v = acc[mi][ni];
            #pragma unroll
            for (int j = 0; j < 4; ++j) {
                int mm = m0 + j;
                int b = mm >> sl, n = mm & smask;
                if (which == 0) {
                    if (qb) qb[(((size_t)b * HH + h) * seq + n) * 64 + d] = f2b(v[j] * 0.125f);
                } else if (which == 1) {
                    if (kb) kb[(((size_t)b * HH + h) * seq + n) * 64 + d] = f2b(v[j]);
                } else {
                    vt[(((size_t)b * HH + h) * 64 + d) * seq + n] = f2b(v[j]);
                }
            }
        }
    }
}

// ---------------------------------------------------------------------------
// Proj GEMM: A bf16 [M,512] @ Wt bf16 [512,512]^T + bscale*bias
// ---------------------------------------------------------------------------
template<bool OUTBF>
__global__ __launch_bounds__(256) void gemm_proj_mfma_k(
    const u16* __restrict__ A, const u16* __restrict__ Wt,
    const float* __restrict__ bias, float bscale, void* __restrict__ outp)
{
    __shared__ __align__(16) short As[128][72];
    __shared__ __align__(16) short Bs[128][72];
    const int tid = threadIdx.x;
    const int wave = tid >> 6, lane = tid & 63;
    const int lr = lane & 15, lk = (lane >> 4) * 8;
    const int rb = blockIdx.y * 128, cb = blockIdx.x * 128;
    const int wr = (wave >> 1) * 64, wc = (wave & 1) * 64;
    f32x4 acc[4][4] = {};
    const int srow = tid >> 3, skc = (tid & 7) * 8;
    for (int k0 = 0; k0 < 512; k0 += 64) {
        #pragma unroll
        for (int it = 0; it < 4; ++it) {
            int row = it * 32 + srow;
            *reinterpret_cast<bf16x8*>(&As[row][skc]) =
                *reinterpret_cast<const bf16x8*>(A + (size_t)(rb + row) * 512 + k0 + skc);
            *reinterpret_cast<bf16x8*>(&Bs[row][skc]) =
                *reinterpret_cast<const bf16x8*>(Wt + (size_t)(cb + row) * 512 + k0 + skc);
        }
        __syncthreads();
        #pragma unroll
        for (int ks = 0; ks < 2; ++ks) {
            bf16x8 af[4], bf_[4];
            #pragma unroll
            for (int mi = 0; mi < 4; ++mi)
                af[mi] = *reinterpret_cast<const bf16x8*>(&As[wr + mi * 16 + lr][ks * 32 + lk]);
            #pragma unroll
            for (int ni = 0; ni < 4; ++ni)
                bf_[ni] = *reinterpret_cast<const bf16x8*>(&Bs[wc + ni * 16 + lr][ks * 32 + lk]);
            #pragma unroll
            for (int mi = 0; mi < 4; ++mi)
                #pragma unroll
                for (int ni = 0; ni < 4; ++ni)
                    acc[mi][ni] = mfma16(af[mi], bf_[ni], acc[mi][ni]);
        }
        __syncthreads();
    }
    #pragma unroll
    for (int mi = 0; mi < 4; ++mi) {
        int m0 = rb + wr + mi * 16 + (lane >> 4) * 4;
        #pragma unroll
        for (int ni = 0; ni < 4; ++ni) {
            int c = cb + wc + ni * 16 + lr;
            float bv = bscale * bias[c];
            f32x4 v = acc[mi][ni];
            #pragma unroll
            for (int j = 0; j < 4; ++j) {
                size_t o = (size_t)(m0 + j) * 512 + c;
                if (OUTBF) reinterpret_cast<u16*>(outp)[o] = f2b(v[j] + bv);
                else       reinterpret_cast<float*>(outp)[o] = v[j] + bv;
            }
        }
    }
}

// ---------------------------------------------------------------------------
// Scores: S[bh,r,c] = Aq[bh,r,:64] . Bk[bh,c,:64] (q pre-scaled), bf16 out
// ---------------------------------------------------------------------------
__global__ __launch_bounds__(256) void scores_mfma_k(
    const u16* __restrict__ Aq, const u16* __restrict__ Bk,
    u16* __restrict__ S, int R, int C)
{
    __shared__ __align__(16) short As[128][72];
    __shared__ __align__(16) short Bs[128][72];
    const int tid = threadIdx.x;
    const int wave = tid >> 6, lane = tid & 63;
    const int lr = lane & 15, lk = (lane >> 4) * 8;
    const int bh = blockIdx.z;
    const int rb = blockIdx.y * 128, cb = blockIdx.x * 128;
    const int wr = (wave >> 1) * 64, wc = (wave & 1) * 64;
    const u16* Ap = Aq + (size_t)bh * R * 64;
    const u16* Bp = Bk + (size_t)bh * C * 64;
    const int srow = tid >> 3, skc = (tid & 7) * 8;
    #pragma unroll
    for (int it = 0; it < 4; ++it) {
        int row = it * 32 + srow;
        *reinterpret_cast<bf16x8*>(&As[row][skc]) =
            *reinterpret_cast<const bf16x8*>(Ap + (size_t)(rb + row) * 64 + skc);
        *reinterpret_cast<bf16x8*>(&Bs[row][skc]) =
            *reinterpret_cast<const bf16x8*>(Bp + (size_t)(cb + row) * 64 + skc);
    }
    __syncthreads();
    f32x4 acc[4][4] = {};
    #pragma unroll
    for (int ks = 0; ks < 2; ++ks) {
        bf16x8 af[4], bf_[4];
        #pragma unroll
        for (int mi = 0; mi < 4; ++mi)
            af[mi] = *reinterpret_cast<const bf16x8*>(&As[wr + mi * 16 + lr][ks * 32 + lk]);
        #pragma unroll
        for (int ni = 0; ni < 4; ++ni)
            bf_[ni] = *reinterpret_cast<const bf16x8*>(&Bs[wc + ni * 16 + lr][ks * 32 + lk]);
        #pragma unroll
        for (int mi = 0; mi < 4; ++mi)
            #pragma unroll
            for (int ni = 0; ni < 4; ++ni)
                acc[mi][ni] = mfma16(af[mi], bf_[ni], acc[mi][ni]);
    }
    #pragma unroll
    for (int mi = 0; mi < 4; ++mi) {
        int r0 = rb + wr + mi * 16 + (lane >> 4) * 4;
        #pragma unroll
        for (int ni = 0; ni < 4; ++ni) {
            int c = cb + wc + ni * 16 + lr;
            f32x4 v = acc[mi][ni];
            #pragma unroll
            for (int j = 0; j < 4; ++j)
                S[((size_t)bh * R + r0 + j) * C + c] = f2b(v[j]);
        }
    }
}

// ---------------------------------------------------------------------------
// PV (wide path): out[b,r,h*64+d] = P[bh,r,:C] @ V[bh,:C,d]; Vt [bh,64,C]
// ---------------------------------------------------------------------------
__global__ __launch_bounds__(256) void pv_mfma_k(
    const u16* __restrict__ P1, const u16* __restrict__ V1t,
    u16* __restrict__ out, int R, int C)
{
    __shared__ __align__(16) short As[64][72];
    __shared__ __align__(16) short Bs[64][72];
    const int tid = threadIdx.x;
    const int wave = tid >> 6, lane = tid & 63;
    const int lr = lane & 15, lg = lane >> 4, lk = lg * 8;
    const int bh = blockIdx.y, b = bh >> 3, h = bh & 7;
    const int rb = blockIdx.x * 64;
    const int wr = wave * 16;
    f32x4 acc[4] = {};
    const u16* Pb = P1 + ((size_t)bh * R + rb) * C;
    const u16* Vb = V1t + (size_t)bh * 64 * C;
    for (int c0 = 0; c0 < C; c0 += 64) {
        #pragma unroll
        for (int it = 0; it < 2; ++it) {
            int chunk = tid + it * 256;
            int r_ = chunk >> 3, c8 = (chunk & 7) * 8;
            *reinterpret_cast<bf16x8*>(&As[r_][c8]) =
                *reinterpret_cast<const bf16x8*>(Pb + (size_t)r_ * C + c0 + c8);
            *reinterpret_cast<bf16x8*>(&Bs[r_][c8]) =
                *reinterpret_cast<const bf16x8*>(Vb + (size_t)r_ * C + c0 + c8);
        }
        __syncthreads();
        #pragma unroll
        for (int ks = 0; ks < 2; ++ks) {
            bf16x8 ap = *reinterpret_cast<const bf16x8*>(&As[wr + lr][ks * 32 + lk]);
            #pragma unroll
            for (int ni = 0; ni < 4; ++ni) {
                bf16x8 bv = *reinterpret_cast<const bf16x8*>(&Bs[ni * 16 + lr][ks * 32 + lk]);
                acc[ni] = mfma16(ap, bv, acc[ni]);
            }
        }
        __syncthreads();
    }
    #pragma unroll
    for (int ni = 0; ni < 4; ++ni) {
        int d = ni * 16 + lr;
        f32x4 v = acc[ni];
        #pragma unroll
        for (int j = 0; j < 4; ++j) {
            int r0 = rb + wr + lg * 4 + j;
            out[((size_t)(b * R + r0)) * 512 + h * 64 + d] = f2b(v[j]);
        }
    }
}

// ---------------------------------------------------------------------------
// Wide softmax over 1024-col rows of S. BIASMODE 1: add bf16 bias row
// (mask folded in). BIASMODE 0: u8 maskT row -> maskval.
// ---------------------------------------------------------------------------
template<int BIASMODE>
__global__ __launch_bounds__(256) void softmax_wide_k(
    u16* __restrict__ S, const u16* __restrict__ bias,
    const unsigned char* __restrict__ maskT, float maskval)
{
    const int row_g = blockIdx.x;
    const int tid = threadIdx.x;
    const int wave = tid >> 6, lane = tid & 63;
    const int c = tid * 4;
    u16* rowp = S + (size_t)row_g * 1024;
    ushort4 sv = *reinterpret_cast<const ushort4*>(rowp + c);
    float s[4] = { b2f(sv.x), b2f(sv.y), b2f(sv.z), b2f(sv.w) };
    if (BIASMODE) {
        ushort4 bv = *reinterpret_cast<const ushort4*>(bias + (size_t)row_g * 1024 + c);
        s[0] += b2f(bv.x); s[1] += b2f(bv.y); s[2] += b2f(bv.z); s[3] += b2f(bv.w);
    } else {
        uchar4 mk = *reinterpret_cast<const uchar4*>(maskT + (size_t)row_g * 1024 + c);
        if (mk.x) s[0] = maskval; if (mk.y) s[1] = maskval;
        if (mk.z) s[2] = maskval; if (mk.w) s[3] = maskval;
    }
    __shared__ float swv[4];
    float lm = fmaxf(fmaxf(s[0], s[1]), fmaxf(s[2], s[3]));
    lm = wred_max(lm);
    if (lane == 0) swv[wave] = lm;
    __syncthreads();
    float m = fmaxf(fmaxf(swv[0], swv[1]), fmaxf(swv[2], swv[3]));
    __syncthreads();
    float ls = 0.0f;
    #pragma unroll
    for (int j = 0; j < 4; ++j) { s[j] = __expf(s[j] - m); ls += s[j]; }
    ls = wred_sum(ls);
    if (lane == 0) swv[wave] = ls;
    __syncthreads();
    float inv = 1.0f / (swv[0] + swv[1] + swv[2] + swv[3]);
    ushort4 ov = { f2b(s[0] * inv), f2b(s[1] * inv), f2b(s[2] * inv), f2b(s[3] * inv) };
    *reinterpret_cast<ushort4*>(rowp + c) = ov;
}

// ---------------------------------------------------------------------------
// Fused attention v4: 64 x-rows/block, 256 threads (4 waves), wave owns 16
// full rows. Q in registers (wave-local rows); V read direct from global
// (L1/L2-resident 32KB tile); single 36KB LDS union {K [256][72] | bias/P
// [64][264]}. Bias prefetched to regs, LDS-bounced after K consumed.
// 4 barriers per source. Grid 512 blocks, XCD-swizzled.
// ---------------------------------------------------------------------------
template<int NSRC>
__global__ __launch_bounds__(256, 3) void attn_xk_fused_k(
    const u16* __restrict__ Qp,
    const u16* __restrict__ K1, const u16* __restrict__ V1t, const u16* __restrict__ B1,
    const u16* __restrict__ K2, const u16* __restrict__ V2t, const u16* __restrict__ B2,
    u16* __restrict__ outm)
{
    const int tid = threadIdx.x;
    const int w = tid >> 6, lane = tid & 63;
    const int lr = lane & 15, lg = lane >> 4, lk = lg * 8;
    const int lin = blockIdx.x;
    const int xcd = lin & 7, idx = lin >> 3;
    const int bh = xcd * 4 + (idx & 3);
    const int rb = (idx >> 2) * 64;
    const int b = bh >> 3, h = bh & 7;
    const int wr = w * 16;                 // wave's row strip

    __shared__ __align__(16) short KP[18432];   // K [256][72] | bias/P [64][264]

    // Q fragments in registers (wave-local rows), loaded once
    bf16x8 qf0, qf1;
    {
        const u16* Qb = Qp + ((size_t)bh * 1024 + rb + wr + lr) * 64;
        qf0 = *reinterpret_cast<const bf16x8*>(Qb + lk);
        qf1 = *reinterpret_cast<const bf16x8*>(Qb + 32 + lk);
    }

    f32x4 acc2[4] = {};

    #pragma unroll
    for (int s = 0; s < NSRC; ++s) {
        const u16* Kp = s ? K2 : K1;
        const u16* Vp = s ? V2t : V1t;
        const u16* Bp = s ? B2 : B1;
        // bias prefetch into regs (coalesced 16B); consumed after scores
        bf16x8 breg[8];
        #pragma unroll
        for (int it = 0; it < 8; ++it) {
            int chunk = tid + it * 256;
            int row = chunk >> 5, c8 = (chunk & 31) * 8;
            breg[it] = *reinterpret_cast<const bf16x8*>(
                Bp + ((size_t)bh * 1024 + rb + row) * 256 + c8);
        }
        __syncthreads();   // (A) prev source's P fully consumed
        // stage K [256][64]
        #pragma unroll
        for (int it = 0; it < 8; ++it) {
            int chunk = tid + it * 256;
            int r_ = chunk >> 3, c8 = (chunk & 7) * 8;
            *reinterpret_cast<bf16x8*>(&KP[r_ * 72 + c8]) =
                *reinterpret_cast<const bf16x8*>(Kp + ((size_t)bh * 256 + r_) * 64 + c8);
        }
        __syncthreads();   // (B) K ready
        // scores: 16 rows x 256 cols per wave (q pre-scaled)
        f32x4 acc[16];
        #pragma unroll
        for (int ni = 0; ni < 16; ++ni) acc[ni] = (f32x4){0.f, 0.f, 0.f, 0.f};
        #pragma unroll
        for (int ni = 0; ni < 16; ++ni) {
            bf16x8 b0 = *reinterpret_cast<const bf16x8*>(&KP[(ni * 16 + lr) * 72 + lk]);
            acc[ni] = mfma16(qf0, b0, acc[ni]);
        }
        #pragma unroll
        for (int ni = 0; ni < 16; ++ni) {
            bf16x8 b1 = *reinterpret_cast<const bf16x8*>(&KP[(ni * 16 + lr) * 72 + 32 + lk]);
            acc[ni] = mfma16(qf1, b1, acc[ni]);
        }
        __syncthreads();   // (C) K consumed -> bias may overwrite
        // bias regs -> LDS [64][264]
        #pragma unroll
        for (int it = 0; it < 8; ++it) {
            int chunk = tid + it * 256;
            int row = chunk >> 5, c8 = (chunk & 31) * 8;
            *reinterpret_cast<bf16x8*>(&KP[row * 264 + c8]) = breg[it];
        }
        __syncthreads();   // (D) bias ready
        // apply bias + in-wave softmax (rows wr+lg*4+j, cols ni*16+lr)
        float mx[4] = { -3.4e38f, -3.4e38f, -3.4e38f, -3.4e38f };
        #pragma unroll
        for (int ni = 0; ni < 16; ++ni) {
            #pragma unroll
            for (int j = 0; j < 4; ++j) {
                float v = acc[ni][j] + b2f((u16)KP[(wr + lg * 4 + j) * 264 + ni * 16 + lr]);
                acc[ni][j] = v;
                mx[j] = fmaxf(mx[j], v);
            }
        }
        #pragma unroll
        for (int j = 0; j < 4; ++j) {
            #pragma unroll
            for (int o = 1; o < 16; o <<= 1) mx[j] = fmaxf(mx[j], __shfl_xor(mx[j], o, 64));
        }
        float sm[4] = {};
        #pragma unroll
        for (int ni = 0; ni < 16; ++ni) {
            #pragma unroll
            for (int j = 0; j < 4; ++j) {
                float e = __expf(acc[ni][j] - mx[j]);
                acc[ni][j] = e;
                sm[j] += e;
            }
        }
        #pragma unroll
        for (int j = 0; j < 4; ++j) {
            #pragma unroll
            for (int o = 1; o < 16; o <<= 1) sm[j] += __shfl_xor(sm[j], o, 64);
            sm[j] = 1.0f / sm[j];
        }
        // write P (wave-local rows; lane overwrites the slots it just read)
        #pragma unroll
        for (int ni = 0; ni < 16; ++ni)
            #pragma unroll
            for (int j = 0; j < 4; ++j)
                KP[(wr + lg * 4 + j) * 264 + ni * 16 + lr] = (short)f2b(acc[ni][j] * sm[j]);
        // PV: 16 rows x 64 d per wave, K=256; P wave-local in LDS, V direct
        #pragma unroll
        for (int kc = 0; kc < 8; ++kc) {
            bf16x8 ap = *reinterpret_cast<const bf16x8*>(&KP[(wr + lr) * 264 + kc * 32 + lk]);
            #pragma unroll
            for (int ni = 0; ni < 4; ++ni) {
                bf16x8 vv = *reinterpret_cast<const bf16x8*>(
                    Vp + ((size_t)bh * 64 + ni * 16 + lr) * 256 + kc * 32 + lk);
                acc2[ni] = mfma16(ap, vv, acc2[ni]);
            }
        }
    }
    // epilogue: merged bf16 out [b, x, 512]
    #pragma unroll
    for (int ni = 0; ni < 4; ++ni) {
        int d = ni * 16 + lr;
        f32x4 v = acc2[ni];
        #pragma unroll
        for (int j = 0; j < 4; ++j) {
            int row = rb + wr + lg * 4 + j;
            outm[((size_t)(b * 1024 + row)) * 512 + h * 64 + d] = f2b(v[j]);
        }
    }
}

// ---------------------------------------------------------------------------
extern "C" void kernel_launch(void* const* d_in, const int* in_sizes, int n_in,
                              void* d_out, int out_size, void* d_ws, size_t ws_size,
                              hipStream_t stream)
{
    const float* x        = (const float*)d_in[0];
    const float* kernal   = (const float*)d_in[1];
    const float* i_x      = (const float*)d_in[2];
    const float* i_kernal = (const float*)d_in[3];
    const int*   rd       = (const int*)d_in[4];
    const int*   polar    = (const int*)d_in[5];
    const int*   att      = (const int*)d_in[6];
    const int*   i_att    = (const int*)d_in[7];
    const int*   cross    = (const int*)d_in[8];
    const float* Wqkv     = (const float*)d_in[9];
    const float* Wqkv_i   = (const float*)d_in[10];
    const float* Wqkv_i2  = (const float*)d_in[11];
    const float* Wproj    = (const float*)d_in[12];
    const float* bproj    = (const float*)d_in[13];
    const float* Wproj_i  = (const float*)d_in[14];
    const float* bproj_i  = (const float*)d_in[15];
    const float* Wproj_i2 = (const float*)d_in[16];
    const float* bproj_i2 = (const float*)d_in[17];
    const float* dis      = (const float*)d_in[18];
    const float* pemb     = (const float*)d_in[19];

    float* out = (float*)d_out;
    float* x_out   = out;
    float* k_out   = out + (size_t)BB * XLL * DIMM;
    float* i_x_out = k_out + (size_t)BB * KLL * DIMM;

    char* ws = (char*)d_ws;
    size_t off = 0;
    auto alloc = [&](size_t bytes) { void* p = ws + off; off += (bytes + 255) & ~(size_t)255; return p; };

    const size_t NAX = (size_t)BB * XLL * DIMM;
    const size_t NAK = (size_t)BB * KLL * DIMM;
    const size_t NHX = (size_t)BHH * XLL * HEADD;
    const size_t NHK = (size_t)BHH * KLL * HEADD;
    const size_t NS  = (size_t)BHH * KLL * XLL;

    u16* WqkvT     = (u16*)alloc((size_t)1536 * 512 * 2);
    u16* WqkvIT    = (u16*)alloc((size_t)1536 * 512 * 2);
    u16* WqkvI2T   = (u16*)alloc((size_t)1536 * 512 * 2);
    u16* WprojT    = (u16*)alloc((size_t)512 * 512 * 2);
    u16* WprojIT   = (u16*)alloc((size_t)512 * 512 * 2);
    u16* WprojI2T  = (u16*)alloc((size_t)512 * 512 * 2);
    u16* Abf  = (u16*)alloc(NAX * 2);
    u16* Q    = (u16*)alloc(NHX * 2);
    u16* KX   = (u16*)alloc(NHX * 2);
    u16* VXt  = (u16*)alloc(NHX * 2);
    u16* KQ   = (u16*)alloc(NHK * 2);
    u16* KK   = (u16*)alloc(NHK * 2);
    u16* KVt  = (u16*)alloc(NHK * 2);
    u16* IQ   = (u16*)alloc(NHX * 2);
    u16* IK   = (u16*)alloc(NHX * 2);
    u16* IVt  = (u16*)alloc(NHX * 2);
    u16* IKQ  = (u16*)alloc(NHK * 2);
    u16* IKK  = (u16*)alloc(NHK * 2);
    u16* IKVt = (u16*)alloc(NHK * 2);
    u16* K2K  = (u16*)alloc(NHK * 2);
    u16* K2Vt = (u16*)alloc(NHK * 2);
    u16* SPa  = (u16*)alloc(NS * 2);      // S (branches 1,3) / crossBias (branch 2 src1)
    u16* KMb  = (u16*)alloc(NAK * 2);
    u16* XMb  = (u16*)alloc(NAX * 2);
    u16* IKOUTb = (u16*)alloc(NAK * 2);
    u16* biasT = (u16*)alloc(NS * 2);     // branch2 bias / later iattBias
    u16* bias1 = (u16*)alloc(NS * 2);     // branch1 bias [bh,k,x]
    unsigned char* iattT8 = (unsigned char*)alloc(NS);
    int* MO   = (int*)alloc((size_t)BHH * KLL * 4);

    u16* crossB = SPa;     // alias: crossBias lives in SPa between pv1 and fused2
    u16* iattB  = biasT;   // alias: iattBias lives in biasT after fused2

    dim3 blk(256);

    // weight transposes
    transpose_cast_k<<<dim3(48, 16), blk, 0, stream>>>(Wqkv,     WqkvT,   512, 1536);
    transpose_cast_k<<<dim3(48, 16), blk, 0, stream>>>(Wqkv_i,   WqkvIT,  512, 1536);
    transpose_cast_k<<<dim3(48, 16), blk, 0, stream>>>(Wqkv_i2,  WqkvI2T, 512, 1536);
    transpose_cast_k<<<dim3(16, 16), blk, 0, stream>>>(Wproj,    WprojT,  512, 512);
    transpose_cast_k<<<dim3(16, 16), blk, 0, stream>>>(Wproj_i,  WprojIT, 512, 512);
    transpose_cast_k<<<dim3(16, 16), blk, 0, stream>>>(Wproj_i2, WprojI2T,512, 512);

    // QKV projections (q pre-scaled by 0.125)
    cast_bf16_k<<<dim3(1024), blk, 0, stream>>>(x, Abf, (int)(NAX / 8));
    gemm_qkv_mfma_k<<<dim3(12, 32), blk, 0, stream>>>(Abf, WqkvT, Q, KX, VXt, 10);
    cast_bf16_k<<<dim3(256), blk, 0, stream>>>(kernal, Abf, (int)(NAK / 8));
    gemm_qkv_mfma_k<<<dim3(12, 8), blk, 0, stream>>>(Abf, WqkvT, KQ, KK, KVt, 8);
    cast_bf16_k<<<dim3(1024), blk, 0, stream>>>(i_x, Abf, (int)(NAX / 8));
    gemm_qkv_mfma_k<<<dim3(12, 32), blk, 0, stream>>>(Abf, WqkvIT, IQ, IK, IVt, 10);
    cast_bf16_k<<<dim3(256), blk, 0, stream>>>(i_kernal, Abf, (int)(NAK / 8));
    gemm_qkv_mfma_k<<<dim3(12, 8), blk, 0, stream>>>(Abf, WqkvIT, IKQ, IKK, IKVt, 8);

    // --- branch 1: k_out ---
    scores_mfma_k<<<dim3(8, 2, BHH), blk, 0, stream>>>(KQ, KX, SPa, KLL, XLL);
    main_ori_k8<<<dim3(BB * KLL), blk, 0, stream>>>(SPa, polar, MO);
    bias_build_k<<<dim3(32, 8, BB), blk, 0, stream>>>(rd, polar, att, dis, pemb, MO, biasT, bias1);
    softmax_wide_k<1><<<dim3(BHH * KLL), blk, 0, stream>>>(SPa, bias1, nullptr, 0.0f);
    pv_mfma_k<<<dim3(4, BHH), blk, 0, stream>>>(SPa, VXt, KMb, KLL, XLL);
    gemm_proj_mfma_k<false><<<dim3(4, 8), blk, 0, stream>>>(KMb, WprojT, bproj, 1.0f, k_out);

    // --- branch 2: x_out (fused dual attention; crossBias into SPa alias) ---
    mask_bias_k<<<dim3(8192), blk, 0, stream>>>(cross, crossB, (int)(NS / 4));
    attn_xk_fused_k<2><<<dim3(512), blk, 0, stream>>>(
        Q, KK, KVt, biasT, IKK, IKVt, crossB, XMb);
    gemm_proj_mfma_k<false><<<dim3(4, 32), blk, 0, stream>>>(XMb, WprojT, bproj, 2.0f, x_out);

    // --- branch 3: i_x_out (iatt conversions into biasT alias after fused2) ---
    conv_iatt_k<<<dim3(32, 8, BHH), blk, 0, stream>>>(i_att, iattT8, iattB);
    scores_mfma_k<<<dim3(8, 2, BHH), blk, 0, stream>>>(IKQ, IK, SPa, KLL, XLL);
    softmax_wide_k<0><<<dim3(BHH * KLL), blk, 0, stream>>>(SPa, nullptr, iattT8, -1e9f);
    pv_mfma_k<<<dim3(4, BHH), blk, 0, stream>>>(SPa, IVt, KMb, KLL, XLL);
    gemm_proj_mfma_k<true><<<dim3(4, 8), blk, 0, stream>>>(KMb, WprojIT, bproj_i, 1.0f, IKOUTb);
    gemm_qkv_mfma_k<<<dim3(12, 8), blk, 0, stream>>>(IKOUTb, WqkvI2T, nullptr, K2K, K2Vt, 8);
    attn_xk_fused_k<1><<<dim3(512), blk, 0, stream>>>(
        IQ, K2K, K2Vt, iattB, nullptr, nullptr, nullptr, XMb);
    gemm_proj_mfma_k<false><<<dim3(4, 32), blk, 0, stream>>>(XMb, WprojI2T, bproj_i2, 1.0f, i_x_out);

    (void)in_sizes; (void)n_in; (void)out_size; (void)ws_size;
}

// Round 8
// 456.527 us; speedup vs baseline: 1.0779x; 1.0166x over previous
//
#include <hip/hip_runtime.h>
#include <cstddef>
#include <cstdint>

#define BB 4
#define HH 8
#define HEADD 64
#define DIMM 512
#define XLL 1024
#define KLL 256
#define BHH (BB*HH)

typedef __attribute__((ext_vector_type(8))) short bf16x8;
typedef __attribute__((ext_vector_type(8))) unsigned short u16x8;
typedef __attribute__((ext_vector_type(4))) float f32x4;
typedef unsigned short u16;

__device__ __forceinline__ u16 f2b(float f) {
    unsigned int u = __builtin_bit_cast(unsigned int, f);
    u = u + 0x7fffu + ((u >> 16) & 1u);
    return (u16)(u >> 16);
}
__device__ __forceinline__ float b2f(u16 h) {
    unsigned int u = ((unsigned int)h) << 16;
    return __builtin_bit_cast(float, u);
}
__device__ __forceinline__ f32x4 mfma16(bf16x8 a, bf16x8 b, f32x4 c) {
    return __builtin_amdgcn_mfma_f32_16x16x32_bf16(a, b, c, 0, 0, 0);
}
__device__ __forceinline__ float wred_max(float v) {
    #pragma unroll
    for (int o = 1; o < 64; o <<= 1) v = fmaxf(v, __shfl_xor(v, o, 64));
    return v;
}
__device__ __forceinline__ float wred_sum(float v) {
    #pragma unroll
    for (int o = 1; o < 64; o <<= 1) v += __shfl_xor(v, o, 64);
    return v;
}

// Fragment-order bias layout:
//   E(bh,x,k) = ((bh*64 + (x>>4))*8 + (k>>5))*512
//             + (((x>>2)&3)*16 + (k&15))*8 + ((k>>4)&1)*4 + (x&3)
// so that in the fused kernel, wave strip s, lane l reads its 64 values as
// 8 contiguous 16B chunks at ((bh*64+s)*8+itp)*512 + l*8.

// ---------------------------------------------------------------------------
// f32 -> bf16 cast, 8 elems/thread
// ---------------------------------------------------------------------------
__global__ __launch_bounds__(256) void cast_bf16_k(
    const float* __restrict__ in, u16* __restrict__ out, int n8)
{
    int i = blockIdx.x * 256 + threadIdx.x;
    if (i >= n8) return;
    const float4* p = reinterpret_cast<const float4*>(in) + (size_t)i * 2;
    float4 a = p[0], b = p[1];
    u16x8 o;
    o[0] = f2b(a.x); o[1] = f2b(a.y); o[2] = f2b(a.z); o[3] = f2b(a.w);
    o[4] = f2b(b.x); o[5] = f2b(b.y); o[6] = f2b(b.z); o[7] = f2b(b.w);
    *reinterpret_cast<u16x8*>(out + (size_t)i * 8) = o;
}

// ---------------------------------------------------------------------------
// W [K][N] f32  ->  Wt [N][K] bf16
// ---------------------------------------------------------------------------
__global__ __launch_bounds__(256) void transpose_cast_k(
    const float* __restrict__ W, u16* __restrict__ Wt, int K, int N)
{
    __shared__ float t[32][33];
    int bx = blockIdx.x, by = blockIdx.y;
    int tx = threadIdx.x & 31, ty = threadIdx.x >> 5;
    #pragma unroll
    for (int r = ty; r < 32; r += 8)
        t[r][tx] = W[(size_t)(by * 32 + r) * N + bx * 32 + tx];
    __syncthreads();
    #pragma unroll
    for (int r = ty; r < 32; r += 8)
        Wt[(size_t)(bx * 32 + r) * K + by * 32 + tx] = f2b(t[tx][r]);
}

// ---------------------------------------------------------------------------
// i_att int32 [bh,x,k] -> iattT8 u8 [bh,k,x]  AND  fragment-order bf16 bias
// ---------------------------------------------------------------------------
__global__ __launch_bounds__(256) void conv_iatt_k(
    const int* __restrict__ m, unsigned char* __restrict__ mt,
    u16* __restrict__ mbF)
{
    __shared__ unsigned char t[32][33];   // [x][k]
    const int bh = blockIdx.z, xt = blockIdx.x, kt = blockIdx.y;
    const int tid = threadIdx.x;
    const int tx = tid & 31, ty = tid >> 5;
    const u16 NEG = f2b(-1e9f);
    #pragma unroll
    for (int r = ty; r < 32; r += 8)
        t[r][tx] = (unsigned char)(m[((size_t)bh * 1024 + xt * 32 + r) * 256 + kt * 32 + tx] != 0);
    __syncthreads();
    #pragma unroll
    for (int r = ty; r < 32; r += 8)
        mt[((size_t)bh * 256 + kt * 32 + r) * 1024 + xt * 32 + tx] = t[tx][r];
    // fragment-order output
    const int sl = tid >> 7, rem = tid & 127, l = rem >> 1, nilow = rem & 1;
    const int lg = l >> 4, lr_ = l & 15;
    const int xl0 = sl * 16 + lg * 4, kl = nilow * 16 + lr_;
    ushort4 o;
    o.x = t[xl0 + 0][kl] ? NEG : (u16)0;
    o.y = t[xl0 + 1][kl] ? NEG : (u16)0;
    o.z = t[xl0 + 2][kl] ? NEG : (u16)0;
    o.w = t[xl0 + 3][kl] ? NEG : (u16)0;
    size_t eb = (((size_t)bh * 64 + xt * 2 + sl) * 8 + kt) * 512 + (size_t)l * 8 + nilow * 4;
    *reinterpret_cast<ushort4*>(mbF + eb) = o;
}

// ---------------------------------------------------------------------------
// mask int32 [bh,x,k] -> fragment-order bf16 bias (0 / -1e9)
// ---------------------------------------------------------------------------
__global__ __launch_bounds__(256) void mask_biasF_k(
    const int* __restrict__ m, u16* __restrict__ oF)
{
    const int bh = blockIdx.z, xt = blockIdx.x, kt = blockIdx.y;
    const int tid = threadIdx.x;
    const u16 NEG = f2b(-1e9f);
    const int sl = tid >> 7, rem = tid & 127, l = rem >> 1, nilow = rem & 1;
    const int lg = l >> 4, lr_ = l & 15;
    const int xl0 = sl * 16 + lg * 4, kl = nilow * 16 + lr_;
    const int kg = kt * 32 + kl;
    u16 o_[4];
    #pragma unroll
    for (int j = 0; j < 4; ++j) {
        int mm = m[((size_t)bh * 1024 + xt * 32 + xl0 + j) * 256 + kg];
        o_[j] = mm ? NEG : (u16)0;
    }
    ushort4 o; o.x = o_[0]; o.y = o_[1]; o.z = o_[2]; o.w = o_[3];
    size_t eb = (((size_t)bh * 64 + xt * 2 + sl) * 8 + kt) * 512 + (size_t)l * 8 + nilow * 4;
    *reinterpret_cast<ushort4*>(oF + eb) = o;
}

// ---------------------------------------------------------------------------
// main orientation: block per (b,k); reads polar row once, loops 8 heads.
// ---------------------------------------------------------------------------
__global__ __launch_bounds__(256) void main_ori_k8(
    const u16* __restrict__ S, const int* __restrict__ polar,
    int* __restrict__ MO)
{
    const int blk = blockIdx.x;          // b*256 + k
    const int b = blk >> 8, k = blk & 255;
    const int tid = threadIdx.x;
    const int wave = tid >> 6, lane = tid & 63;
    const int c = tid * 4;
    int4 p4 = *reinterpret_cast<const int4*>(polar + ((size_t)b * 256 + k) * 1024 + c);
    int pp[4] = { p4.x, p4.y, p4.z, p4.w };
    #pragma unroll
    for (int j = 0; j < 4; ++j) { int p = pp[j]; pp[j] = p < 0 ? 0 : (p > 7 ? 7 : p); }
    __shared__ float sred[4][8];
    for (int h = 0; h < 8; ++h) {
        const int bh = b * 8 + h;
        ushort4 sv = *reinterpret_cast<const ushort4*>(S + ((size_t)bh * 256 + k) * 1024 + c);
        float av[4] = { fabsf(b2f(sv.x)), fabsf(b2f(sv.y)), fabsf(b2f(sv.z)), fabsf(b2f(sv.w)) };
        float bins[8] = {};
        #pragma unroll
        for (int j = 0; j < 4; ++j) {
            #pragma unroll
            for (int o = 0; o < 8; ++o) bins[o] += (pp[j] == o) ? av[j] : 0.0f;
        }
        #pragma unroll
        for (int o = 0; o < 8; ++o) bins[o] = wred_sum(bins[o]);
        if (lane == 0) {
            #pragma unroll
            for (int o = 0; o < 8; ++o) sred[wave][o] = bins[o];
        }
        __syncthreads();
        if (tid == 0) {
            int best = 0; float bv = -1.0f;
            #pragma unroll
            for (int o = 0; o < 8; ++o) {
                float s = sred[0][o] + sred[1][o] + sred[2][o] + sred[3][o];
                if (s > bv) { bv = s; best = o; }
            }
            MO[bh * 256 + k] = best;
        }
        __syncthreads();
    }
}

// ---------------------------------------------------------------------------
// Combined bias build (after MO): per (b, x-tile32, k-tile32), all 8 heads:
//   v = dis[rd]+pemb[(polar-MO)&7]
//   biasF (fragment order) = att ? -1e9 : v   (branch 2 fused)
//   bias1 [bh,k,x]         = att ? -1e6 : v   (branch 1 wide)
// ---------------------------------------------------------------------------
__global__ __launch_bounds__(256) void bias_build_k(
    const int* __restrict__ rd, const int* __restrict__ polar,
    const int* __restrict__ att, const float* __restrict__ dis,
    const float* __restrict__ pemb, const int* __restrict__ MO,
    u16* __restrict__ biasF, u16* __restrict__ bias1)
{
    const int b = blockIdx.z;
    const int xt = blockIdx.x * 32, kt = blockIdx.y * 32;
    const int tid = threadIdx.x;
    __shared__ float dsh[528];
    __shared__ int rds[32][33];   // [x][k]
    __shared__ int pls[32][33];
    __shared__ u16 bt[32][33];    // -1e6 variant [x][k]
    for (int i = tid; i < 528; i += 256) dsh[i] = dis[i];
    const int tx = tid & 31, ty = tid >> 5;
    #pragma unroll
    for (int r = ty; r < 32; r += 8) {
        size_t src = ((size_t)b * 256 + kt + r) * 1024 + xt + tx;  // rd[b,k,x]
        rds[tx][r] = rd[src];
        int p = polar[src]; pls[tx][r] = p < 0 ? 0 : (p > 7 ? 7 : p);
    }
    float pe[8];
    #pragma unroll
    for (int o = 0; o < 8; ++o) pe[o] = pemb[o];
    __syncthreads();
    const int sl = tid >> 7, rem = tid & 127, l = rem >> 1, nilow = rem & 1;
    const int lg = l >> 4, lr_ = l & 15;
    const int xl0 = sl * 16 + lg * 4, kl = nilow * 16 + lr_;
    const int kg = kt + kl;
    const u16 NEG9 = f2b(-1e9f), NEG6 = f2b(-1e6f);
    for (int h = 0; h < 8; ++h) {
        const int bh = b * 8 + h;
        int mo = MO[bh * 256 + kg];
        u16 o9[4];
        #pragma unroll
        for (int j = 0; j < 4; ++j) {
            int xl = xl0 + j;
            int mm = att[((size_t)bh * 1024 + xt + xl) * 256 + kg];
            float v = dsh[rds[xl][kl] * 8 + h] + pe[(pls[xl][kl] - mo + 8) & 7];
            u16 vb = f2b(v);
            o9[j] = mm ? NEG9 : vb;
            bt[xl][kl] = mm ? NEG6 : vb;
        }
        size_t eb = (((size_t)bh * 64 + (xt >> 4) + sl) * 8 + (kt >> 5)) * 512 + (size_t)l * 8 + nilow * 4;
        ushort4 ov; ov.x = o9[0]; ov.y = o9[1]; ov.z = o9[2]; ov.w = o9[3];
        *reinterpret_cast<ushort4*>(biasF + eb) = ov;
        __syncthreads();
        const int k_ = tid >> 3, x4 = (tid & 7) * 4;
        ushort4 o2;
        o2.x = bt[x4 + 0][k_]; o2.y = bt[x4 + 1][k_];
        o2.z = bt[x4 + 2][k_]; o2.w = bt[x4 + 3][k_];
        *reinterpret_cast<ushort4*>(bias1 + ((size_t)bh * 256 + kt + k_) * 1024 + xt + x4) = o2;
        __syncthreads();
    }
}

// ---------------------------------------------------------------------------
// QKV GEMM: A bf16 [M,512] @ Wt bf16 [1536,512]^T; q pre-scaled by 0.125.
// q,k -> [b,h,n,64] bf16; v -> [b,h,64,n] bf16 (transposed)
// ---------------------------------------------------------------------------
__global__ __launch_bounds__(256) void gemm_qkv_mfma_k(
    const u16* __restrict__ A, const u16* __restrict__ Wt,
    u16* __restrict__ qb, u16* __restrict__ kb, u16* __restrict__ vt,
    int sl)
{
    __shared__ __align__(16) short As[128][72];
    __shared__ __align__(16) short Bs[128][72];
    const int tid = threadIdx.x;
    const int wave = tid >> 6, lane = tid & 63;
    const int lr = lane & 15, lk = (lane >> 4) * 8;
    const int rb = blockIdx.y * 128, cb = blockIdx.x * 128;
    const int wr = (wave >> 1) * 64, wc = (wave & 1) * 64;
    const int seq = 1 << sl, smask = seq - 1;
    f32x4 acc[4][4] = {};
    const int srow = tid >> 3, skc = (tid & 7) * 8;
    for (int k0 = 0; k0 < 512; k0 += 64) {
        #pragma unroll
        for (int it = 0; it < 4; ++it) {
            int row = it * 32 + srow;
            *reinterpret_cast<bf16x8*>(&As[row][skc]) =
                *reinterpret_cast<const bf16x8*>(A + (size_t)(rb + row) * 512 + k0 + skc);
            *reinterpret_cast<bf16x8*>(&Bs[row][skc]) =
                *reinterpret_cast<const bf16x8*>(Wt + (size_t)(cb + row) * 512 + k0 + skc);
        }
        __syncthreads();
        #pragma unroll
        for (int ks = 0; ks < 2; ++ks) {
            bf16x8 af[4], bf_[4];
            #pragma unroll
            for (int mi = 0; mi < 4; ++mi)
                af[mi] = *reinterpret_cast<const bf16x8*>(&As[wr + mi * 16 + lr][ks * 32 + lk]);
            #pragma unroll
            for (int ni = 0; ni < 4; ++ni)
                bf_[ni] = *reinterpret_cast<const bf16x8*>(&Bs[wc + ni * 16 + lr][ks * 32 + lk]);
            #pragma unroll
            for (int mi = 0; mi < 4; ++mi)
                #pragma unroll
                for (int ni = 0; ni < 4; ++ni)
                    acc[mi][ni] = mfma16(af[mi], bf_[ni], acc[mi][ni]);
        }
        __syncthreads();
    }
    #pragma unroll
    for (int mi = 0; mi < 4; ++mi) {
        int m0 = rb + wr + mi * 16 + (lane >> 4) * 4;
        #pragma unroll
        for (int ni = 0; ni < 4; ++ni) {
            int c = cb + wc + ni * 16 + lr;
            int which = c >> 9, h = (c >> 6) & 7, d = c & 63;
            f32x4 v = acc[mi][ni];
            #pragma unroll
            for (int j = 0; j < 4; ++j) {
                int mm = m0 + j;
                int b = mm >> sl, n = mm & smask;
                if (which == 0) {
                    if (qb) qb[(((size_t)b * HH + h) * seq + n) * 64 + d] = f2b(v[j] * 0.125f);
                } else if (which == 1) {
                    if (kb) kb[(((size_t)b * HH + h) * seq + n) * 64 + d] = f2b(v[j]);
                } else {
                    vt[(((size_t)b * HH + h) * 64 + d) * seq + n] = f2b(v[j]);
                }
            }
        }
    }
}

// ---------------------------------------------------------------------------
// Proj GEMM: A bf16 [M,512] @ Wt bf16 [512,512]^T + bscale*bias
// ---------------------------------------------------------------------------
template<bool OUTBF>
__global__ __launch_bounds__(256) void gemm_proj_mfma_k(
    const u16* __restrict__ A, const u16* __restrict__ Wt,
    const float* __restrict__ bias, float bscale, void* __restrict__ outp)
{
    __shared__ __align__(16) short As[128][72];
    __shared__ __align__(16) short Bs[128][72];
    const int tid = threadIdx.x;
    const int wave = tid >> 6, lane = tid & 63;
    const int lr = lane & 15, lk = (lane >> 4) * 8;
    const int rb = blockIdx.y * 128, cb = blockIdx.x * 128;
    const int wr = (wave >> 1) * 64, wc = (wave & 1) * 64;
    f32x4 acc[4][4] = {};
    const int srow = tid >> 3, skc = (tid & 7) * 8;
    for (int k0 = 0; k0 < 512; k0 += 64) {
        #pragma unroll
        for (int it = 0; it < 4; ++it) {
            int row = it * 32 + srow;
            *reinterpret_cast<bf16x8*>(&As[row][skc]) =
                *reinterpret_cast<const bf16x8*>(A + (size_t)(rb + row) * 512 + k0 + skc);
            *reinterpret_cast<bf16x8*>(&Bs[row][skc]) =
                *reinterpret_cast<const bf16x8*>(Wt + (size_t)(cb + row) * 512 + k0 + skc);
        }
        __syncthreads();
        #pragma unroll
        for (int ks = 0; ks < 2; ++ks) {
            bf16x8 af[4], bf_[4];
            #pragma unroll
            for (int mi = 0; mi < 4; ++mi)
                af[mi] = *reinterpret_cast<const bf16x8*>(&As[wr + mi * 16 + lr][ks * 32 + lk]);
            #pragma unroll
            for (int ni = 0; ni < 4; ++ni)
                bf_[ni] = *reinterpret_cast<const bf16x8*>(&Bs[wc + ni * 16 + lr][ks * 32 + lk]);
            #pragma unroll
            for (int mi = 0; mi < 4; ++mi)
                #pragma unroll
                for (int ni = 0; ni < 4; ++ni)
                    acc[mi][ni] = mfma16(af[mi], bf_[ni], acc[mi][ni]);
        }
        __syncthreads();
    }
    #pragma unroll
    for (int mi = 0; mi < 4; ++mi) {
        int m0 = rb + wr + mi * 16 + (lane >> 4) * 4;
        #pragma unroll
        for (int ni = 0; ni < 4; ++ni) {
            int c = cb + wc + ni * 16 + lr;
            float bv = bscale * bias[c];
            f32x4 v = acc[mi][ni];
            #pragma unroll
            for (int j = 0; j < 4; ++j) {
                size_t o = (size_t)(m0 + j) * 512 + c;
                if (OUTBF) reinterpret_cast<u16*>(outp)[o] = f2b(v[j] + bv);
                else       reinterpret_cast<float*>(outp)[o] = v[j] + bv;
            }
        }
    }
}

// ---------------------------------------------------------------------------
// Scores: S[bh,r,c] = Aq[bh,r,:64] . Bk[bh,c,:64] (q pre-scaled), bf16 out
// ---------------------------------------------------------------------------
__global__ __launch_bounds__(256) void scores_mfma_k(
    const u16* __restrict__ Aq, const u16* __restrict__ Bk,
    u16* __restrict__ S, int R, int C)
{
    __shared__ __align__(16) short As[128][72];
    __shared__ __align__(16) short Bs[128][72];
    const int tid = threadIdx.x;
    const int wave = tid >> 6, lane = tid & 63;
    const int lr = lane & 15, lk = (lane >> 4) * 8;
    const int bh = blockIdx.z;
    const int rb = blockIdx.y * 128, cb = blockIdx.x * 128;
    const int wr = (wave >> 1) * 64, wc = (wave & 1) * 64;
    const u16* Ap = Aq + (size_t)bh * R * 64;
    const u16* Bp = Bk + (size_t)bh * C * 64;
    const int srow = tid >> 3, skc = (tid & 7) * 8;
    #pragma unroll
    for (int it = 0; it < 4; ++it) {
        int row = it * 32 + srow;
        *reinterpret_cast<bf16x8*>(&As[row][skc]) =
            *reinterpret_cast<const bf16x8*>(Ap + (size_t)(rb + row) * 64 + skc);
        *reinterpret_cast<bf16x8*>(&Bs[row][skc]) =
            *reinterpret_cast<const bf16x8*>(Bp + (size_t)(cb + row) * 64 + skc);
    }
    __syncthreads();
    f32x4 acc[4][4] = {};
    #pragma unroll
    for (int ks = 0; ks < 2; ++ks) {
        bf16x8 af[4], bf_[4];
        #pragma unroll
        for (int mi = 0; mi < 4; ++mi)
            af[mi] = *reinterpret_cast<const bf16x8*>(&As[wr + mi * 16 + lr][ks * 32 + lk]);
        #pragma unroll
        for (int ni = 0; ni < 4; ++ni)
            bf_[ni] = *reinterpret_cast<const bf16x8*>(&Bs[wc + ni * 16 + lr][ks * 32 + lk]);
        #pragma unroll
        for (int mi = 0; mi < 4; ++mi)
            #pragma unroll
            for (int ni = 0; ni < 4; ++ni)
                acc[mi][ni] = mfma16(af[mi], bf_[ni], acc[mi][ni]);
    }
    #pragma unroll
    for (int mi = 0; mi < 4; ++mi) {
        int r0 = rb + wr + mi * 16 + (lane >> 4) * 4;
        #pragma unroll
        for (int ni = 0; ni < 4; ++ni) {
            int c = cb + wc + ni * 16 + lr;
            f32x4 v = acc[mi][ni];
            #pragma unroll
            for (int j = 0; j < 4; ++j)
                S[((size_t)bh * R + r0 + j) * C + c] = f2b(v[j]);
        }
    }
}

// ---------------------------------------------------------------------------
// PV (wide path): out[b,r,h*64+d] = P[bh,r,:C] @ V[bh,:C,d]; Vt [bh,64,C]
// ---------------------------------------------------------------------------
__global__ __launch_bounds__(256) void pv_mfma_k(
    const u16* __restrict__ P1, const u16* __restrict__ V1t,
    u16* __restrict__ out, int R, int C)
{
    __shared__ __align__(16) short As[64][72];
    __shared__ __align__(16) short Bs[64][72];
    const int tid = threadIdx.x;
    const int wave = tid >> 6, lane = tid & 63;
    const int lr = lane & 15, lg = lane >> 4, lk = lg * 8;
    const int bh = blockIdx.y, b = bh >> 3, h = bh & 7;
    const int rb = blockIdx.x * 64;
    const int wr = wave * 16;
    f32x4 acc[4] = {};
    const u16* Pb = P1 + ((size_t)bh * R + rb) * C;
    const u16* Vb = V1t + (size_t)bh * 64 * C;
    for (int c0 = 0; c0 < C; c0 += 64) {
        #pragma unroll
        for (int it = 0; it < 2; ++it) {
            int chunk = tid + it * 256;
            int r_ = chunk >> 3, c8 = (chunk & 7) * 8;
            *reinterpret_cast<bf16x8*>(&As[r_][c8]) =
                *reinterpret_cast<const bf16x8*>(Pb + (size_t)r_ * C + c0 + c8);
            *reinterpret_cast<bf16x8*>(&Bs[r_][c8]) =
                *reinterpret_cast<const bf16x8*>(Vb + (size_t)r_ * C + c0 + c8);
        }
        __syncthreads();
        #pragma unroll
        for (int ks = 0; ks < 2; ++ks) {
            bf16x8 ap = *reinterpret_cast<const bf16x8*>(&As[wr + lr][ks * 32 + lk]);
            #pragma unroll
            for (int ni = 0; ni < 4; ++ni) {
                bf16x8 bv = *reinterpret_cast<const bf16x8*>(&Bs[ni * 16 + lr][ks * 32 + lk]);
                acc[ni] = mfma16(ap, bv, acc[ni]);
            }
        }
        __syncthreads();
    }
    #pragma unroll
    for (int ni = 0; ni < 4; ++ni) {
        int d = ni * 16 + lr;
        f32x4 v = acc[ni];
        #pragma unroll
        for (int j = 0; j < 4; ++j) {
            int r0 = rb + wr + lg * 4 + j;
            out[((size_t)(b * R + r0)) * 512 + h * 64 + d] = f2b(v[j]);
        }
    }
}

// ---------------------------------------------------------------------------
// Wide softmax over 1024-col rows of S. BIASMODE 1: add bf16 bias row
// (mask folded in). BIASMODE 0: u8 maskT row -> maskval.
// ---------------------------------------------------------------------------
template<int BIASMODE>
__global__ __launch_bounds__(256) void softmax_wide_k(
    u16* __restrict__ S, const u16* __restrict__ bias,
    const unsigned char* __restrict__ maskT, float maskval)
{
    const int row_g = blockIdx.x;
    const int tid = threadIdx.x;
    const int wave = tid >> 6, lane = tid & 63;
    const int c = tid * 4;
    u16* rowp = S + (size_t)row_g * 1024;
    ushort4 sv = *reinterpret_cast<const ushort4*>(rowp + c);
    float s[4] = { b2f(sv.x), b2f(sv.y), b2f(sv.z), b2f(sv.w) };
    if (BIASMODE) {
        ushort4 bv = *reinterpret_cast<const ushort4*>(bias + (size_t)row_g * 1024 + c);
        s[0] += b2f(bv.x); s[1] += b2f(bv.y); s[2] += b2f(bv.z); s[3] += b2f(bv.w);
    } else {
        uchar4 mk = *reinterpret_cast<const uchar4*>(maskT + (size_t)row_g * 1024 + c);
        if (mk.x) s[0] = maskval; if (mk.y) s[1] = maskval;
        if (mk.z) s[2] = maskval; if (mk.w) s[3] = maskval;
    }
    __shared__ float swv[4];
    float lm = fmaxf(fmaxf(s[0], s[1]), fmaxf(s[2], s[3]));
    lm = wred_max(lm);
    if (lane == 0) swv[wave] = lm;
    __syncthreads();
    float m = fmaxf(fmaxf(swv[0], swv[1]), fmaxf(swv[2], swv[3]));
    __syncthreads();
    float ls = 0.0f;
    #pragma unroll
    for (int j = 0; j < 4; ++j) { s[j] = __expf(s[j] - m); ls += s[j]; }
    ls = wred_sum(ls);
    if (lane == 0) swv[wave] = ls;
    __syncthreads();
    float inv = 1.0f / (swv[0] + swv[1] + swv[2] + swv[3]);
    ushort4 ov = { f2b(s[0] * inv), f2b(s[1] * inv), f2b(s[2] * inv), f2b(s[3] * inv) };
    *reinterpret_cast<ushort4*>(rowp + c) = ov;
}

// ---------------------------------------------------------------------------
// Fused attention v5: 64 x-rows/block, 4 waves, wave owns 16 rows.
// Q in regs; V direct from global; bias in FRAGMENT ORDER applied from regs
// (no LDS bounce). LDS: K 36864 + wave-local P 33792 = 70656 B.
// 2 barriers per source. Grid 512 blocks, XCD-swizzled.
// ---------------------------------------------------------------------------
template<int NSRC>
__global__ __launch_bounds__(256) void attn_xk_fused_k(
    const u16* __restrict__ Qp,
    const u16* __restrict__ K1, const u16* __restrict__ V1t, const u16* __restrict__ B1F,
    const u16* __restrict__ K2, const u16* __restrict__ V2t, const u16* __restrict__ B2F,
    u16* __restrict__ outm)
{
    const int tid = threadIdx.x;
    const int w = tid >> 6, lane = tid & 63;
    const int lr = lane & 15, lg = lane >> 4, lk = lg * 8;
    const int lin = blockIdx.x;
    const int xcd = lin & 7, idx = lin >> 3;
    const int bh = xcd * 4 + (idx & 3);
    const int rb = (idx >> 2) * 64;
    const int b = bh >> 3, h = bh & 7;
    const int wr = w * 16;                       // wave's row strip
    const int strip = (rb >> 4) + w;             // global strip index

    __shared__ __align__(16) short Ks[256 * 72];   // 36864 B
    __shared__ __align__(16) short Ps[64 * 264];   // 33792 B (wave-local rows)

    // Q fragments in registers (wave-local rows), loaded once
    bf16x8 qf0, qf1;
    {
        const u16* Qb = Qp + ((size_t)bh * 1024 + rb + wr + lr) * 64;
        qf0 = *reinterpret_cast<const bf16x8*>(Qb + lk);
        qf1 = *reinterpret_cast<const bf16x8*>(Qb + 32 + lk);
    }

    f32x4 acc2[4] = {};

    #pragma unroll
    for (int s = 0; s < NSRC; ++s) {
        const u16* Kp = s ? K2 : K1;
        const u16* Vp = s ? V2t : V1t;
        const u16* BF = s ? B2F : B1F;
        // bias prefetch (fragment order): 8 x 16B fully-coalesced loads
        bf16x8 breg[8];
        {
            const u16* bb = BF + (((size_t)bh * 64 + strip) * 8) * 512 + (size_t)lane * 8;
            #pragma unroll
            for (int itp = 0; itp < 8; ++itp)
                breg[itp] = *reinterpret_cast<const bf16x8*>(bb + (size_t)itp * 512);
        }
        __syncthreads();   // (A) prev source's K reads complete
        // stage K [256][64]
        #pragma unroll
        for (int it = 0; it < 8; ++it) {
            int chunk = tid + it * 256;
            int r_ = chunk >> 3, c8 = (chunk & 7) * 8;
            *reinterpret_cast<bf16x8*>(&Ks[r_ * 72 + c8]) =
                *reinterpret_cast<const bf16x8*>(Kp + ((size_t)bh * 256 + r_) * 64 + c8);
        }
        __syncthreads();   // (B) K ready
        // scores: 16 rows x 256 cols per wave (q pre-scaled)
        f32x4 acc[16];
        #pragma unroll
        for (int ni = 0; ni < 16; ++ni) acc[ni] = (f32x4){0.f, 0.f, 0.f, 0.f};
        #pragma unroll
        for (int ni = 0; ni < 16; ++ni) {
            bf16x8 b0 = *reinterpret_cast<const bf16x8*>(&Ks[(ni * 16 + lr) * 72 + lk]);
            acc[ni] = mfma16(qf0, b0, acc[ni]);
        }
        #pragma unroll
        for (int ni = 0; ni < 16; ++ni) {
            bf16x8 b1 = *reinterpret_cast<const bf16x8*>(&Ks[(ni * 16 + lr) * 72 + 32 + lk]);
            acc[ni] = mfma16(qf1, b1, acc[ni]);
        }
        // apply bias from regs + in-wave softmax (rows wr+lg*4+j, cols ni*16+lr)
        float mx[4] = { -3.4e38f, -3.4e38f, -3.4e38f, -3.4e38f };
        #pragma unroll
        for (int ni = 0; ni < 16; ++ni) {
            const bf16x8 br = breg[ni >> 1];
            #pragma unroll
            for (int j = 0; j < 4; ++j) {
                float v = acc[ni][j] + b2f((u16)br[(ni & 1) * 4 + j]);
                acc[ni][j] = v;
                mx[j] = fmaxf(mx[j], v);
            }
        }
        #pragma unroll
        for (int j = 0; j < 4; ++j) {
            #pragma unroll
            for (int o = 1; o < 16; o <<= 1) mx[j] = fmaxf(mx[j], __shfl_xor(mx[j], o, 64));
        }
        float sm[4] = {};
        #pragma unroll
        for (int ni = 0; ni < 16; ++ni) {
            #pragma unroll
            for (int j = 0; j < 4; ++j) {
                float e = __expf(acc[ni][j] - mx[j]);
                acc[ni][j] = e;
                sm[j] += e;
            }
        }
        #pragma unroll
        for (int j = 0; j < 4; ++j) {
            #pragma unroll
            for (int o = 1; o < 16; o <<= 1) sm[j] += __shfl_xor(sm[j], o, 64);
            sm[j] = 1.0f / sm[j];
        }
        // write P to wave-local LDS rows (transpose for PV A-fragment)
        #pragma unroll
        for (int ni = 0; ni < 16; ++ni)
            #pragma unroll
            for (int j = 0; j < 4; ++j)
                Ps[(wr + lg * 4 + j) * 264 + ni * 16 + lr] = (short)f2b(acc[ni][j] * sm[j]);
        // PV: 16 rows x 64 d per wave, K=256; V direct from global (L2)
        #pragma unroll
        for (int kc = 0; kc < 8; ++kc) {
            bf16x8 ap = *reinterpret_cast<const bf16x8*>(&Ps[(wr + lr) * 264 + kc * 32 + lk]);
            #pragma unroll
            for (int ni = 0; ni < 4; ++ni) {
                bf16x8 vv = *reinterpret_cast<const bf16x8*>(
                    Vp + ((size_t)bh * 64 + ni * 16 + lr) * 256 + kc * 32 + lk);
                acc2[ni] = mfma16(ap, vv, acc2[ni]);
            }
        }
    }
    // epilogue: merged bf16 out [b, x, 512]
    #pragma unroll
    for (int ni = 0; ni < 4; ++ni) {
        int d = ni * 16 + lr;
        f32x4 v = acc2[ni];
        #pragma unroll
        for (int j = 0; j < 4; ++j) {
            int row = rb + wr + lg * 4 + j;
            outm[((size_t)(b * 1024 + row)) * 512 + h * 64 + d] = f2b(v[j]);
        }
    }
}

// ---------------------------------------------------------------------------
extern "C" void kernel_launch(void* const* d_in, const int* in_sizes, int n_in,
                              void* d_out, int out_size, void* d_ws, size_t ws_size,
                              hipStream_t stream)
{
    const float* x        = (const float*)d_in[0];
    const float* kernal   = (const float*)d_in[1];
    const float* i_x      = (const float*)d_in[2];
    const float* i_kernal = (const float*)d_in[3];
    const int*   rd       = (const int*)d_in[4];
    const int*   polar    = (const int*)d_in[5];
    const int*   att      = (const int*)d_in[6];
    const int*   i_att    = (const int*)d_in[7];
    const int*   cross    = (const int*)d_in[8];
    const float* Wqkv     = (const float*)d_in[9];
    const float* Wqkv_i   = (const float*)d_in[10];
    const float* Wqkv_i2  = (const float*)d_in[11];
    const float* Wproj    = (const float*)d_in[12];
    const float* bproj    = (const float*)d_in[13];
    const float* Wproj_i  = (const float*)d_in[14];
    const float* bproj_i  = (const float*)d_in[15];
    const float* Wproj_i2 = (const float*)d_in[16];
    const float* bproj_i2 = (const float*)d_in[17];
    const float* dis      = (const float*)d_in[18];
    const float* pemb     = (const float*)d_in[19];

    float* out = (float*)d_out;
    float* x_out   = out;
    float* k_out   = out + (size_t)BB * XLL * DIMM;
    float* i_x_out = k_out + (size_t)BB * KLL * DIMM;

    char* ws = (char*)d_ws;
    size_t off = 0;
    auto alloc = [&](size_t bytes) { void* p = ws + off; off += (bytes + 255) & ~(size_t)255; return p; };

    const size_t NAX = (size_t)BB * XLL * DIMM;
    const size_t NAK = (size_t)BB * KLL * DIMM;
    const size_t NHX = (size_t)BHH * XLL * HEADD;
    const size_t NHK = (size_t)BHH * KLL * HEADD;
    const size_t NS  = (size_t)BHH * KLL * XLL;

    u16* WqkvT     = (u16*)alloc((size_t)1536 * 512 * 2);
    u16* WqkvIT    = (u16*)alloc((size_t)1536 * 512 * 2);
    u16* WqkvI2T   = (u16*)alloc((size_t)1536 * 512 * 2);
    u16* WprojT    = (u16*)alloc((size_t)512 * 512 * 2);
    u16* WprojIT   = (u16*)alloc((size_t)512 * 512 * 2);
    u16* WprojI2T  = (u16*)alloc((size_t)512 * 512 * 2);
    u16* Abf  = (u16*)alloc(NAX * 2);
    u16* Q    = (u16*)alloc(NHX * 2);
    u16* KX   = (u16*)alloc(NHX * 2);
    u16* VXt  = (u16*)alloc(NHX * 2);
    u16* KQ   = (u16*)alloc(NHK * 2);
    u16* KK   = (u16*)alloc(NHK * 2);
    u16* KVt  = (u16*)alloc(NHK * 2);
    u16* IQ   = (u16*)alloc(NHX * 2);
    u16* IK   = (u16*)alloc(NHX * 2);
    u16* IVt  = (u16*)alloc(NHX * 2);
    u16* IKQ  = (u16*)alloc(NHK * 2);
    u16* IKK  = (u16*)alloc(NHK * 2);
    u16* IKVt = (u16*)alloc(NHK * 2);
    u16* K2K  = (u16*)alloc(NHK * 2);
    u16* K2Vt = (u16*)alloc(NHK * 2);
    u16* SPa  = (u16*)alloc(NS * 2);      // S (branches 1,3) / crossBiasF (branch 2 src1)
    u16* KMb  = (u16*)alloc(NAK * 2);
    u16* XMb  = (u16*)alloc(NAX * 2);
    u16* IKOUTb = (u16*)alloc(NAK * 2);
    u16* biasF = (u16*)alloc(NS * 2);     // branch2 fragment bias / later iattBiasF
    u16* bias1 = (u16*)alloc(NS * 2);     // branch1 bias [bh,k,x]
    unsigned char* iattT8 = (unsigned char*)alloc(NS);
    int* MO   = (int*)alloc((size_t)BHH * KLL * 4);

    u16* crossBF = SPa;    // alias: lives in SPa between pv1 and fused2
    u16* iattBF  = biasF;  // alias: lives in biasF after fused2

    dim3 blk(256);

    // weight transposes
    transpose_cast_k<<<dim3(48, 16), blk, 0, stream>>>(Wqkv,     WqkvT,   512, 1536);
    transpose_cast_k<<<dim3(48, 16), blk, 0, stream>>>(Wqkv_i,   WqkvIT,  512, 1536);
    transpose_cast_k<<<dim3(48, 16), blk, 0, stream>>>(Wqkv_i2,  WqkvI2T, 512, 1536);
    transpose_cast_k<<<dim3(16, 16), blk, 0, stream>>>(Wproj,    WprojT,  512, 512);
    transpose_cast_k<<<dim3(16, 16), blk, 0, stream>>>(Wproj_i,  WprojIT, 512, 512);
    transpose_cast_k<<<dim3(16, 16), blk, 0, stream>>>(Wproj_i2, WprojI2T,512, 512);

    // QKV projections (q pre-scaled by 0.125)
    cast_bf16_k<<<dim3(1024), blk, 0, stream>>>(x, Abf, (int)(NAX / 8));
    gemm_qkv_mfma_k<<<dim3(12, 32), blk, 0, stream>>>(Abf, WqkvT, Q, KX, VXt, 10);
    cast_bf16_k<<<dim3(256), blk, 0, stream>>>(kernal, Abf, (int)(NAK / 8));
    gemm_qkv_mfma_k<<<dim3(12, 8), blk, 0, stream>>>(Abf, WqkvT, KQ, KK, KVt, 8);
    cast_bf16_k<<<dim3(1024), blk, 0, stream>>>(i_x, Abf, (int)(NAX / 8));
    gemm_qkv_mfma_k<<<dim3(12, 32), blk, 0, stream>>>(Abf, WqkvIT, IQ, IK, IVt, 10);
    cast_bf16_k<<<dim3(256), blk, 0, stream>>>(i_kernal, Abf, (int)(NAK / 8));
    gemm_qkv_mfma_k<<<dim3(12, 8), blk, 0, stream>>>(Abf, WqkvIT, IKQ, IKK, IKVt, 8);

    // --- branch 1: k_out ---
    scores_mfma_k<<<dim3(8, 2, BHH), blk, 0, stream>>>(KQ, KX, SPa, KLL, XLL);
    main_ori_k8<<<dim3(BB * KLL), blk, 0, stream>>>(SPa, polar, MO);
    bias_build_k<<<dim3(32, 8, BB), blk, 0, stream>>>(rd, polar, att, dis, pemb, MO, biasF, bias1);
    softmax_wide_k<1><<<dim3(BHH * KLL), blk, 0, stream>>>(SPa, bias1, nullptr, 0.0f);
    pv_mfma_k<<<dim3(4, BHH), blk, 0, stream>>>(SPa, VXt, KMb, KLL, XLL);
    gemm_proj_mfma_k<false><<<dim3(4, 8), blk, 0, stream>>>(KMb, WprojT, bproj, 1.0f, k_out);

    // --- branch 2: x_out (fused dual attention; crossBiasF into SPa alias) ---
    mask_biasF_k<<<dim3(32, 8, BHH), blk, 0, stream>>>(cross, crossBF);
    attn_xk_fused_k<2><<<dim3(512), blk, 0, stream>>>(
        Q, KK, KVt, biasF, IKK, IKVt, crossBF, XMb);
    gemm_proj_mfma_k<false><<<dim3(4, 32), blk, 0, stream>>>(XMb, WprojT, bproj, 2.0f, x_out);

    // --- branch 3: i_x_out (iatt conversions into biasF alias after fused2) ---
    conv_iatt_k<<<dim3(32, 8, BHH), blk, 0, stream>>>(i_att, iattT8, iattBF);
    scores_mfma_k<<<dim3(8, 2, BHH), blk, 0, stream>>>(IKQ, IK, SPa, KLL, XLL);
    softmax_wide_k<0><<<dim3(BHH * KLL), blk, 0, stream>>>(SPa, nullptr, iattT8, -1e9f);
    pv_mfma_k<<<dim3(4, BHH), blk, 0, stream>>>(SPa, IVt, KMb, KLL, XLL);
    gemm_proj_mfma_k<true><<<dim3(4, 8), blk, 0, stream>>>(KMb, WprojIT, bproj_i, 1.0f, IKOUTb);
    gemm_qkv_mfma_k<<<dim3(12, 8), blk, 0, stream>>>(IKOUTb, WqkvI2T, nullptr, K2K, K2Vt, 8);
    attn_xk_fused_k<1><<<dim3(512), blk, 0, stream>>>(
        IQ, K2K, K2Vt, iattBF, nullptr, nullptr, nullptr, XMb);
    gemm_proj_mfma_k<false><<<dim3(4, 32), blk, 0, stream>>>(XMb, WprojI2T, bproj_i2, 1.0f, i_x_out);

    (void)in_sizes; (void)n_in; (void)out_size; (void)ws_size;
}

// Round 9
// 362.340 us; speedup vs baseline: 1.3581x; 1.2599x over previous
//
#include <hip/hip_runtime.h>
#include <cstddef>
#include <cstdint>

#define BB 4
#define HH 8
#define HEADD 64
#define DIMM 512
#define XLL 1024
#define KLL 256
#define BHH (BB*HH)

typedef __attribute__((ext_vector_type(8))) short bf16x8;
typedef __attribute__((ext_vector_type(8))) unsigned short u16x8;
typedef __attribute__((ext_vector_type(4))) float f32x4;
typedef unsigned short u16;

__device__ __forceinline__ u16 f2b(float f) {
    unsigned int u = __builtin_bit_cast(unsigned int, f);
    u = u + 0x7fffu + ((u >> 16) & 1u);
    return (u16)(u >> 16);
}
__device__ __forceinline__ float b2f(u16 h) {
    unsigned int u = ((unsigned int)h) << 16;
    return __builtin_bit_cast(float, u);
}
__device__ __forceinline__ f32x4 mfma16(bf16x8 a, bf16x8 b, f32x4 c) {
    return __builtin_amdgcn_mfma_f32_16x16x32_bf16(a, b, c, 0, 0, 0);
}
__device__ __forceinline__ float wred_max(float v) {
    #pragma unroll
    for (int o = 1; o < 64; o <<= 1) v = fmaxf(v, __shfl_xor(v, o, 64));
    return v;
}
__device__ __forceinline__ float wred_sum(float v) {
    #pragma unroll
    for (int o = 1; o < 64; o <<= 1) v += __shfl_xor(v, o, 64);
    return v;
}

// Fragment-order bias layout:
//   E(bh,x,k) = ((bh*64 + (x>>4))*8 + (k>>5))*512
//             + (((x>>2)&3)*16 + (k&15))*8 + ((k>>4)&1)*4 + (x&3)

// ---------------------------------------------------------------------------
// All 6 weight transposes in one launch. f32 [K][N] -> bf16 [N][K].
// ---------------------------------------------------------------------------
__global__ __launch_bounds__(256) void transpose_all_k(
    const float* __restrict__ s0, const float* __restrict__ s1,
    const float* __restrict__ s2, const float* __restrict__ s3,
    const float* __restrict__ s4, const float* __restrict__ s5,
    u16* __restrict__ d0, u16* __restrict__ d1, u16* __restrict__ d2,
    u16* __restrict__ d3, u16* __restrict__ d4, u16* __restrict__ d5)
{
    __shared__ float t[32][33];
    const int id = blockIdx.x;
    const float* W; u16* Wt; int N, bx, by;
    if (id < 2304) {
        int which = id / 768, local = id - which * 768;
        W = which == 0 ? s0 : (which == 1 ? s1 : s2);
        Wt = which == 0 ? d0 : (which == 1 ? d1 : d2);
        N = 1536; bx = local % 48; by = local / 48;
    } else {
        int which = (id - 2304) / 256, local = (id - 2304) % 256;
        W = which == 0 ? s3 : (which == 1 ? s4 : s5);
        Wt = which == 0 ? d3 : (which == 1 ? d4 : d5);
        N = 512; bx = local % 16; by = local / 16;
    }
    const int K = 512;
    int tx = threadIdx.x & 31, ty = threadIdx.x >> 5;
    #pragma unroll
    for (int r = ty; r < 32; r += 8)
        t[r][tx] = W[(size_t)(by * 32 + r) * N + bx * 32 + tx];
    __syncthreads();
    #pragma unroll
    for (int r = ty; r < 32; r += 8)
        Wt[(size_t)(bx * 32 + r) * K + by * 32 + tx] = f2b(t[tx][r]);
}

// ---------------------------------------------------------------------------
// All 4 input casts in one launch (8 elems/thread).
// chunks: x [0,262144) kern [..327680) i_x [..589824) i_kern [..655360)
// ---------------------------------------------------------------------------
__global__ __launch_bounds__(256) void cast_all_k(
    const float* __restrict__ x, const float* __restrict__ kern,
    const float* __restrict__ ix, const float* __restrict__ ikern,
    u16* __restrict__ a0, u16* __restrict__ a1,
    u16* __restrict__ a2, u16* __restrict__ a3)
{
    int i = blockIdx.x * 256 + threadIdx.x;
    const float* src; u16* dst; int base;
    if (i < 262144)      { src = x;     dst = a0; base = 0; }
    else if (i < 327680) { src = kern;  dst = a1; base = 262144; }
    else if (i < 589824) { src = ix;    dst = a2; base = 327680; }
    else                 { src = ikern; dst = a3; base = 589824; }
    int j = i - base;
    const float4* p = reinterpret_cast<const float4*>(src) + (size_t)j * 2;
    float4 a = p[0], b = p[1];
    u16x8 o;
    o[0] = f2b(a.x); o[1] = f2b(a.y); o[2] = f2b(a.z); o[3] = f2b(a.w);
    o[4] = f2b(b.x); o[5] = f2b(b.y); o[6] = f2b(b.z); o[7] = f2b(b.w);
    *reinterpret_cast<u16x8*>(dst + (size_t)j * 8) = o;
}

// ---------------------------------------------------------------------------
// mask int32 [bh,1024,256] -> u8 [bh,256,1024]
// ---------------------------------------------------------------------------
__global__ __launch_bounds__(256) void mask_t8_k(
    const int* __restrict__ m, unsigned char* __restrict__ mt)
{
    __shared__ unsigned char t[32][33];
    const int bh = blockIdx.z, xt = blockIdx.x, kt = blockIdx.y;
    const int tx = threadIdx.x & 31, ty = threadIdx.x >> 5;
    #pragma unroll
    for (int r = ty; r < 32; r += 8)
        t[r][tx] = (unsigned char)(m[((size_t)bh * 1024 + xt * 32 + r) * 256 + kt * 32 + tx] != 0);
    __syncthreads();
    #pragma unroll
    for (int r = ty; r < 32; r += 8)
        mt[((size_t)bh * 256 + kt * 32 + r) * 1024 + xt * 32 + tx] = t[tx][r];
}

// ---------------------------------------------------------------------------
// Two mask->fragment-order bf16 bias builds in one launch (cross, i_att).
// ---------------------------------------------------------------------------
__global__ __launch_bounds__(256) void mask_biasF_pair_k(
    const int* __restrict__ m1, u16* __restrict__ o1F,
    const int* __restrict__ m2, u16* __restrict__ o2F)
{
    const int z = blockIdx.z;
    const int bh = z & 31;
    const int* m = (z < 32) ? m1 : m2;
    u16* oF = (z < 32) ? o1F : o2F;
    const int xt = blockIdx.x, kt = blockIdx.y;
    const int tid = threadIdx.x;
    const u16 NEG = f2b(-1e9f);
    const int sl = tid >> 7, rem = tid & 127, l = rem >> 1, nilow = rem & 1;
    const int lg = l >> 4, lr_ = l & 15;
    const int xl0 = sl * 16 + lg * 4, kl = nilow * 16 + lr_;
    const int kg = kt * 32 + kl;
    u16 o_[4];
    #pragma unroll
    for (int j = 0; j < 4; ++j) {
        int mm = m[((size_t)bh * 1024 + xt * 32 + xl0 + j) * 256 + kg];
        o_[j] = mm ? NEG : (u16)0;
    }
    ushort4 o; o.x = o_[0]; o.y = o_[1]; o.z = o_[2]; o.w = o_[3];
    size_t eb = (((size_t)bh * 64 + xt * 2 + sl) * 8 + kt) * 512 + (size_t)l * 8 + nilow * 4;
    *reinterpret_cast<ushort4*>(oF + eb) = o;
}

// ---------------------------------------------------------------------------
// main orientation: block per (b,k); reads polar row once, loops 8 heads.
// ---------------------------------------------------------------------------
__global__ __launch_bounds__(256) void main_ori_k8(
    const u16* __restrict__ S, const int* __restrict__ polar,
    int* __restrict__ MO)
{
    const int blk = blockIdx.x;          // b*256 + k
    const int b = blk >> 8, k = blk & 255;
    const int tid = threadIdx.x;
    const int wave = tid >> 6, lane = tid & 63;
    const int c = tid * 4;
    int4 p4 = *reinterpret_cast<const int4*>(polar + ((size_t)b * 256 + k) * 1024 + c);
    int pp[4] = { p4.x, p4.y, p4.z, p4.w };
    #pragma unroll
    for (int j = 0; j < 4; ++j) { int p = pp[j]; pp[j] = p < 0 ? 0 : (p > 7 ? 7 : p); }
    __shared__ float sred[4][8];
    for (int h = 0; h < 8; ++h) {
        const int bh = b * 8 + h;
        ushort4 sv = *reinterpret_cast<const ushort4*>(S + ((size_t)bh * 256 + k) * 1024 + c);
        float av[4] = { fabsf(b2f(sv.x)), fabsf(b2f(sv.y)), fabsf(b2f(sv.z)), fabsf(b2f(sv.w)) };
        float bins[8] = {};
        #pragma unroll
        for (int j = 0; j < 4; ++j) {
            #pragma unroll
            for (int o = 0; o < 8; ++o) bins[o] += (pp[j] == o) ? av[j] : 0.0f;
        }
        #pragma unroll
        for (int o = 0; o < 8; ++o) bins[o] = wred_sum(bins[o]);
        if (lane == 0) {
            #pragma unroll
            for (int o = 0; o < 8; ++o) sred[wave][o] = bins[o];
        }
        __syncthreads();
        if (tid == 0) {
            int best = 0; float bv = -1.0f;
            #pragma unroll
            for (int o = 0; o < 8; ++o) {
                float s = sred[0][o] + sred[1][o] + sred[2][o] + sred[3][o];
                if (s > bv) { bv = s; best = o; }
            }
            MO[bh * 256 + k] = best;
        }
        __syncthreads();
    }
}

// ---------------------------------------------------------------------------
// Combined bias build (after MO): biasF fragment order (-1e9) + bias1 [bh,k,x] (-1e6)
// ---------------------------------------------------------------------------
__global__ __launch_bounds__(256) void bias_build_k(
    const int* __restrict__ rd, const int* __restrict__ polar,
    const int* __restrict__ att, const float* __restrict__ dis,
    const float* __restrict__ pemb, const int* __restrict__ MO,
    u16* __restrict__ biasF, u16* __restrict__ bias1)
{
    const int b = blockIdx.z;
    const int xt = blockIdx.x * 32, kt = blockIdx.y * 32;
    const int tid = threadIdx.x;
    __shared__ float dsh[528];
    __shared__ int rds[32][33];   // [x][k]
    __shared__ int pls[32][33];
    __shared__ u16 bt[32][33];    // -1e6 variant [x][k]
    for (int i = tid; i < 528; i += 256) dsh[i] = dis[i];
    const int tx = tid & 31, ty = tid >> 5;
    #pragma unroll
    for (int r = ty; r < 32; r += 8) {
        size_t src = ((size_t)b * 256 + kt + r) * 1024 + xt + tx;  // rd[b,k,x]
        rds[tx][r] = rd[src];
        int p = polar[src]; pls[tx][r] = p < 0 ? 0 : (p > 7 ? 7 : p);
    }
    float pe[8];
    #pragma unroll
    for (int o = 0; o < 8; ++o) pe[o] = pemb[o];
    __syncthreads();
    const int sl = tid >> 7, rem = tid & 127, l = rem >> 1, nilow = rem & 1;
    const int lg = l >> 4, lr_ = l & 15;
    const int xl0 = sl * 16 + lg * 4, kl = nilow * 16 + lr_;
    const int kg = kt + kl;
    const u16 NEG9 = f2b(-1e9f), NEG6 = f2b(-1e6f);
    for (int h = 0; h < 8; ++h) {
        const int bh = b * 8 + h;
        int mo = MO[bh * 256 + kg];
        u16 o9[4];
        #pragma unroll
        for (int j = 0; j < 4; ++j) {
            int xl = xl0 + j;
            int mm = att[((size_t)bh * 1024 + xt + xl) * 256 + kg];
            float v = dsh[rds[xl][kl] * 8 + h] + pe[(pls[xl][kl] - mo + 8) & 7];
            u16 vb = f2b(v);
            o9[j] = mm ? NEG9 : vb;
            bt[xl][kl] = mm ? NEG6 : vb;
        }
        size_t eb = (((size_t)bh * 64 + (xt >> 4) + sl) * 8 + (kt >> 5)) * 512 + (size_t)l * 8 + nilow * 4;
        ushort4 ov; ov.x = o9[0]; ov.y = o9[1]; ov.z = o9[2]; ov.w = o9[3];
        *reinterpret_cast<ushort4*>(biasF + eb) = ov;
        __syncthreads();
        const int k_ = tid >> 3, x4 = (tid & 7) * 4;
        ushort4 o2;
        o2.x = bt[x4 + 0][k_]; o2.y = bt[x4 + 1][k_];
        o2.z = bt[x4 + 2][k_]; o2.w = bt[x4 + 3][k_];
        *reinterpret_cast<ushort4*>(bias1 + ((size_t)bh * 256 + kt + k_) * 1024 + xt + x4) = o2;
        __syncthreads();
    }
}

// ---------------------------------------------------------------------------
// Shared QKV GEMM body. A bf16 [M,512] @ Wt [1536,512]^T; q pre-scaled 0.125.
// ---------------------------------------------------------------------------
__device__ __forceinline__ void qkv_body(
    const u16* __restrict__ A, const u16* __restrict__ Wt,
    u16* __restrict__ qb, u16* __restrict__ kb, u16* __restrict__ vt,
    int sl, int rb, int cb)
{
    __shared__ __align__(16) short As[128][72];
    __shared__ __align__(16) short Bs[128][72];
    const int tid = threadIdx.x;
    const int wave = tid >> 6, lane = tid & 63;
    const int lr = lane & 15, lk = (lane >> 4) * 8;
    const int wr = (wave >> 1) * 64, wc = (wave & 1) * 64;
    const int seq = 1 << sl, smask = seq - 1;
    f32x4 acc[4][4] = {};
    const int srow = tid >> 3, skc = (tid & 7) * 8;
    for (int k0 = 0; k0 < 512; k0 += 64) {
        #pragma unroll
        for (int it = 0; it < 4; ++it) {
            int row = it * 32 + srow;
            *reinterpret_cast<bf16x8*>(&As[row][skc]) =
                *reinterpret_cast<const bf16x8*>(A + (size_t)(rb + row) * 512 + k0 + skc);
            *reinterpret_cast<bf16x8*>(&Bs[row][skc]) =
                *reinterpret_cast<const bf16x8*>(Wt + (size_t)(cb + row) * 512 + k0 + skc);
        }
        __syncthreads();
        #pragma unroll
        for (int ks = 0; ks < 2; ++ks) {
            bf16x8 af[4], bf_[4];
            #pragma unroll
            for (int mi = 0; mi < 4; ++mi)
                af[mi] = *reinterpret_cast<const bf16x8*>(&As[wr + mi * 16 + lr][ks * 32 + lk]);
            #pragma unroll
            for (int ni = 0; ni < 4; ++ni)
                bf_[ni] = *reinterpret_cast<const bf16x8*>(&Bs[wc + ni * 16 + lr][ks * 32 + lk]);
            #pragma unroll
            for (int mi = 0; mi < 4; ++mi)
                #pragma unroll
                for (int ni = 0; ni < 4; ++ni)
                    acc[mi][ni] = mfma16(af[mi], bf_[ni], acc[mi][ni]);
        }
        __syncthreads();
    }
    #pragma unroll
    for (int mi = 0; mi < 4; ++mi) {
        int m0 = rb + wr + mi * 16 + (lane >> 4) * 4;
        #pragma unroll
        for (int ni = 0; ni < 4; ++ni) {
            int c = cb + wc + ni * 16 + lr;
            int which = c >> 9, h = (c >> 6) & 7, d = c & 63;
            f32x4 v = acc[mi][ni];
            #pragma unroll
            for (int j = 0; j < 4; ++j) {
                int mm = m0 + j;
                int b = mm >> sl, n = mm & smask;
                if (which == 0) {
                    if (qb) qb[(((size_t)b * HH + h) * seq + n) * 64 + d] = f2b(v[j] * 0.125f);
                } else if (which == 1) {
                    if (kb) kb[(((size_t)b * HH + h) * seq + n) * 64 + d] = f2b(v[j]);
                } else {
                    vt[(((size_t)b * HH + h) * 64 + d) * seq + n] = f2b(v[j]);
                }
            }
        }
    }
}

// All 4 first-stage QKV GEMMs: grid (12, 80)
__global__ __launch_bounds__(256) void gemm_qkv_all_k(
    const u16* __restrict__ A0, const u16* __restrict__ A1,
    const u16* __restrict__ A2, const u16* __restrict__ A3,
    const u16* __restrict__ W01, const u16* __restrict__ W23,
    u16* q0, u16* k0, u16* v0, u16* q1, u16* k1, u16* v1,
    u16* q2, u16* k2, u16* v2, u16* q3, u16* k3, u16* v3)
{
    const int y = blockIdx.y;
    const u16 *A, *Wt; u16 *qb, *kb, *vt; int sl, ry;
    if (y < 32)      { A = A0; Wt = W01; qb = q0; kb = k0; vt = v0; sl = 10; ry = y; }
    else if (y < 40) { A = A1; Wt = W01; qb = q1; kb = k1; vt = v1; sl = 8;  ry = y - 32; }
    else if (y < 72) { A = A2; Wt = W23; qb = q2; kb = k2; vt = v2; sl = 10; ry = y - 40; }
    else             { A = A3; Wt = W23; qb = q3; kb = k3; vt = v3; sl = 8;  ry = y - 72; }
    qkv_body(A, Wt, qb, kb, vt, sl, ry * 128, blockIdx.x * 128);
}

// Single QKV GEMM (second stage, IKOUT)
__global__ __launch_bounds__(256) void gemm_qkv_mfma_k(
    const u16* __restrict__ A, const u16* __restrict__ Wt,
    u16* qb, u16* kb, u16* vt, int sl)
{
    qkv_body(A, Wt, qb, kb, vt, sl, blockIdx.y * 128, blockIdx.x * 128);
}

// ---------------------------------------------------------------------------
// Proj GEMM body: A bf16 [M,512] @ Wt [512,512]^T + bscale*bias
// ---------------------------------------------------------------------------
template<bool OUTBF>
__device__ __forceinline__ void proj_body(
    const u16* __restrict__ A, const u16* __restrict__ Wt,
    const float* __restrict__ bias, float bscale, void* __restrict__ outp,
    int rb, int cb)
{
    __shared__ __align__(16) short As[128][72];
    __shared__ __align__(16) short Bs[128][72];
    const int tid = threadIdx.x;
    const int wave = tid >> 6, lane = tid & 63;
    const int lr = lane & 15, lk = (lane >> 4) * 8;
    const int wr = (wave >> 1) * 64, wc = (wave & 1) * 64;
    f32x4 acc[4][4] = {};
    const int srow = tid >> 3, skc = (tid & 7) * 8;
    for (int k0 = 0; k0 < 512; k0 += 64) {
        #pragma unroll
        for (int it = 0; it < 4; ++it) {
            int row = it * 32 + srow;
            *reinterpret_cast<bf16x8*>(&As[row][skc]) =
                *reinterpret_cast<const bf16x8*>(A + (size_t)(rb + row) * 512 + k0 + skc);
            *reinterpret_cast<bf16x8*>(&Bs[row][skc]) =
                *reinterpret_cast<const bf16x8*>(Wt + (size_t)(cb + row) * 512 + k0 + skc);
        }
        __syncthreads();
        #pragma unroll
        for (int ks = 0; ks < 2; ++ks) {
            bf16x8 af[4], bf_[4];
            #pragma unroll
            for (int mi = 0; mi < 4; ++mi)
                af[mi] = *reinterpret_cast<const bf16x8*>(&As[wr + mi * 16 + lr][ks * 32 + lk]);
            #pragma unroll
            for (int ni = 0; ni < 4; ++ni)
                bf_[ni] = *reinterpret_cast<const bf16x8*>(&Bs[wc + ni * 16 + lr][ks * 32 + lk]);
            #pragma unroll
            for (int mi = 0; mi < 4; ++mi)
                #pragma unroll
                for (int ni = 0; ni < 4; ++ni)
                    acc[mi][ni] = mfma16(af[mi], bf_[ni], acc[mi][ni]);
        }
        __syncthreads();
    }
    #pragma unroll
    for (int mi = 0; mi < 4; ++mi) {
        int m0 = rb + wr + mi * 16 + (lane >> 4) * 4;
        #pragma unroll
        for (int ni = 0; ni < 4; ++ni) {
            int c = cb + wc + ni * 16 + lr;
            float bv = bscale * bias[c];
            f32x4 v = acc[mi][ni];
            #pragma unroll
            for (int j = 0; j < 4; ++j) {
                size_t o = (size_t)(m0 + j) * 512 + c;
                if (OUTBF) reinterpret_cast<u16*>(outp)[o] = f2b(v[j] + bv);
                else       reinterpret_cast<float*>(outp)[o] = v[j] + bv;
            }
        }
    }
}

// single proj (IKOUT, bf16 out)
__global__ __launch_bounds__(256) void gemm_proj_bf16_k(
    const u16* __restrict__ A, const u16* __restrict__ Wt,
    const float* __restrict__ bias, float bscale, u16* __restrict__ outp)
{
    proj_body<true>(A, Wt, bias, bscale, outp, blockIdx.y * 128, blockIdx.x * 128);
}

// final combined proj: z=0 x_out (XMb,Wproj,2*bproj), z=1 i_x_out (XMb2,WprojI2),
// z=2 k_out (KMb,Wproj) with only 8 y-tiles.
__global__ __launch_bounds__(256) void gemm_proj3_k(
    const u16* __restrict__ A0, const u16* __restrict__ A1, const u16* __restrict__ A2,
    const u16* __restrict__ W, const u16* __restrict__ Wi2,
    const float* __restrict__ bp, const float* __restrict__ bpi2,
    float* __restrict__ o0, float* __restrict__ o1, float* __restrict__ o2)
{
    const int z = blockIdx.z;
    if (z == 2 && blockIdx.y >= 8) return;
    const u16* A = z == 0 ? A0 : (z == 1 ? A1 : A2);
    const u16* Wt = (z == 1) ? Wi2 : W;
    const float* bias = (z == 1) ? bpi2 : bp;
    float bscale = (z == 0) ? 2.0f : 1.0f;
    float* outp = z == 0 ? o0 : (z == 1 ? o1 : o2);
    proj_body<false>(A, Wt, bias, bscale, outp, blockIdx.y * 128, blockIdx.x * 128);
}

// ---------------------------------------------------------------------------
// Paired wide scores: z<32 -> (KQ,KX)->SPa ; else (IKQ,IK)->SPb. R=256,C=1024.
// ---------------------------------------------------------------------------
__global__ __launch_bounds__(256) void scores_pair_k(
    const u16* __restrict__ A1, const u16* __restrict__ B1, u16* __restrict__ S1,
    const u16* __restrict__ A2, const u16* __restrict__ B2, u16* __restrict__ S2)
{
    __shared__ __align__(16) short As[128][72];
    __shared__ __align__(16) short Bs[128][72];
    const int z = blockIdx.z, bh = z & 31;
    const u16* Aq = (z < 32) ? A1 : A2;
    const u16* Bk = (z < 32) ? B1 : B2;
    u16* S = (z < 32) ? S1 : S2;
    const int tid = threadIdx.x;
    const int wave = tid >> 6, lane = tid & 63;
    const int lr = lane & 15, lk = (lane >> 4) * 8;
    const int rb = blockIdx.y * 128, cb = blockIdx.x * 128;
    const int wr = (wave >> 1) * 64, wc = (wave & 1) * 64;
    const u16* Ap = Aq + (size_t)bh * 256 * 64;
    const u16* Bp = Bk + (size_t)bh * 1024 * 64;
    const int srow = tid >> 3, skc = (tid & 7) * 8;
    #pragma unroll
    for (int it = 0; it < 4; ++it) {
        int row = it * 32 + srow;
        *reinterpret_cast<bf16x8*>(&As[row][skc]) =
            *reinterpret_cast<const bf16x8*>(Ap + (size_t)(rb + row) * 64 + skc);
        *reinterpret_cast<bf16x8*>(&Bs[row][skc]) =
            *reinterpret_cast<const bf16x8*>(Bp + (size_t)(cb + row) * 64 + skc);
    }
    __syncthreads();
    f32x4 acc[4][4] = {};
    #pragma unroll
    for (int ks = 0; ks < 2; ++ks) {
        bf16x8 af[4], bf_[4];
        #pragma unroll
        for (int mi = 0; mi < 4; ++mi)
            af[mi] = *reinterpret_cast<const bf16x8*>(&As[wr + mi * 16 + lr][ks * 32 + lk]);
        #pragma unroll
        for (int ni = 0; ni < 4; ++ni)
            bf_[ni] = *reinterpret_cast<const bf16x8*>(&Bs[wc + ni * 16 + lr][ks * 32 + lk]);
        #pragma unroll
        for (int mi = 0; mi < 4; ++mi)
            #pragma unroll
            for (int ni = 0; ni < 4; ++ni)
                acc[mi][ni] = mfma16(af[mi], bf_[ni], acc[mi][ni]);
    }
    #pragma unroll
    for (int mi = 0; mi < 4; ++mi) {
        int r0 = rb + wr + mi * 16 + (lane >> 4) * 4;
        #pragma unroll
        for (int ni = 0; ni < 4; ++ni) {
            int c = cb + wc + ni * 16 + lr;
            f32x4 v = acc[mi][ni];
            #pragma unroll
            for (int j = 0; j < 4; ++j)
                S[((size_t)bh * 256 + r0 + j) * 1024 + c] = f2b(v[j]);
        }
    }
}

// ---------------------------------------------------------------------------
// Paired wide softmax: rows [0,8192) -> SPa + bf16 bias1 ; [8192,16384) ->
// SPb + u8 maskT (-1e9).
// ---------------------------------------------------------------------------
__global__ __launch_bounds__(256) void softmax_pair_k(
    u16* __restrict__ S1, const u16* __restrict__ bias1,
    u16* __restrict__ S2, const unsigned char* __restrict__ maskT)
{
    const int rg = blockIdx.x;
    const bool first = rg < 8192;
    const int row_g = first ? rg : rg - 8192;
    const int tid = threadIdx.x;
    const int wave = tid >> 6, lane = tid & 63;
    const int c = tid * 4;
    u16* rowp = (first ? S1 : S2) + (size_t)row_g * 1024;
    ushort4 sv = *reinterpret_cast<const ushort4*>(rowp + c);
    float s[4] = { b2f(sv.x), b2f(sv.y), b2f(sv.z), b2f(sv.w) };
    if (first) {
        ushort4 bv = *reinterpret_cast<const ushort4*>(bias1 + (size_t)row_g * 1024 + c);
        s[0] += b2f(bv.x); s[1] += b2f(bv.y); s[2] += b2f(bv.z); s[3] += b2f(bv.w);
    } else {
        uchar4 mk = *reinterpret_cast<const uchar4*>(maskT + (size_t)row_g * 1024 + c);
        if (mk.x) s[0] = -1e9f; if (mk.y) s[1] = -1e9f;
        if (mk.z) s[2] = -1e9f; if (mk.w) s[3] = -1e9f;
    }
    __shared__ float swv[4];
    float lm = fmaxf(fmaxf(s[0], s[1]), fmaxf(s[2], s[3]));
    lm = wred_max(lm);
    if (lane == 0) swv[wave] = lm;
    __syncthreads();
    float m = fmaxf(fmaxf(swv[0], swv[1]), fmaxf(swv[2], swv[3]));
    __syncthreads();
    float ls = 0.0f;
    #pragma unroll
    for (int j = 0; j < 4; ++j) { s[j] = __expf(s[j] - m); ls += s[j]; }
    ls = wred_sum(ls);
    if (lane == 0) swv[wave] = ls;
    __syncthreads();
    float inv = 1.0f / (swv[0] + swv[1] + swv[2] + swv[3]);
    ushort4 ov = { f2b(s[0] * inv), f2b(s[1] * inv), f2b(s[2] * inv), f2b(s[3] * inv) };
    *reinterpret_cast<ushort4*>(rowp + c) = ov;
}

// ---------------------------------------------------------------------------
// Paired PV, barrier-free direct-global. z=0: (SPa,VXt)->KMb ; z=1: (SPb,IVt)->KMb2
// R=256 rows, C=1024. Each wave: 16 rows, full C loop.
// ---------------------------------------------------------------------------
__global__ __launch_bounds__(256) void pv_pair_k(
    const u16* __restrict__ P1, const u16* __restrict__ V1, u16* __restrict__ o1,
    const u16* __restrict__ P2, const u16* __restrict__ V2, u16* __restrict__ o2)
{
    const int z = blockIdx.z;
    const u16* P = z ? P2 : P1;
    const u16* V = z ? V2 : V1;
    u16* out = z ? o2 : o1;
    const int tid = threadIdx.x;
    const int wave = tid >> 6, lane = tid & 63;
    const int lr = lane & 15, lg = lane >> 4, lk = lg * 8;
    const int bh = blockIdx.y, b = bh >> 3, h = bh & 7;
    const int rb = blockIdx.x * 64;
    const int wr = wave * 16;
    f32x4 acc[4] = {};
    const u16* Pb = P + ((size_t)bh * 256 + rb) * 1024;
    const u16* Vb = V + (size_t)bh * 64 * 1024;
    for (int c0 = 0; c0 < 1024; c0 += 64) {
        #pragma unroll
        for (int ks = 0; ks < 2; ++ks) {
            bf16x8 ap = *reinterpret_cast<const bf16x8*>(
                Pb + (size_t)(wr + lr) * 1024 + c0 + ks * 32 + lk);
            #pragma unroll
            for (int ni = 0; ni < 4; ++ni) {
                bf16x8 vv = *reinterpret_cast<const bf16x8*>(
                    Vb + (size_t)(ni * 16 + lr) * 1024 + c0 + ks * 32 + lk);
                acc[ni] = mfma16(ap, vv, acc[ni]);
            }
        }
    }
    #pragma unroll
    for (int ni = 0; ni < 4; ++ni) {
        int d = ni * 16 + lr;
        f32x4 v = acc[ni];
        #pragma unroll
        for (int j = 0; j < 4; ++j) {
            int r0 = rb + wr + lg * 4 + j;
            out[((size_t)(b * 256 + r0)) * 512 + h * 64 + d] = f2b(v[j]);
        }
    }
}

// ---------------------------------------------------------------------------
// Fused attention v6: 64 x-rows/block, 4 waves, wave owns 16 rows. ZERO
// barriers: Q in regs, K and V direct from global (L1/L2-resident per-bh
// tiles), bias fragment-order from regs, per-wave LDS only for P transpose.
// LDS 33792 B. Grid 512, XCD-swizzled.
// ---------------------------------------------------------------------------
template<int NSRC>
__global__ __launch_bounds__(256) void attn_xk_fused_k(
    const u16* __restrict__ Qp,
    const u16* __restrict__ K1, const u16* __restrict__ V1t, const u16* __restrict__ B1F,
    const u16* __restrict__ K2, const u16* __restrict__ V2t, const u16* __restrict__ B2F,
    u16* __restrict__ outm)
{
    const int tid = threadIdx.x;
    const int w = tid >> 6, lane = tid & 63;
    const int lr = lane & 15, lg = lane >> 4, lk = lg * 8;
    const int lin = blockIdx.x;
    const int xcd = lin & 7, idx = lin >> 3;
    const int bh = xcd * 4 + (idx & 3);
    const int rb = (idx >> 2) * 64;
    const int b = bh >> 3, h = bh & 7;
    const int wr = w * 16;
    const int strip = (rb >> 4) + w;

    __shared__ __align__(16) short Ps[4 * 16 * 264];   // per-wave scratch
    short* myP = &Ps[w * 16 * 264];

    bf16x8 qf0, qf1;
    {
        const u16* Qb = Qp + ((size_t)bh * 1024 + rb + wr + lr) * 64;
        qf0 = *reinterpret_cast<const bf16x8*>(Qb + lk);
        qf1 = *reinterpret_cast<const bf16x8*>(Qb + 32 + lk);
    }

    f32x4 acc2[4] = {};

    #pragma unroll
    for (int s = 0; s < NSRC; ++s) {
        const u16* Kp = s ? K2 : K1;
        const u16* Vp = s ? V2t : V1t;
        const u16* BF = s ? B2F : B1F;
        // bias prefetch (fragment order): 8 x 16B coalesced loads
        bf16x8 breg[8];
        {
            const u16* bb = BF + (((size_t)bh * 64 + strip) * 8) * 512 + (size_t)lane * 8;
            #pragma unroll
            for (int itp = 0; itp < 8; ++itp)
                breg[itp] = *reinterpret_cast<const bf16x8*>(bb + (size_t)itp * 512);
        }
        // scores: 16 rows x 256 cols per wave; K direct from global
        const u16* Kb = Kp + (size_t)bh * 256 * 64;
        f32x4 acc[16];
        #pragma unroll
        for (int ni = 0; ni < 16; ++ni) acc[ni] = (f32x4){0.f, 0.f, 0.f, 0.f};
        #pragma unroll
        for (int ni = 0; ni < 16; ++ni) {
            bf16x8 b0 = *reinterpret_cast<const bf16x8*>(Kb + (size_t)(ni * 16 + lr) * 64 + lk);
            acc[ni] = mfma16(qf0, b0, acc[ni]);
        }
        #pragma unroll
        for (int ni = 0; ni < 16; ++ni) {
            bf16x8 b1 = *reinterpret_cast<const bf16x8*>(Kb + (size_t)(ni * 16 + lr) * 64 + 32 + lk);
            acc[ni] = mfma16(qf1, b1, acc[ni]);
        }
        // bias from regs + in-wave softmax
        float mx[4] = { -3.4e38f, -3.4e38f, -3.4e38f, -3.4e38f };
        #pragma unroll
        for (int ni = 0; ni < 16; ++ni) {
            const bf16x8 br = breg[ni >> 1];
            #pragma unroll
            for (int j = 0; j < 4; ++j) {
                float v = acc[ni][j] + b2f((u16)br[(ni & 1) * 4 + j]);
                acc[ni][j] = v;
                mx[j] = fmaxf(mx[j], v);
            }
        }
        #pragma unroll
        for (int j = 0; j < 4; ++j) {
            #pragma unroll
            for (int o = 1; o < 16; o <<= 1) mx[j] = fmaxf(mx[j], __shfl_xor(mx[j], o, 64));
        }
        float sm[4] = {};
        #pragma unroll
        for (int ni = 0; ni < 16; ++ni) {
            #pragma unroll
            for (int j = 0; j < 4; ++j) {
                float e = __expf(acc[ni][j] - mx[j]);
                acc[ni][j] = e;
                sm[j] += e;
            }
        }
        #pragma unroll
        for (int j = 0; j < 4; ++j) {
            #pragma unroll
            for (int o = 1; o < 16; o <<= 1) sm[j] += __shfl_xor(sm[j], o, 64);
            sm[j] = 1.0f / sm[j];
        }
        // P to wave-local LDS (in-wave transpose), then PV with V from global
        #pragma unroll
        for (int ni = 0; ni < 16; ++ni)
            #pragma unroll
            for (int j = 0; j < 4; ++j)
                myP[(lg * 4 + j) * 264 + ni * 16 + lr] = (short)f2b(acc[ni][j] * sm[j]);
        #pragma unroll
        for (int kc = 0; kc < 8; ++kc) {
            bf16x8 ap = *reinterpret_cast<const bf16x8*>(&myP[lr * 264 + kc * 32 + lk]);
            #pragma unroll
            for (int ni = 0; ni < 4; ++ni) {
                bf16x8 vv = *reinterpret_cast<const bf16x8*>(
                    Vp + ((size_t)bh * 64 + ni * 16 + lr) * 256 + kc * 32 + lk);
                acc2[ni] = mfma16(ap, vv, acc2[ni]);
            }
        }
    }
    #pragma unroll
    for (int ni = 0; ni < 4; ++ni) {
        int d = ni * 16 + lr;
        f32x4 v = acc2[ni];
        #pragma unroll
        for (int j = 0; j < 4; ++j) {
            int row = rb + wr + lg * 4 + j;
            outm[((size_t)(b * 1024 + row)) * 512 + h * 64 + d] = f2b(v[j]);
        }
    }
}

// ---------------------------------------------------------------------------
extern "C" void kernel_launch(void* const* d_in, const int* in_sizes, int n_in,
                              void* d_out, int out_size, void* d_ws, size_t ws_size,
                              hipStream_t stream)
{
    const float* x        = (const float*)d_in[0];
    const float* kernal   = (const float*)d_in[1];
    const float* i_x      = (const float*)d_in[2];
    const float* i_kernal = (const float*)d_in[3];
    const int*   rd       = (const int*)d_in[4];
    const int*   polar    = (const int*)d_in[5];
    const int*   att      = (const int*)d_in[6];
    const int*   i_att    = (const int*)d_in[7];
    const int*   cross    = (const int*)d_in[8];
    const float* Wqkv     = (const float*)d_in[9];
    const float* Wqkv_i   = (const float*)d_in[10];
    const float* Wqkv_i2  = (const float*)d_in[11];
    const float* Wproj    = (const float*)d_in[12];
    const float* bproj    = (const float*)d_in[13];
    const float* Wproj_i  = (const float*)d_in[14];
    const float* bproj_i  = (const float*)d_in[15];
    const float* Wproj_i2 = (const float*)d_in[16];
    const float* bproj_i2 = (const float*)d_in[17];
    const float* dis      = (const float*)d_in[18];
    const float* pemb     = (const float*)d_in[19];

    float* out = (float*)d_out;
    float* x_out   = out;
    float* k_out   = out + (size_t)BB * XLL * DIMM;
    float* i_x_out = k_out + (size_t)BB * KLL * DIMM;

    char* ws = (char*)d_ws;
    size_t off = 0;
    auto alloc = [&](size_t bytes) { void* p = ws + off; off += (bytes + 255) & ~(size_t)255; return p; };

    const size_t NAX = (size_t)BB * XLL * DIMM;
    const size_t NAK = (size_t)BB * KLL * DIMM;
    const size_t NHX = (size_t)BHH * XLL * HEADD;
    const size_t NHK = (size_t)BHH * KLL * HEADD;
    const size_t NS  = (size_t)BHH * KLL * XLL;

    u16* WqkvT    = (u16*)alloc((size_t)1536 * 512 * 2);
    u16* WqkvIT   = (u16*)alloc((size_t)1536 * 512 * 2);
    u16* WqkvI2T  = (u16*)alloc((size_t)1536 * 512 * 2);
    u16* WprojT   = (u16*)alloc((size_t)512 * 512 * 2);
    u16* WprojIT  = (u16*)alloc((size_t)512 * 512 * 2);
    u16* WprojI2T = (u16*)alloc((size_t)512 * 512 * 2);
    u16* Abf1 = (u16*)alloc(NAX * 2);
    u16* Abf2 = (u16*)alloc(NAK * 2);
    u16* Abf3 = (u16*)alloc(NAX * 2);
    u16* Abf4 = (u16*)alloc(NAK * 2);
    u16* Q    = (u16*)alloc(NHX * 2);
    u16* KX   = (u16*)alloc(NHX * 2);
    u16* VXt  = (u16*)alloc(NHX * 2);
    u16* IQ   = (u16*)alloc(NHX * 2);
    u16* IK   = (u16*)alloc(NHX * 2);
    u16* IVt  = (u16*)alloc(NHX * 2);
    u16* KQ   = (u16*)alloc(NHK * 2);
    u16* KK   = (u16*)alloc(NHK * 2);
    u16* KVt  = (u16*)alloc(NHK * 2);
    u16* IKQ  = (u16*)alloc(NHK * 2);
    u16* IKK  = (u16*)alloc(NHK * 2);
    u16* IKVt = (u16*)alloc(NHK * 2);
    u16* K2K  = (u16*)alloc(NHK * 2);
    u16* K2Vt = (u16*)alloc(NHK * 2);
    u16* SPa  = (u16*)alloc(NS * 2);
    u16* SPb  = (u16*)alloc(NS * 2);
    u16* KMb  = (u16*)alloc(NAK * 2);
    u16* KMb2 = (u16*)alloc(NAK * 2);
    u16* XMb  = (u16*)alloc(NAX * 2);
    u16* XMb2 = (u16*)alloc(NAX * 2);
    u16* IKOUTb = (u16*)alloc(NAK * 2);
    u16* biasF = (u16*)alloc(NS * 2);
    u16* bias1 = (u16*)alloc(NS * 2);
    unsigned char* iattT8 = (unsigned char*)alloc(NS);
    int* MO   = (int*)alloc((size_t)BHH * KLL * 4);

    u16* crossBF = SPa;    // built after pv_pair (SPa free)
    u16* iattBF  = bias1;  // built after softmax_pair (bias1 free)

    dim3 blk(256);

    // 1. prep
    transpose_all_k<<<dim3(3072), blk, 0, stream>>>(
        Wqkv, Wqkv_i, Wqkv_i2, Wproj, Wproj_i, Wproj_i2,
        WqkvT, WqkvIT, WqkvI2T, WprojT, WprojIT, WprojI2T);
    cast_all_k<<<dim3(2560), blk, 0, stream>>>(
        x, kernal, i_x, i_kernal, Abf1, Abf2, Abf3, Abf4);
    mask_t8_k<<<dim3(32, 8, 32), blk, 0, stream>>>(i_att, iattT8);

    // 2. all first-stage QKV GEMMs (q pre-scaled by 0.125)
    gemm_qkv_all_k<<<dim3(12, 80), blk, 0, stream>>>(
        Abf1, Abf2, Abf3, Abf4, WqkvT, WqkvIT,
        Q, KX, VXt, KQ, KK, KVt, IQ, IK, IVt, IKQ, IKK, IKVt);

    // 3. wide scores (branch1 + branch3)
    scores_pair_k<<<dim3(8, 2, 64), blk, 0, stream>>>(KQ, KX, SPa, IKQ, IK, SPb);
    // 4. main orientation + bias builds
    main_ori_k8<<<dim3(BB * KLL), blk, 0, stream>>>(SPa, polar, MO);
    bias_build_k<<<dim3(32, 8, BB), blk, 0, stream>>>(rd, polar, att, dis, pemb, MO, biasF, bias1);
    // 5. wide softmaxes
    softmax_pair_k<<<dim3(16384), blk, 0, stream>>>(SPa, bias1, SPb, iattT8);
    // 6. wide PVs (barrier-free)
    pv_pair_k<<<dim3(4, 32, 2), blk, 0, stream>>>(SPa, VXt, KMb, SPb, IVt, KMb2);
    // 7. mask-only fragment biases (alias into freed SPa / bias1)
    mask_biasF_pair_k<<<dim3(32, 8, 64), blk, 0, stream>>>(cross, crossBF, i_att, iattBF);
    // 8. IKOUT proj (bf16) + second qkv
    gemm_proj_bf16_k<<<dim3(4, 8), blk, 0, stream>>>(KMb2, WprojIT, bproj_i, 1.0f, IKOUTb);
    gemm_qkv_mfma_k<<<dim3(12, 8), blk, 0, stream>>>(IKOUTb, WqkvI2T, nullptr, K2K, K2Vt, 8);
    // 9. fused attentions
    attn_xk_fused_k<2><<<dim3(512), blk, 0, stream>>>(
        Q, KK, KVt, biasF, IKK, IKVt, crossBF, XMb);
    attn_xk_fused_k<1><<<dim3(512), blk, 0, stream>>>(
        IQ, K2K, K2Vt, iattBF, nullptr, nullptr, nullptr, XMb2);
    // 10. final combined projections (x_out, i_x_out, k_out)
    gemm_proj3_k<<<dim3(4, 32, 3), blk, 0, stream>>>(
        XMb, XMb2, KMb, WprojT, WprojI2T, bproj, bproj_i2, x_out, i_x_out, k_out);

    (void)in_sizes; (void)n_in; (void)out_size; (void)ws_size;
}